// Round 9
// baseline (348.248 us; speedup 1.0000x reference)
//
#include <hip/hip_runtime.h>
#include <math.h>

// ---------------------------------------------------------------------------
// QuantumTransformerE2E on MI355X — R9.
// k_pre:  R8 structure + LN1 folded into GEMV weights and pooled sum
//         (hid = i_t*(D - m_t*G) + B; summ = g*(sum W'_t h_raw - S) + b).
//         Removes the LN-apply LDS round-trip; barriers 6 -> 4.
// k_circ: verbatim R8 (verified): 16 chunks/wave, regs+DPP, zero DS.
// k_post8: 8 chunks per block — op_w/sa1_w loads amortized 8x.
// k_rpart/k_final + fallback: verbatim R8.
// ---------------------------------------------------------------------------

constexpr int kNQ    = 6;
constexpr int kDM    = 128;
constexpr int kCH    = 4;
constexpr int kSEQ   = 2048;
constexpr int kCHUNK = 16;
constexpr int kBATCH = 128;
constexpr int kNCH   = kSEQ / kCHUNK;  // 128
constexpr int kNP    = 120;
constexpr float kPI  = 3.14159265358979323846f;

__device__ __forceinline__ float fast_tanh(float x) {
  float e = __expf(-2.f * fabsf(x));
  float r = (1.f - e) * __builtin_amdgcn_rcpf(1.f + e);
  return copysignf(r, x);
}
__device__ __forceinline__ float fast_silu(float x) {
  return x * __builtin_amdgcn_rcpf(1.f + __expf(-x));
}

// ---------------------------------------------------------------------------
// quad_perm DPP helpers (VALU pipe — NOT ds_swizzle).
template <int XM>
__device__ __forceinline__ float qp(float v) {
  constexpr int ctrl = (XM == 1) ? 0xB1 : 0x4E;
  return __int_as_float(
      __builtin_amdgcn_update_dpp(0, __float_as_int(v), ctrl, 0xF, 0xF, true));
}

// ---- register-resident 6-qubit gates (verified R8) ------------------------

template <int RB>
__device__ __forceinline__ void rx_reg(float c, float s, float* sr, float* si) {
#pragma unroll
  for (int r0 = 0; r0 < 16; ++r0) {
    if (r0 & RB) continue;
    int r1 = r0 | RB;
    float ar = sr[r0], ai = si[r0], br = sr[r1], bi = si[r1];
    sr[r0] = fmaf(c, ar,  s * bi);  si[r0] = fmaf(c, ai, -s * br);
    sr[r1] = fmaf(c, br,  s * ai);  si[r1] = fmaf(c, bi, -s * ar);
  }
}

template <int RB>
__device__ __forceinline__ void ry_reg(float c, float s, float* sr, float* si) {
#pragma unroll
  for (int r0 = 0; r0 < 16; ++r0) {
    if (r0 & RB) continue;
    int r1 = r0 | RB;
    float ar = sr[r0], ai = si[r0], br = sr[r1], bi = si[r1];
    sr[r0] = fmaf(c, ar, -s * br);  si[r0] = fmaf(c, ai, -s * bi);
    sr[r1] = fmaf(s, ar,  c * br);  si[r1] = fmaf(s, ai,  c * bi);
  }
}

template <int RB>
__device__ __forceinline__ void rz_reg(float c, float s, float* sr, float* si) {
#pragma unroll
  for (int r = 0; r < 16; ++r) {
    float sp = (r & RB) ? s : -s;
    float ar = sr[r], ai = si[r];
    sr[r] = fmaf(c, ar, -sp * ai);
    si[r] = fmaf(c, ai,  sp * ar);
  }
}

template <int XM>
__device__ __forceinline__ void rx_lane(float c, float s, float* sr, float* si) {
#pragma unroll
  for (int r = 0; r < 16; ++r) {
    float pr = qp<XM>(sr[r]), pi = qp<XM>(si[r]);
    sr[r] = fmaf(c, sr[r],  s * pi);
    si[r] = fmaf(c, si[r], -s * pr);
  }
}

template <int XM>
__device__ __forceinline__ void ry_lane(float c, float sg, float* sr, float* si) {
#pragma unroll
  for (int r = 0; r < 16; ++r) {
    float pr = qp<XM>(sr[r]), pi = qp<XM>(si[r]);
    sr[r] = fmaf(c, sr[r], sg * pr);
    si[r] = fmaf(c, si[r], sg * pi);
  }
}

__device__ __forceinline__ void rz_lane(float c, float sp, float* sr, float* si) {
#pragma unroll
  for (int r = 0; r < 16; ++r) {
    float ar = sr[r], ai = si[r];
    sr[r] = fmaf(c, ar, -sp * ai);
    si[r] = fmaf(c, ai,  sp * ar);
  }
}

template <int RB, int CB>
__device__ __forceinline__ void crx_reg_reg(float c, float s, float* sr, float* si) {
#pragma unroll
  for (int r0 = 0; r0 < 16; ++r0) {
    if ((r0 & RB) || !(r0 & CB)) continue;
    int r1 = r0 | RB;
    float ar = sr[r0], ai = si[r0], br = sr[r1], bi = si[r1];
    sr[r0] = fmaf(c, ar,  s * bi);  si[r0] = fmaf(c, ai, -s * br);
    sr[r1] = fmaf(c, br,  s * ai);  si[r1] = fmaf(c, bi, -s * ar);
  }
}

template <int XM, int CB>
__device__ __forceinline__ void crx_reg_lane(float c, float s, float* sr, float* si) {
#pragma unroll
  for (int r = 0; r < 16; ++r) {
    if (!(r & CB)) continue;
    float pr = qp<XM>(sr[r]), pi = qp<XM>(si[r]);
    sr[r] = fmaf(c, sr[r],  s * pi);
    si[r] = fmaf(c, si[r], -s * pr);
  }
}

template <int RB>
__device__ __forceinline__ void meas_reg(const float* sr, const float* si,
                                         float& tr, float& ti, float& zz) {
  tr = 0.f; ti = 0.f; zz = 0.f;
#pragma unroll
  for (int r0 = 0; r0 < 16; ++r0) {
    float n = fmaf(sr[r0], sr[r0], si[r0] * si[r0]);
    zz += (r0 & RB) ? -n : n;
    if (r0 & RB) continue;
    int r1 = r0 | RB;
    tr = fmaf(sr[r0], sr[r1], fmaf(si[r0], si[r1], tr));
    ti = fmaf(sr[r0], si[r1], fmaf(-si[r0], sr[r1], ti));
  }
  tr += qp<1>(tr); tr += qp<2>(tr);
  ti += qp<1>(ti); ti += qp<2>(ti);
  zz += qp<1>(zz); zz += qp<2>(zz);
}

// ---------------------------------------------------------------------------
// k_pre: conv(global) + LN-folded chunk attention + projections -> csb_g.
// LN fold: hid[t][j] = i_t*(D[t][j] - m_t*G_j) + B_j with D over RAW h and
// weights (g*w); summ_d = g_d*(sum_t W'_t h_raw - S) + b_d, W'=w_t*i_t.

__global__ __launch_bounds__(128) void k_pre(
    const float* __restrict__ x,
    const float* __restrict__ conv_w, const float* __restrict__ conv_b,
    const float* __restrict__ ln1_g,  const float* __restrict__ ln1_b,
    const float* __restrict__ ca1_w,  const float* __restrict__ ca1_b,
    const float* __restrict__ ca2_w,  const float* __restrict__ ca2_b,
    const float* __restrict__ pp_w,   const float* __restrict__ pp_b,
    const float* __restrict__ ep_w,   const float* __restrict__ ep_b,
    float* __restrict__ csb_g)
{
  __shared__ float hbuf[kCHUNK][132];
  __shared__ __align__(16) float Bu[640];  // part[18][32]=576 | summ[128]+wl[17]
  __shared__ float mrow[kCHUNK], irow[kCHUNK];

  float (*part)[32] = (float(*)[32])Bu;  // rows 0..15: D; 16: G; 17: B
  float* summ = Bu;                      // [128] (part dead by then)
  float* wl   = Bu + 128;                // [17]: W'[16], S

  const int tid   = threadIdx.x;
  const int chunk = blockIdx.x;
  const int b     = chunk >> 7;
  const int nc    = chunk & 127;
  const int t0    = nc * kCHUNK;
  const int d     = tid;
  const int j     = tid & 31;
  const int sub   = tid >> 5;

  // ---- early loads ----
  float w12[12];
  {
    const float4* cw = (const float4*)(conv_w + d * 12);
    float4 a0 = cw[0], a1 = cw[1], a2 = cw[2];
    w12[0]=a0.x; w12[1]=a0.y; w12[2]=a0.z; w12[3]=a0.w;
    w12[4]=a1.x; w12[5]=a1.y; w12[6]=a1.z; w12[7]=a1.w;
    w12[8]=a2.x; w12[9]=a2.y; w12[10]=a2.z; w12[11]=a2.w;
  }
  float cb = conv_b[d];
  float g1 = ln1_g[d], b1 = ln1_b[d];
  float wreg[32];
  float pG = 0.f, pB = 0.f;
  {
    const float* wp = ca1_w + (sub * 32) * 32 + j;
#pragma unroll
    for (int k = 0; k < 32; ++k) wreg[k] = wp[k * 32];
    const float4* gp = (const float4*)(ln1_g + sub * 32);
    const float4* bp = (const float4*)(ln1_b + sub * 32);
#pragma unroll
    for (int q = 0; q < 8; ++q) {
      float4 gv = gp[q], bv = bp[q];
      pB = fmaf(bv.x, wreg[q*4+0], pB); pB = fmaf(bv.y, wreg[q*4+1], pB);
      pB = fmaf(bv.z, wreg[q*4+2], pB); pB = fmaf(bv.w, wreg[q*4+3], pB);
      wreg[q*4+0] *= gv.x; wreg[q*4+1] *= gv.y;
      wreg[q*4+2] *= gv.z; wreg[q*4+3] *= gv.w;
      pG += wreg[q*4+0] + wreg[q*4+1] + wreg[q*4+2] + wreg[q*4+3];
    }
  }

  // ---- conv1d from global (R8 verified) -> raw h regs + hbuf ----
  float h[kCHUNK];
#pragma unroll
  for (int t = 0; t < kCHUNK; ++t) h[t] = cb;
#pragma unroll
  for (int ch = 0; ch < kCH; ++ch) {
    const float* xb = x + ((size_t)b * kCH + ch) * kSEQ + t0 - 4;
    float xv[24];
#pragma unroll
    for (int sl = 1; sl <= 4; ++sl) {
      float4 v = *(const float4*)(xb + sl * 4);
      xv[sl*4+0]=v.x; xv[sl*4+1]=v.y; xv[sl*4+2]=v.z; xv[sl*4+3]=v.w;
    }
    if (nc > 0) {
      float4 v = *(const float4*)(xb);
      xv[0]=v.x; xv[1]=v.y; xv[2]=v.z; xv[3]=v.w;
    } else { xv[0]=xv[1]=xv[2]=xv[3]=0.f; }
    if (nc < 127) {
      float4 v = *(const float4*)(xb + 20);
      xv[20]=v.x; xv[21]=v.y; xv[22]=v.z; xv[23]=v.w;
    } else { xv[20]=xv[21]=xv[22]=xv[23]=0.f; }
    float c0 = w12[ch*3+0], c1 = w12[ch*3+1], c2 = w12[ch*3+2];
#pragma unroll
    for (int t = 0; t < kCHUNK; ++t)
      h[t] = fmaf(xv[t+3], c0, fmaf(xv[t+4], c1, fmaf(xv[t+5], c2, h[t])));
  }
#pragma unroll
  for (int t = 0; t < kCHUNK; ++t) hbuf[t][d] = h[t];
  __syncthreads();                                   // barrier 1

  // ---- LN1 stats (reads RAW hbuf) ----
  {
    int row = tid >> 3, k = tid & 7;
    const float4* rp = (const float4*)&hbuf[row][k * 16];
    float s1 = 0.f, s2 = 0.f;
#pragma unroll
    for (int q = 0; q < 4; ++q) {
      float4 v = rp[q];
      s1 += v.x + v.y + v.z + v.w;
      s2 = fmaf(v.x,v.x,s2); s2 = fmaf(v.y,v.y,s2);
      s2 = fmaf(v.z,v.z,s2); s2 = fmaf(v.w,v.w,s2);
    }
#pragma unroll
    for (int o = 1; o < 8; o <<= 1) {
      s1 += __shfl_xor(s1, o, 64);
      s2 += __shfl_xor(s2, o, 64);
    }
    if (k == 0) {
      float m = s1 * (1.f / kDM);
      mrow[row] = m;
      irow[row] = rsqrtf(s2 * (1.f / kDM) - m * m + 1e-5f);
    }
  }

  // ---- GEMV over RAW hbuf with g-scaled weights (no barrier needed:
  //      hbuf unchanged since barrier 1; mrow/irow consumed after barrier 2)
  float p[kCHUNK];
#pragma unroll
  for (int t = 0; t < kCHUNK; ++t) {
    float acc = 0.f;
#pragma unroll
    for (int qq = 0; qq < 8; ++qq) {
      int q = (qq + 2 * sub) & 7;
      float4 v = *(const float4*)&hbuf[t][sub * 32 + q * 4];
      acc = fmaf(v.x, wreg[q*4+0], acc);
      acc = fmaf(v.y, wreg[q*4+1], acc);
      acc = fmaf(v.z, wreg[q*4+2], acc);
      acc = fmaf(v.w, wreg[q*4+3], acc);
    }
    p[t] = acc;
  }
#pragma unroll
  for (int t = 0; t < kCHUNK; ++t) p[t] += __shfl_xor(p[t], 32, 64);
  pG += __shfl_xor(pG, 32, 64);
  pB += __shfl_xor(pB, 32, 64);
  if (sub == 2) {
#pragma unroll
    for (int t = 0; t < kCHUNK; ++t) part[t][j] = p[t];
    part[16][j] = pG;
    part[17][j] = pB;
  }
  __syncthreads();                                   // barrier 2

  // ---- wave0: LN-corrected hid, scores, softmax, W'/S ----
  if (tid < 64) {
    float bj = ca1_b[j], w2 = ca2_w[j];
    float G  = pG + part[16][j];
    float Bc = pB + part[17][j];
#pragma unroll
    for (int t = 0; t < kCHUNK; ++t) {
      float Dt = p[t] + part[t][j];
      p[t] = fast_tanh(fmaf(irow[t], Dt - mrow[t] * G, Bc) + bj) * w2;
    }
#pragma unroll
    for (int o = 16; o; o >>= 1)
#pragma unroll
      for (int t = 0; t < kCHUNK; ++t) p[t] += __shfl_xor(p[t], o, 64);
    float mx = p[0];
#pragma unroll
    for (int t = 1; t < kCHUNK; ++t) mx = fmaxf(mx, p[t]);
    float e[kCHUNK], ssum = 0.f;
#pragma unroll
    for (int t = 0; t < kCHUNK; ++t) { e[t] = __expf(p[t] - mx); ssum += e[t]; }
    float inv = 1.f / ssum;
    if (tid == 0) {
      float wv[kCHUNK], S = 0.f;
#pragma unroll
      for (int t = 0; t < kCHUNK; ++t) {
        wv[t] = e[t] * inv * irow[t];
        S = fmaf(wv[t], mrow[t], S);
      }
      float4* w4 = (float4*)wl;
      w4[0] = make_float4(wv[0],  wv[1],  wv[2],  wv[3]);
      w4[1] = make_float4(wv[4],  wv[5],  wv[6],  wv[7]);
      w4[2] = make_float4(wv[8],  wv[9],  wv[10], wv[11]);
      w4[3] = make_float4(wv[12], wv[13], wv[14], wv[15]);
      wl[16] = S;
    }
  }
  __syncthreads();                                   // barrier 3

  // ---- summ from RAW h regs + LN fold ----
  {
    float acc = 0.f;
    const float4* w4 = (const float4*)wl;
#pragma unroll
    for (int tq = 0; tq < 4; ++tq) {
      float4 wv = w4[tq];
      acc = fmaf(wv.x, h[tq*4+0], acc);
      acc = fmaf(wv.y, h[tq*4+1], acc);
      acc = fmaf(wv.z, h[tq*4+2], acc);
      acc = fmaf(wv.w, h[tq*4+3], acc);
    }
    float S = wl[16];
    summ[d] = fmaf(g1, acc - S, b1);
  }
  __syncthreads();                                   // barrier 4

  // ---- projections -> HALF-angles to global (R8 verified) ----
  if (tid < kNP) {
    float acc = pp_b[tid];
    const float4* s4 = (const float4*)summ;
#pragma unroll 8
    for (int q = 0; q < 32; ++q) {
      float4 v = s4[q];
      acc = fmaf(v.x, pp_w[(q*4+0)*kNP + tid], acc);
      acc = fmaf(v.y, pp_w[(q*4+1)*kNP + tid], acc);
      acc = fmaf(v.z, pp_w[(q*4+2)*kNP + tid], acc);
      acc = fmaf(v.w, pp_w[(q*4+3)*kNP + tid], acc);
    }
    csb_g[(size_t)chunk * 126 + 6 + tid] = 0.5f * acc;
  } else if (tid < kNP + kNQ) {
    int jj = tid - kNP;
    float acc = ep_b[jj];
    const float4* s4 = (const float4*)summ;
#pragma unroll 8
    for (int q = 0; q < 32; ++q) {
      float4 v = s4[q];
      acc = fmaf(v.x, ep_w[(q*4+0)*kNQ + jj], acc);
      acc = fmaf(v.y, ep_w[(q*4+1)*kNQ + jj], acc);
      acc = fmaf(v.z, ep_w[(q*4+2)*kNQ + jj], acc);
      acc = fmaf(v.w, ep_w[(q*4+3)*kNQ + jj], acc);
    }
    float a = fast_tanh(acc) * kPI;
    csb_g[(size_t)chunk * 126 + jj] = 0.5f * a;
  }
}

// ---------------------------------------------------------------------------
// k_circ: verbatim R8 (verified).

__global__ __launch_bounds__(64) void k_circ(const float* __restrict__ csb_g,
                                             float* __restrict__ qv_g)
{
  const int lane  = threadIdx.x;
  const int c     = lane >> 2;
  const int l     = lane & 3;
  const int chunk = blockIdx.x * 16 + c;
  const float* cp = csb_g + (size_t)chunk * 126;
  const int b0 = (l >> 1) & 1;
  const int b1 = l & 1;

  float sr[16], si[16];
#pragma unroll
  for (int r = 0; r < 16; ++r) { sr[r] = 0.f; si[r] = 0.f; }
  sr[0] = (l == 0) ? 1.f : 0.f;

  {
    float gc[6], gs[6];
#pragma unroll
    for (int g = 0; g < 6; ++g) { float th = cp[g]; gc[g] = __cosf(th); gs[g] = __sinf(th); }
    ry_lane<2>(gc[0], b0 ? gs[0] : -gs[0], sr, si);
    ry_lane<1>(gc[1], b1 ? gs[1] : -gs[1], sr, si);
    ry_reg<8>(gc[2], gs[2], sr, si);
    ry_reg<4>(gc[3], gs[3], sr, si);
    ry_reg<2>(gc[4], gs[4], sr, si);
    ry_reg<1>(gc[5], gs[5], sr, si);
  }

  for (int a = 0; a < 4; ++a) {
    const float* pb = cp + 6 + a * 30;
    float gc[30], gs[30];
#pragma unroll
    for (int g = 0; g < 30; ++g) { float th = pb[g]; gc[g] = __cosf(th); gs[g] = __sinf(th); }
    rx_lane<2>(gc[0], gs[0], sr, si);
    ry_lane<2>(gc[1], b0 ? gs[1] : -gs[1], sr, si);
    rz_lane   (gc[2], b0 ? gs[2] : -gs[2], sr, si);
    rx_lane<1>(gc[3], gs[3], sr, si);
    ry_lane<1>(gc[4], b1 ? gs[4] : -gs[4], sr, si);
    rz_lane   (gc[5], b1 ? gs[5] : -gs[5], sr, si);
    rx_reg<8>(gc[6],  gs[6],  sr, si);  ry_reg<8>(gc[7],  gs[7],  sr, si);  rz_reg<8>(gc[8],  gs[8],  sr, si);
    rx_reg<4>(gc[9],  gs[9],  sr, si);  ry_reg<4>(gc[10], gs[10], sr, si);  rz_reg<4>(gc[11], gs[11], sr, si);
    rx_reg<2>(gc[12], gs[12], sr, si);  ry_reg<2>(gc[13], gs[13], sr, si);  rz_reg<2>(gc[14], gs[14], sr, si);
    rx_reg<1>(gc[15], gs[15], sr, si);  ry_reg<1>(gc[16], gs[16], sr, si);  rz_reg<1>(gc[17], gs[17], sr, si);
    { float c2 = b0 ? gc[18] : 1.f, s2 = b0 ? gs[18] : 0.f; rx_lane<1>(c2, s2, sr, si); }
    { float c2 = b1 ? gc[19] : 1.f, s2 = b1 ? gs[19] : 0.f; rx_reg<8>(c2, s2, sr, si); }
    crx_reg_reg<4, 8>(gc[20], gs[20], sr, si);
    crx_reg_reg<2, 4>(gc[21], gs[21], sr, si);
    crx_reg_reg<1, 2>(gc[22], gs[22], sr, si);
    crx_reg_lane<2, 1>(gc[23], gs[23], sr, si);
    crx_reg_reg<2, 1>(gc[24], gs[24], sr, si);
    crx_reg_reg<4, 2>(gc[25], gs[25], sr, si);
    crx_reg_reg<8, 4>(gc[26], gs[26], sr, si);
    crx_reg_lane<1, 8>(gc[27], gs[27], sr, si);
    { float c2 = b1 ? gc[28] : 1.f, s2 = b1 ? gs[28] : 0.f; rx_lane<2>(c2, s2, sr, si); }
    { float c2 = b0 ? gc[29] : 1.f, s2 = b0 ? gs[29] : 0.f; rx_reg<1>(c2, s2, sr, si); }
  }

  float res[18];
  {
    float tr = 0.f, ti = 0.f, zz = 0.f;
#pragma unroll
    for (int r = 0; r < 16; ++r) {
      float pr = qp<2>(sr[r]), pi = qp<2>(si[r]);
      tr = fmaf(sr[r], pr, fmaf(si[r], pi, tr));
      ti = fmaf(sr[r], pi, fmaf(-si[r], pr, ti));
      zz = fmaf(sr[r], sr[r], fmaf(si[r], si[r], zz));
    }
    tr = b0 ? 0.f : tr;  ti = b0 ? 0.f : ti;  zz = b0 ? -zz : zz;
    tr += qp<1>(tr); tr += qp<2>(tr);
    ti += qp<1>(ti); ti += qp<2>(ti);
    zz += qp<1>(zz); zz += qp<2>(zz);
    res[0] = 2.f * tr; res[6] = 2.f * ti; res[12] = zz;
  }
  {
    float tr = 0.f, ti = 0.f, zz = 0.f;
#pragma unroll
    for (int r = 0; r < 16; ++r) {
      float pr = qp<1>(sr[r]), pi = qp<1>(si[r]);
      tr = fmaf(sr[r], pr, fmaf(si[r], pi, tr));
      ti = fmaf(sr[r], pi, fmaf(-si[r], pr, ti));
      zz = fmaf(sr[r], sr[r], fmaf(si[r], si[r], zz));
    }
    tr = b1 ? 0.f : tr;  ti = b1 ? 0.f : ti;  zz = b1 ? -zz : zz;
    tr += qp<1>(tr); tr += qp<2>(tr);
    ti += qp<1>(ti); ti += qp<2>(ti);
    zz += qp<1>(zz); zz += qp<2>(zz);
    res[1] = 2.f * tr; res[7] = 2.f * ti; res[13] = zz;
  }
  {
    float tr, ti, zz;
    meas_reg<8>(sr, si, tr, ti, zz); res[2] = 2.f*tr; res[8]  = 2.f*ti; res[14] = zz;
    meas_reg<4>(sr, si, tr, ti, zz); res[3] = 2.f*tr; res[9]  = 2.f*ti; res[15] = zz;
    meas_reg<2>(sr, si, tr, ti, zz); res[4] = 2.f*tr; res[10] = 2.f*ti; res[16] = zz;
    meas_reg<1>(sr, si, tr, ti, zz); res[5] = 2.f*tr; res[11] = 2.f*ti; res[17] = zz;
  }
  if (l == 0) {
    float* qo = qv_g + (size_t)chunk * 18;
#pragma unroll
    for (int k = 0; k < 18; ++k) qo[k] = res[k];
  }
}

// ---------------------------------------------------------------------------
// k_post8: 8 chunks per block — weights loaded once, reused 8x.

__global__ __launch_bounds__(128) void k_post8(
    const float* __restrict__ qv_g,
    const float* __restrict__ op_w, const float* __restrict__ op_b,
    const float* __restrict__ ln2_g, const float* __restrict__ ln2_b,
    const float* __restrict__ sa1_w, const float* __restrict__ sa1_b,
    const float* __restrict__ sa2_w, const float* __restrict__ sa2_b,
    float* __restrict__ cf, float* __restrict__ sclb)
{
  __shared__ float cfs[132];
  __shared__ float part1[32];
  __shared__ float red[4];

  const int tid = threadIdx.x, d = tid;
  const int j = tid & 31, sub = tid >> 5;
  const int c0 = blockIdx.x * 8;

  float ow[18];
#pragma unroll
  for (int k = 0; k < 18; ++k) ow[k] = op_w[k * kDM + d];
  float g2 = ln2_g[d], b2 = ln2_b[d], ob = op_b[d];
  float swreg[32];
  {
    const float* wp2 = sa1_w + (sub * 32) * 32 + j;
#pragma unroll
    for (int k = 0; k < 32; ++k) swreg[k] = wp2[k * 32];
  }
  float sb1 = sa1_b[j], sw2 = sa2_w[j], sb2 = sa2_b[0];

  for (int c = 0; c < 8; ++c) {
    const int chunk = c0 + c;
    const float* qpp = qv_g + (size_t)chunk * 18;
    float acc = ob;
#pragma unroll
    for (int k = 0; k < 18; ++k) acc = fmaf(qpp[k], ow[k], acc);

    float v = acc, v2 = acc * acc;
#pragma unroll
    for (int o = 32; o; o >>= 1) { v += __shfl_xor(v, o, 64); v2 += __shfl_xor(v2, o, 64); }
    if ((tid & 63) == 0) { red[tid >> 6] = v; red[2 + (tid >> 6)] = v2; }
    __syncthreads();
    float s1 = red[0] + red[1], s2 = red[2] + red[3];
    float m = s1 * (1.f / kDM);
    float var = s2 * (1.f / kDM) - m * m;
    float xn = fmaf((acc - m) * rsqrtf(var + 1e-5f), g2, b2);
    float cfv = fast_silu(xn);
    cf[(size_t)chunk * kDM + d] = cfv;
    cfs[d] = cfv;
    __syncthreads();

    float acc2 = 0.f;
#pragma unroll
    for (int q = 0; q < 8; ++q) {
      float4 hv = *(const float4*)&cfs[sub * 32 + q * 4];
      acc2 = fmaf(hv.x, swreg[q*4+0], acc2);
      acc2 = fmaf(hv.y, swreg[q*4+1], acc2);
      acc2 = fmaf(hv.z, swreg[q*4+2], acc2);
      acc2 = fmaf(hv.w, swreg[q*4+3], acc2);
    }
    acc2 += __shfl_xor(acc2, 32, 64);
    if (sub == 2) part1[j] = acc2;
    __syncthreads();
    if (tid < 32) {
      float hv = fast_tanh(acc2 + part1[j] + sb1) * sw2;
#pragma unroll
      for (int o = 16; o; o >>= 1) hv += __shfl_xor(hv, o, 64);
      if (j == 0) sclb[chunk] = hv + sb2;
    }
    __syncthreads();   // protect red/cfs/part1 for next chunk
  }
}

// ---------------------------------------------------------------------------
// k_rpart / k_final: verbatim R8.

__global__ __launch_bounds__(128) void k_rpart(
    const float* __restrict__ cf, const float* __restrict__ sclb,
    float* __restrict__ rep_part)
{
  __shared__ float wl[kNCH];
  __shared__ float red2[2];

  const int blk = blockIdx.x, tid = threadIdx.x;
  const int b = blk >> 3, sl = blk & 7;

  float s = sclb[b * kNCH + tid];
  float mx = s;
#pragma unroll
  for (int o = 32; o; o >>= 1) mx = fmaxf(mx, __shfl_xor(mx, o, 64));
  if ((tid & 63) == 0) red2[tid >> 6] = mx;
  __syncthreads();
  mx = fmaxf(red2[0], red2[1]);
  wl[tid] = __expf(s - mx);
  __syncthreads();

  const float* cfb = cf + ((size_t)b * kNCH + sl * 16) * kDM;
  const float* wls = wl + sl * 16;
  float a0 = 0.f, a1 = 0.f, a2 = 0.f, a3 = 0.f;
#pragma unroll
  for (int k = 0; k < 16; k += 4) {
    a0 = fmaf(wls[k+0], cfb[(k+0) * kDM + tid], a0);
    a1 = fmaf(wls[k+1], cfb[(k+1) * kDM + tid], a1);
    a2 = fmaf(wls[k+2], cfb[(k+2) * kDM + tid], a2);
    a3 = fmaf(wls[k+3], cfb[(k+3) * kDM + tid], a3);
  }
  rep_part[(size_t)blk * kDM + tid] = (a0 + a1) + (a2 + a3);
}

__global__ __launch_bounds__(128) void k_final(
    const float* __restrict__ rep_part, const float* __restrict__ sclb,
    const float* __restrict__ cl1_w, const float* __restrict__ cl1_b,
    const float* __restrict__ cl2_w, const float* __restrict__ cl2_b,
    float* __restrict__ out)
{
  __shared__ float summ[132];
  __shared__ float up[64];
  __shared__ float ul[64];
  __shared__ float red2[4];

  const int b = blockIdx.x, tid = threadIdx.x;
  float s = sclb[b * kNCH + tid];
  float mx = s;
#pragma unroll
  for (int o = 32; o; o >>= 1) mx = fmaxf(mx, __shfl_xor(mx, o, 64));
  if ((tid & 63) == 0) red2[tid >> 6] = mx;
  __syncthreads();
  mx = fmaxf(red2[0], red2[1]);
  float e = __expf(s - mx);
  float se = e;
#pragma unroll
  for (int o = 32; o; o >>= 1) se += __shfl_xor(se, o, 64);
  if ((tid & 63) == 0) red2[2 + (tid >> 6)] = se;
  __syncthreads();
  float inv = 1.f / (red2[2] + red2[3]);

  float rp = 0.f;
#pragma unroll
  for (int p8 = 0; p8 < 8; ++p8) rp += rep_part[((size_t)b * 8 + p8) * kDM + tid];
  summ[tid] = rp * inv;
  __syncthreads();

  {
    int jj = tid & 63, half = tid >> 6;
    float acc = 0.f;
#pragma unroll
    for (int q = 0; q < 16; ++q) {
      float4 v = *(const float4*)&summ[half * 64 + q * 4];
      acc = fmaf(v.x, cl1_w[(half*64 + q*4 + 0) * 64 + jj], acc);
      acc = fmaf(v.y, cl1_w[(half*64 + q*4 + 1) * 64 + jj], acc);
      acc = fmaf(v.z, cl1_w[(half*64 + q*4 + 2) * 64 + jj], acc);
      acc = fmaf(v.w, cl1_w[(half*64 + q*4 + 3) * 64 + jj], acc);
    }
    if (half == 1) up[jj] = acc;
    __syncthreads();
    if (half == 0) ul[jj] = fast_silu(acc + up[jj] + cl1_b[jj]);
  }
  __syncthreads();

  if (tid < 2) {
    float acc = cl2_b[tid];
#pragma unroll
    for (int k = 0; k < 64; ++k) acc = fmaf(ul[k], cl2_w[k * 2 + tid], acc);
    out[b * 2 + tid] = acc;
  }
}

// ===========================================================================
// FALLBACK (ws too small): verbatim R8 fallback pipeline.
// ===========================================================================

__device__ __forceinline__ void fb_rx(float2 cs, int w, int lane, float& ar, float& ai) {
  int m = 1 << (5 - w);
  float pr = __shfl_xor(ar, m, 64), pi = __shfl_xor(ai, m, 64);
  float nr = fmaf(cs.x, ar, cs.y * pi), ni = fmaf(cs.x, ai, -cs.y * pr);
  ar = nr; ai = ni;
}
__device__ __forceinline__ void fb_ry(float2 cs, int w, int lane, float& ar, float& ai) {
  int m = 1 << (5 - w);
  float pr = __shfl_xor(ar, m, 64), pi = __shfl_xor(ai, m, 64);
  float sg = ((lane >> (5 - w)) & 1) ? cs.y : -cs.y;
  float nr = fmaf(cs.x, ar, sg * pr), ni = fmaf(cs.x, ai, sg * pi);
  ar = nr; ai = ni;
}
__device__ __forceinline__ void fb_rz(float2 cs, int w, int lane, float& ar, float& ai) {
  float sp = ((lane >> (5 - w)) & 1) ? cs.y : -cs.y;
  float nr = fmaf(ar, cs.x, -ai * sp), ni = fmaf(ar, sp, ai * cs.x);
  ar = nr; ai = ni;
}
__device__ __forceinline__ void fb_crx(float2 cs, int w0, int w1, int lane, float& ar, float& ai) {
  int m = 1 << (5 - w1);
  float pr = __shfl_xor(ar, m, 64), pi = __shfl_xor(ai, m, 64);
  if ((lane >> (5 - w0)) & 1) {
    float nr = fmaf(cs.x, ar, cs.y * pi), ni = fmaf(cs.x, ai, -cs.y * pr);
    ar = nr; ai = ni;
  }
}
__device__ __forceinline__ void fb_ansatz(const float2* cs, int lane, float& ar, float& ai) {
#pragma unroll
  for (int i = 0; i < kNQ; ++i) {
    fb_rx(cs[3*i+0], i, lane, ar, ai);
    fb_ry(cs[3*i+1], i, lane, ar, ai);
    fb_rz(cs[3*i+2], i, lane, ar, ai);
  }
  int off = 18;
#pragma unroll
  for (int i = 0; i < kNQ; ++i) fb_crx(cs[off++], i, (i+1)%kNQ, lane, ar, ai);
#pragma unroll
  for (int i = kNQ-1; i >= 0; --i) fb_crx(cs[off++], i, (i+5)%kNQ, lane, ar, ai);
}

__global__ __launch_bounds__(128) void k_chunk_fb(
    const float* __restrict__ x,
    const float* __restrict__ conv_w, const float* __restrict__ conv_b,
    const float* __restrict__ ln1_g,  const float* __restrict__ ln1_b,
    const float* __restrict__ ca1_w,  const float* __restrict__ ca1_b,
    const float* __restrict__ ca2_w,  const float* __restrict__ ca2_b,
    const float* __restrict__ pp_w,   const float* __restrict__ pp_b,
    const float* __restrict__ ep_w,   const float* __restrict__ ep_b,
    const float* __restrict__ op_w,   const float* __restrict__ op_b,
    const float* __restrict__ ln2_g,  const float* __restrict__ ln2_b,
    float* __restrict__ cf)
{
  __shared__ float hbuf[kCHUNK][132];
  __shared__ __align__(16) float Bu[512];
  __shared__ float mrow[kCHUNK], irow[kCHUNK];
  __shared__ float red[4];
  float (*xs)[kCHUNK+2] = (float(*)[kCHUNK+2])Bu;
  float (*part)[32] = (float(*)[32])Bu;
  float* summ = Bu; float* wl = Bu + 128; float* qv = Bu + 144;
  float2* csb = (float2*)(Bu + 164);

  const int tid = threadIdx.x, chunk = blockIdx.x;
  const int b = chunk >> 7, nc = chunk & 127, t0 = nc * kCHUNK, d = tid;
  const int j = tid & 31, sub = tid >> 5;

  float w12[12];
  {
    const float4* cw = (const float4*)(conv_w + d*12);
    float4 a0=cw[0],a1=cw[1],a2=cw[2];
    w12[0]=a0.x;w12[1]=a0.y;w12[2]=a0.z;w12[3]=a0.w;
    w12[4]=a1.x;w12[5]=a1.y;w12[6]=a1.z;w12[7]=a1.w;
    w12[8]=a2.x;w12[9]=a2.y;w12[10]=a2.z;w12[11]=a2.w;
  }
  float cb = conv_b[d], g1 = ln1_g[d], b1 = ln1_b[d];
  float wreg[32];
  { const float* wp = ca1_w + (sub*32)*32 + j;
#pragma unroll
    for (int k = 0; k < 32; ++k) wreg[k] = wp[k*32]; }

  if (tid < kCH*(kCHUNK+2)) {
    int ch = tid/(kCHUNK+2), pos = tid%(kCHUNK+2), s = t0-1+pos;
    float v = 0.f; if (s >= 0 && s < kSEQ) v = x[(b*kCH+ch)*kSEQ + s];
    xs[ch][pos] = v;
  }
  __syncthreads();
#pragma unroll
  for (int t = 0; t < kCHUNK; ++t) {
    float acc = cb;
#pragma unroll
    for (int ch = 0; ch < kCH; ++ch)
#pragma unroll
      for (int k = 0; k < 3; ++k) acc = fmaf(xs[ch][t+k], w12[ch*3+k], acc);
    hbuf[t][d] = acc;
  }
  __syncthreads();
  {
    int row = tid >> 3, k = tid & 7;
    const float4* rp = (const float4*)&hbuf[row][k*16];
    float s1 = 0.f, s2 = 0.f;
#pragma unroll
    for (int q = 0; q < 4; ++q) {
      float4 v = rp[q];
      s1 += v.x+v.y+v.z+v.w;
      s2 = fmaf(v.x,v.x,s2); s2 = fmaf(v.y,v.y,s2);
      s2 = fmaf(v.z,v.z,s2); s2 = fmaf(v.w,v.w,s2);
    }
#pragma unroll
    for (int o = 1; o < 8; o <<= 1) { s1 += __shfl_xor(s1,o,64); s2 += __shfl_xor(s2,o,64); }
    if (k == 0) {
      float m = s1*(1.f/kDM);
      mrow[row] = m; irow[row] = rsqrtf(s2*(1.f/kDM) - m*m + 1e-5f);
    }
  }
  __syncthreads();
#pragma unroll
  for (int t = 0; t < kCHUNK; ++t)
    hbuf[t][d] = fmaf((hbuf[t][d]-mrow[t])*irow[t], g1, b1);
  __syncthreads();
  float p[kCHUNK];
#pragma unroll
  for (int t = 0; t < kCHUNK; ++t) {
    float acc = 0.f;
#pragma unroll
    for (int qq = 0; qq < 8; ++qq) {
      int q = (qq + 2*sub) & 7;
      float4 v = *(const float4*)&hbuf[t][sub*32 + q*4];
      acc = fmaf(v.x,wreg[q*4+0],acc); acc = fmaf(v.y,wreg[q*4+1],acc);
      acc = fmaf(v.z,wreg[q*4+2],acc); acc = fmaf(v.w,wreg[q*4+3],acc);
    }
    p[t] = acc;
  }
#pragma unroll
  for (int t = 0; t < kCHUNK; ++t) p[t] += __shfl_xor(p[t], 32, 64);
  if (sub == 2) {
#pragma unroll
    for (int t = 0; t < kCHUNK; ++t) part[t][j] = p[t];
  }
  __syncthreads();
  if (tid < 64) {
    float bj = ca1_b[j], w2 = ca2_w[j];
#pragma unroll
    for (int t = 0; t < kCHUNK; ++t) p[t] = fast_tanh(p[t] + part[t][j] + bj) * w2;
#pragma unroll
    for (int o = 16; o; o >>= 1)
#pragma unroll
      for (int t = 0; t < kCHUNK; ++t) p[t] += __shfl_xor(p[t], o, 64);
    float mx = p[0];
#pragma unroll
    for (int t = 1; t < kCHUNK; ++t) mx = fmaxf(mx, p[t]);
    float e[kCHUNK], ssum = 0.f;
#pragma unroll
    for (int t = 0; t < kCHUNK; ++t) { e[t] = __expf(p[t]-mx); ssum += e[t]; }
    float inv = 1.f/ssum;
    if (tid == 0) {
      float4* w4 = (float4*)wl;
      w4[0]=make_float4(e[0]*inv,e[1]*inv,e[2]*inv,e[3]*inv);
      w4[1]=make_float4(e[4]*inv,e[5]*inv,e[6]*inv,e[7]*inv);
      w4[2]=make_float4(e[8]*inv,e[9]*inv,e[10]*inv,e[11]*inv);
      w4[3]=make_float4(e[12]*inv,e[13]*inv,e[14]*inv,e[15]*inv);
    }
  }
  __syncthreads();
  {
    float acc = 0.f;
    const float4* w4 = (const float4*)wl;
#pragma unroll
    for (int tq = 0; tq < 4; ++tq) {
      float4 wv = w4[tq];
      acc = fmaf(wv.x,hbuf[tq*4+0][d],acc); acc = fmaf(wv.y,hbuf[tq*4+1][d],acc);
      acc = fmaf(wv.z,hbuf[tq*4+2][d],acc); acc = fmaf(wv.w,hbuf[tq*4+3][d],acc);
    }
    summ[d] = acc;
  }
  __syncthreads();
  if (tid < kNP) {
    float acc = pp_b[tid];
    const float4* s4 = (const float4*)summ;
#pragma unroll 8
    for (int q = 0; q < 32; ++q) {
      float4 v = s4[q];
      acc = fmaf(v.x,pp_w[(q*4+0)*kNP+tid],acc); acc = fmaf(v.y,pp_w[(q*4+1)*kNP+tid],acc);
      acc = fmaf(v.z,pp_w[(q*4+2)*kNP+tid],acc); acc = fmaf(v.w,pp_w[(q*4+3)*kNP+tid],acc);
    }
    csb[6+tid] = make_float2(__cosf(0.5f*acc), __sinf(0.5f*acc));
  } else if (tid < kNP + kNQ) {
    int jj = tid - kNP;
    float acc = ep_b[jj];
    for (int dd = 0; dd < kDM; ++dd) acc = fmaf(summ[dd], ep_w[dd*kNQ+jj], acc);
    float a = fast_tanh(acc) * kPI;
    csb[jj] = make_float2(__cosf(0.5f*a), __sinf(0.5f*a));
  }
  float ow[18];
#pragma unroll
  for (int jj = 0; jj < 18; ++jj) ow[jj] = op_w[jj*kDM + d];
  float g2 = ln2_g[d], b2 = ln2_b[d], ob = op_b[d];
  __syncthreads();
  if (tid < 64) {
    int lane = tid;
    float ar = (lane == 0) ? 1.f : 0.f, ai = 0.f;
#pragma unroll
    for (int i = 0; i < kNQ; ++i) fb_ry(csb[i], i, lane, ar, ai);
    fb_ansatz(csb+6, lane, ar, ai);  fb_ansatz(csb+36, lane, ar, ai);
    fb_ansatz(csb+66, lane, ar, ai); fb_ansatz(csb+96, lane, ar, ai);
#pragma unroll
    for (int i = 0; i < kNQ; ++i) {
      int m = 1 << (5-i);
      float pr = __shfl_xor(ar, m, 64), pi = __shfl_xor(ai, m, 64);
      int bit = (lane >> (5-i)) & 1;
      float nrm = fmaf(ar,ar,ai*ai);
      float abr, abi, zz;
      if (bit) { abr = 0.f; abi = 0.f; zz = -nrm; }
      else { abr = fmaf(ar,pr,ai*pi); abi = fmaf(ar,pi,-ai*pr); zz = nrm; }
#pragma unroll
      for (int o = 32; o; o >>= 1) {
        abr += __shfl_xor(abr,o,64); abi += __shfl_xor(abi,o,64); zz += __shfl_xor(zz,o,64);
      }
      if (lane == 0) { qv[i] = 2.f*abr; qv[kNQ+i] = 2.f*abi; qv[2*kNQ+i] = zz; }
    }
  }
  __syncthreads();
  {
    float acc = ob;
#pragma unroll
    for (int jj = 0; jj < 18; ++jj) acc = fmaf(qv[jj], ow[jj], acc);
    float v = acc, v2 = acc*acc;
#pragma unroll
    for (int o = 32; o; o >>= 1) { v += __shfl_xor(v,o,64); v2 += __shfl_xor(v2,o,64); }
    if ((tid & 63) == 0) { red[tid>>6] = v; red[2+(tid>>6)] = v2; }
    __syncthreads();
    float s1 = red[0]+red[1], s2 = red[2]+red[3];
    float m = s1*(1.f/kDM), var = s2*(1.f/kDM) - m*m;
    float xn = fmaf((acc-m)*rsqrtf(var+1e-5f), g2, b2);
    cf[(size_t)chunk*kDM + d] = fast_silu(xn);
  }
}

__global__ __launch_bounds__(256) void k_scl_fb(
    const float* __restrict__ cf,
    const float* __restrict__ sa1_w, const float* __restrict__ sa1_b,
    const float* __restrict__ sa2_w, const float* __restrict__ sa2_b,
    float* __restrict__ scl)
{
  int tid = threadIdx.x, wid = tid >> 6, lane = tid & 63;
  int pair = blockIdx.x * 4 + wid;
  int j = lane & 31, hh = lane >> 5;
  const float4* row = (const float4*)(cf + (size_t)pair*kDM + hh*64);
  const float* wp = sa1_w + (hh*64)*32 + j;
  float acc = 0.f;
#pragma unroll
  for (int q = 0; q < 16; ++q) {
    float4 v = row[q];
    acc = fmaf(v.x,wp[(q*4+0)*32],acc); acc = fmaf(v.y,wp[(q*4+1)*32],acc);
    acc = fmaf(v.z,wp[(q*4+2)*32],acc); acc = fmaf(v.w,wp[(q*4+3)*32],acc);
  }
  acc += __shfl_xor(acc, 32, 64);
  float hv = fast_tanh(acc + sa1_b[j]);
  float v = hv * sa2_w[j];
#pragma unroll
  for (int o = 16; o; o >>= 1) v += __shfl_xor(v, o, 64);
  if (lane == 0) scl[pair] = v + sa2_b[0];
}

__global__ __launch_bounds__(512) void k_pool_cf(
    const float* __restrict__ cf, const float* __restrict__ scl,
    const float* __restrict__ cl1_w, const float* __restrict__ cl1_b,
    const float* __restrict__ cl2_w, const float* __restrict__ cl2_b,
    float* __restrict__ out)
{
  __shared__ float wl[kNCH];
  __shared__ float rep4[4][kDM];
  __shared__ float ulp[8][64];
  __shared__ float ul[64];
  __shared__ float red2[16];
  int b = blockIdx.x, tid = threadIdx.x;
  int idx = tid & 127, wid = tid >> 6;
  float s = scl[b*kNCH + idx];
  float mx = s;
#pragma unroll
  for (int o = 32; o; o >>= 1) mx = fmaxf(mx, __shfl_xor(mx,o,64));
  if ((tid & 63) == 0) red2[wid] = mx;
  __syncthreads();
  mx = fmaxf(red2[0], red2[1]);
  float e = __expf(s - mx);
  float se = e;
#pragma unroll
  for (int o = 32; o; o >>= 1) se += __shfl_xor(se,o,64);
  if ((tid & 63) == 0) red2[8+wid] = se;
  if (tid < kNCH) wl[tid] = e;
  __syncthreads();
  float inv = 1.f/(red2[8]+red2[9]);
  {
    int dd = tid & 127, qq = tid >> 7;
    const float* cfb = cf + (size_t)b*kNCH*kDM + (size_t)qq*32*kDM;
    const float* wlq = wl + qq*32;
    float a0=0,a1=0,a2=0,a3=0;
#pragma unroll 4
    for (int ncc = 0; ncc < 32; ncc += 4) {
      a0 = fmaf(wlq[ncc+0], cfb[(ncc+0)*kDM+dd], a0);
      a1 = fmaf(wlq[ncc+1], cfb[(ncc+1)*kDM+dd], a1);
      a2 = fmaf(wlq[ncc+2], cfb[(ncc+2)*kDM+dd], a2);
      a3 = fmaf(wlq[ncc+3], cfb[(ncc+3)*kDM+dd], a3);
    }
    rep4[qq][dd] = (a0+a1)+(a2+a3);
  }
  __syncthreads();
  {
    int jj = tid & 63, qq = tid >> 6;
    float accp = 0.f;
#pragma unroll
    for (int k = 0; k < 16; ++k) {
      int dd = qq*16 + k;
      float rv = ((rep4[0][dd]+rep4[1][dd])+(rep4[2][dd]+rep4[3][dd]))*inv;
      accp = fmaf(rv, cl1_w[dd*64+jj], accp);
    }
    ulp[qq][jj] = accp;
  }
  __syncthreads();
  if (tid < 64) {
    float acc = cl1_b[tid];
#pragma unroll
    for (int q = 0; q < 8; ++q) acc += ulp[q][tid];
    ul[tid] = fast_silu(acc);
  }
  __syncthreads();
  if (tid < 2) {
    float acc = cl2_b[tid];
#pragma unroll
    for (int k = 0; k < 64; ++k) acc = fmaf(ul[k], cl2_w[k*2+tid], acc);
    out[b*2+tid] = acc;
  }
}

// ---------------------------------------------------------------------------

extern "C" void kernel_launch(void* const* d_in, const int* in_sizes, int n_in,
                              void* d_out, int out_size, void* d_ws, size_t ws_size,
                              hipStream_t stream) {
  const float* x      = (const float*)d_in[0];
  const float* conv_w = (const float*)d_in[1];
  const float* conv_b = (const float*)d_in[2];
  const float* ln1_g  = (const float*)d_in[3];
  const float* ln1_b  = (const float*)d_in[4];
  const float* ca1_w  = (const float*)d_in[5];
  const float* ca1_b  = (const float*)d_in[6];
  const float* ca2_w  = (const float*)d_in[7];
  const float* ca2_b  = (const float*)d_in[8];
  const float* pp_w   = (const float*)d_in[9];
  const float* pp_b   = (const float*)d_in[10];
  const float* ep_w   = (const float*)d_in[11];
  const float* ep_b   = (const float*)d_in[12];
  const float* op_w   = (const float*)d_in[13];
  const float* op_b   = (const float*)d_in[14];
  const float* ln2_g  = (const float*)d_in[15];
  const float* ln2_b  = (const float*)d_in[16];
  const float* sa1_w  = (const float*)d_in[17];
  const float* sa1_b  = (const float*)d_in[18];
  const float* sa2_w  = (const float*)d_in[19];
  const float* sa2_b  = (const float*)d_in[20];
  const float* cl1_w  = (const float*)d_in[21];
  const float* cl1_b  = (const float*)d_in[22];
  const float* cl2_w  = (const float*)d_in[23];
  const float* cl2_b  = (const float*)d_in[24];
  float* out = (float*)d_out;

  const size_t nch = (size_t)kBATCH * kNCH;  // 16384
  const size_t fA    = nch * kDM;            // csb (126f) / cf (128f) aliased
  const size_t need  = (fA + nch * 18 + nch + 1024 * kDM) * sizeof(float);

  if (ws_size >= need) {
    float* A     = (float*)d_ws;
    float* qv_g  = A + fA;
    float* sclb  = qv_g + nch * 18;
    float* rpart = sclb + nch;
    k_pre<<<kBATCH * kNCH, 128, 0, stream>>>(
        x, conv_w, conv_b, ln1_g, ln1_b, ca1_w, ca1_b, ca2_w, ca2_b,
        pp_w, pp_b, ep_w, ep_b, A);
    k_circ<<<(kBATCH * kNCH) / 16, 64, 0, stream>>>(A, qv_g);
    k_post8<<<(kBATCH * kNCH) / 8, 128, 0, stream>>>(
        qv_g, op_w, op_b, ln2_g, ln2_b, sa1_w, sa1_b, sa2_w, sa2_b, A, sclb);
    k_rpart<<<kBATCH * 8, 128, 0, stream>>>(A, sclb, rpart);
    k_final<<<kBATCH, 128, 0, stream>>>(rpart, sclb, cl1_w, cl1_b, cl2_w, cl2_b, out);
  } else {
    float* cf   = (float*)d_ws;
    float* sclb = cf + nch * kDM;
    k_chunk_fb<<<kBATCH * kNCH, 128, 0, stream>>>(
        x, conv_w, conv_b, ln1_g, ln1_b, ca1_w, ca1_b, ca2_w, ca2_b,
        pp_w, pp_b, ep_w, ep_b, op_w, op_b, ln2_g, ln2_b, cf);
    k_scl_fb<<<(kBATCH * kNCH) / 4, 256, 0, stream>>>(cf, sa1_w, sa1_b, sa2_w, sa2_b, sclb);
    k_pool_cf<<<kBATCH, 512, 0, stream>>>(cf, sclb, cl1_w, cl1_b, cl2_w, cl2_b, out);
  }
}

// Round 10
// 229.105 us; speedup vs baseline: 1.5200x; 1.5200x over previous
//
#include <hip/hip_runtime.h>
#include <math.h>

// ---------------------------------------------------------------------------
// QuantumTransformerE2E on MI355X — R10.
// R8 pipeline (best: 311 µs) with ONE change: k_pre's chunk-attention GEMV
// (16x32x128) now uses mfma_f32_16x16x32_bf16 with split-bf16 inputs
// (h = hi+lo; 3-term product => ~fp32 accuracy). A-frags are distinct-address
// ds_read_b128: 8 reads/wave replace 128 broadcast reads. Softmax goes
// all-thread-redundant from spart[2][16] (drops the 64-shfl tree + wl LDS).
// R9's LN-fold and k_post8 reverted (occupancy loss / serialization loss).
// ---------------------------------------------------------------------------

constexpr int kNQ    = 6;
constexpr int kDM    = 128;
constexpr int kCH    = 4;
constexpr int kSEQ   = 2048;
constexpr int kCHUNK = 16;
constexpr int kBATCH = 128;
constexpr int kNCH   = kSEQ / kCHUNK;  // 128
constexpr int kNP    = 120;
constexpr float kPI  = 3.14159265358979323846f;

typedef __attribute__((ext_vector_type(8))) short bf16x8;
typedef __attribute__((ext_vector_type(4))) float f32x4;

__device__ __forceinline__ float fast_tanh(float x) {
  float e = __expf(-2.f * fabsf(x));
  float r = (1.f - e) * __builtin_amdgcn_rcpf(1.f + e);
  return copysignf(r, x);
}
__device__ __forceinline__ float fast_silu(float x) {
  return x * __builtin_amdgcn_rcpf(1.f + __expf(-x));
}

// quad_perm DPP helpers (VALU pipe).
template <int XM>
__device__ __forceinline__ float qp(float v) {
  constexpr int ctrl = (XM == 1) ? 0xB1 : 0x4E;
  return __int_as_float(
      __builtin_amdgcn_update_dpp(0, __float_as_int(v), ctrl, 0xF, 0xF, true));
}

// ---- register-resident 6-qubit gates (verified R8) ------------------------

template <int RB>
__device__ __forceinline__ void rx_reg(float c, float s, float* sr, float* si) {
#pragma unroll
  for (int r0 = 0; r0 < 16; ++r0) {
    if (r0 & RB) continue;
    int r1 = r0 | RB;
    float ar = sr[r0], ai = si[r0], br = sr[r1], bi = si[r1];
    sr[r0] = fmaf(c, ar,  s * bi);  si[r0] = fmaf(c, ai, -s * br);
    sr[r1] = fmaf(c, br,  s * ai);  si[r1] = fmaf(c, bi, -s * ar);
  }
}

template <int RB>
__device__ __forceinline__ void ry_reg(float c, float s, float* sr, float* si) {
#pragma unroll
  for (int r0 = 0; r0 < 16; ++r0) {
    if (r0 & RB) continue;
    int r1 = r0 | RB;
    float ar = sr[r0], ai = si[r0], br = sr[r1], bi = si[r1];
    sr[r0] = fmaf(c, ar, -s * br);  si[r0] = fmaf(c, ai, -s * bi);
    sr[r1] = fmaf(s, ar,  c * br);  si[r1] = fmaf(s, ai,  c * bi);
  }
}

template <int RB>
__device__ __forceinline__ void rz_reg(float c, float s, float* sr, float* si) {
#pragma unroll
  for (int r = 0; r < 16; ++r) {
    float sp = (r & RB) ? s : -s;
    float ar = sr[r], ai = si[r];
    sr[r] = fmaf(c, ar, -sp * ai);
    si[r] = fmaf(c, ai,  sp * ar);
  }
}

template <int XM>
__device__ __forceinline__ void rx_lane(float c, float s, float* sr, float* si) {
#pragma unroll
  for (int r = 0; r < 16; ++r) {
    float pr = qp<XM>(sr[r]), pi = qp<XM>(si[r]);
    sr[r] = fmaf(c, sr[r],  s * pi);
    si[r] = fmaf(c, si[r], -s * pr);
  }
}

template <int XM>
__device__ __forceinline__ void ry_lane(float c, float sg, float* sr, float* si) {
#pragma unroll
  for (int r = 0; r < 16; ++r) {
    float pr = qp<XM>(sr[r]), pi = qp<XM>(si[r]);
    sr[r] = fmaf(c, sr[r], sg * pr);
    si[r] = fmaf(c, si[r], sg * pi);
  }
}

__device__ __forceinline__ void rz_lane(float c, float sp, float* sr, float* si) {
#pragma unroll
  for (int r = 0; r < 16; ++r) {
    float ar = sr[r], ai = si[r];
    sr[r] = fmaf(c, ar, -sp * ai);
    si[r] = fmaf(c, ai,  sp * ar);
  }
}

template <int RB, int CB>
__device__ __forceinline__ void crx_reg_reg(float c, float s, float* sr, float* si) {
#pragma unroll
  for (int r0 = 0; r0 < 16; ++r0) {
    if ((r0 & RB) || !(r0 & CB)) continue;
    int r1 = r0 | RB;
    float ar = sr[r0], ai = si[r0], br = sr[r1], bi = si[r1];
    sr[r0] = fmaf(c, ar,  s * bi);  si[r0] = fmaf(c, ai, -s * br);
    sr[r1] = fmaf(c, br,  s * ai);  si[r1] = fmaf(c, bi, -s * ar);
  }
}

template <int XM, int CB>
__device__ __forceinline__ void crx_reg_lane(float c, float s, float* sr, float* si) {
#pragma unroll
  for (int r = 0; r < 16; ++r) {
    if (!(r & CB)) continue;
    float pr = qp<XM>(sr[r]), pi = qp<XM>(si[r]);
    sr[r] = fmaf(c, sr[r],  s * pi);
    si[r] = fmaf(c, si[r], -s * pr);
  }
}

template <int RB>
__device__ __forceinline__ void meas_reg(const float* sr, const float* si,
                                         float& tr, float& ti, float& zz) {
  tr = 0.f; ti = 0.f; zz = 0.f;
#pragma unroll
  for (int r0 = 0; r0 < 16; ++r0) {
    float n = fmaf(sr[r0], sr[r0], si[r0] * si[r0]);
    zz += (r0 & RB) ? -n : n;
    if (r0 & RB) continue;
    int r1 = r0 | RB;
    tr = fmaf(sr[r0], sr[r1], fmaf(si[r0], si[r1], tr));
    ti = fmaf(sr[r0], si[r1], fmaf(-si[r0], sr[r1], ti));
  }
  tr += qp<1>(tr); tr += qp<2>(tr);
  ti += qp<1>(ti); ti += qp<2>(ti);
  zz += qp<1>(zz); zz += qp<2>(zz);
}

// ---------------------------------------------------------------------------
// k_pre: conv(global) + LN1 + MFMA chunk attention + projections -> csb_g.

__global__ __launch_bounds__(128) void k_pre(
    const float* __restrict__ x,
    const float* __restrict__ conv_w, const float* __restrict__ conv_b,
    const float* __restrict__ ln1_g,  const float* __restrict__ ln1_b,
    const float* __restrict__ ca1_w,  const float* __restrict__ ca1_b,
    const float* __restrict__ ca2_w,  const float* __restrict__ ca2_b,
    const float* __restrict__ pp_w,   const float* __restrict__ pp_b,
    const float* __restrict__ ep_w,   const float* __restrict__ ep_b,
    float* __restrict__ csb_g)
{
  __shared__ float hbuf[kCHUNK][132];           // fp32 raw, then (hi,lo) packed
  __shared__ __align__(16) float spart[2][16];  // per-wave score partials
  __shared__ __align__(16) float summ[kDM];
  __shared__ float mrow[kCHUNK], irow[kCHUNK];

  const int tid   = threadIdx.x;
  const int chunk = blockIdx.x;
  const int b     = chunk >> 7;
  const int nc    = chunk & 127;
  const int t0    = nc * kCHUNK;
  const int d     = tid;
  const int lane  = tid & 63;
  const int wv    = tid >> 6;                   // wave id = N-tile id
  const int col   = (lane & 15) + 16 * wv;      // j column 0..31
  const int qd    = lane >> 4;                  // 0..3

  // ---- early loads (fly under conv) ----
  float w12[12];
  {
    const float4* cw = (const float4*)(conv_w + d * 12);
    float4 a0 = cw[0], a1 = cw[1], a2 = cw[2];
    w12[0]=a0.x; w12[1]=a0.y; w12[2]=a0.z; w12[3]=a0.w;
    w12[4]=a1.x; w12[5]=a1.y; w12[6]=a1.z; w12[7]=a1.w;
    w12[8]=a2.x; w12[9]=a2.y; w12[10]=a2.z; w12[11]=a2.w;
  }
  float cb = conv_b[d];
  float g1 = ln1_g[d], b1 = ln1_b[d];
  // B fragments (ca1_w), fp32 staged: B[k=ks*32+qd*8+j][n=col]
  float Bf[32];
#pragma unroll
  for (int ks = 0; ks < 4; ++ks)
#pragma unroll
    for (int jj = 0; jj < 8; ++jj)
      Bf[ks * 8 + jj] = ca1_w[(ks * 32 + qd * 8 + jj) * 32 + col];
  float cb1 = ca1_b[col], cw2 = ca2_w[col], cb2 = ca2_b[0];

  // ---- conv1d from global (R8 verified) -> raw h regs + hbuf fp32 ----
  float h[kCHUNK];
#pragma unroll
  for (int t = 0; t < kCHUNK; ++t) h[t] = cb;
#pragma unroll
  for (int ch = 0; ch < kCH; ++ch) {
    const float* xb = x + ((size_t)b * kCH + ch) * kSEQ + t0 - 4;
    float xv[24];
#pragma unroll
    for (int sl = 1; sl <= 4; ++sl) {
      float4 v = *(const float4*)(xb + sl * 4);
      xv[sl*4+0]=v.x; xv[sl*4+1]=v.y; xv[sl*4+2]=v.z; xv[sl*4+3]=v.w;
    }
    if (nc > 0) {
      float4 v = *(const float4*)(xb);
      xv[0]=v.x; xv[1]=v.y; xv[2]=v.z; xv[3]=v.w;
    } else { xv[0]=xv[1]=xv[2]=xv[3]=0.f; }
    if (nc < 127) {
      float4 v = *(const float4*)(xb + 20);
      xv[20]=v.x; xv[21]=v.y; xv[22]=v.z; xv[23]=v.w;
    } else { xv[20]=xv[21]=xv[22]=xv[23]=0.f; }
    float c0 = w12[ch*3+0], c1 = w12[ch*3+1], c2 = w12[ch*3+2];
#pragma unroll
    for (int t = 0; t < kCHUNK; ++t)
      h[t] = fmaf(xv[t+3], c0, fmaf(xv[t+4], c1, fmaf(xv[t+5], c2, h[t])));
  }
#pragma unroll
  for (int t = 0; t < kCHUNK; ++t) hbuf[t][d] = h[t];
  __syncthreads();                                   // B1

  // ---- LN1 stats (R8 verified) ----
  {
    int row = tid >> 3, k = tid & 7;
    const float4* rp = (const float4*)&hbuf[row][k * 16];
    float s1 = 0.f, s2 = 0.f;
#pragma unroll
    for (int q = 0; q < 4; ++q) {
      float4 v = rp[q];
      s1 += v.x + v.y + v.z + v.w;
      s2 = fmaf(v.x,v.x,s2); s2 = fmaf(v.y,v.y,s2);
      s2 = fmaf(v.z,v.z,s2); s2 = fmaf(v.w,v.w,s2);
    }
#pragma unroll
    for (int o = 1; o < 8; o <<= 1) {
      s1 += __shfl_xor(s1, o, 64);
      s2 += __shfl_xor(s2, o, 64);
    }
    if (k == 0) {
      float m = s1 * (1.f / kDM);
      mrow[row] = m;
      irow[row] = rsqrtf(s2 * (1.f / kDM) - m * m + 1e-5f);
    }
  }
  __syncthreads();                                   // B2

  // ---- LN1 apply in regs + write (hi,lo) bf16 pair per element ----
#pragma unroll
  for (int t = 0; t < kCHUNK; ++t) {
    h[t] = fmaf((h[t] - mrow[t]) * irow[t], g1, b1);
    unsigned hb = __float_as_uint(h[t]);
    float lof = h[t] - __uint_as_float(hb & 0xffff0000u);
    unsigned pk = (hb >> 16) | (__float_as_uint(lof) & 0xffff0000u);
    ((unsigned*)&hbuf[t][0])[d] = pk;
  }
  __syncthreads();                                   // B3

  // ---- split B into bf16 hi/lo fragment vectors ----
  bf16x8 bhi[4], blo[4];
#pragma unroll
  for (int ks = 0; ks < 4; ++ks)
#pragma unroll
    for (int jj = 0; jj < 8; ++jj) {
      float bvf = Bf[ks * 8 + jj];
      unsigned bb = __float_as_uint(bvf);
      bhi[ks][jj] = (short)(bb >> 16);
      float lf = bvf - __uint_as_float(bb & 0xffff0000u);
      blo[ks][jj] = (short)(__float_as_uint(lf) >> 16);
    }

  // ---- MFMA GEMV: C[16][16] per wave, K=128 in 4 steps, 3-term split ----
  f32x4 acc = {0.f, 0.f, 0.f, 0.f};
  {
    const unsigned* hrow = (const unsigned*)&hbuf[lane & 15][0];
#pragma unroll
    for (int ks = 0; ks < 4; ++ks) {
      const uint4* ap = (const uint4*)(hrow + ks * 32 + qd * 8);
      uint4 w0 = ap[0], w1 = ap[1];
      bf16x8 ahi, alo;
      ahi[0] = (short)(w0.x & 0xffff); ahi[1] = (short)(w0.y & 0xffff);
      ahi[2] = (short)(w0.z & 0xffff); ahi[3] = (short)(w0.w & 0xffff);
      ahi[4] = (short)(w1.x & 0xffff); ahi[5] = (short)(w1.y & 0xffff);
      ahi[6] = (short)(w1.z & 0xffff); ahi[7] = (short)(w1.w & 0xffff);
      alo[0] = (short)(w0.x >> 16); alo[1] = (short)(w0.y >> 16);
      alo[2] = (short)(w0.z >> 16); alo[3] = (short)(w0.w >> 16);
      alo[4] = (short)(w1.x >> 16); alo[5] = (short)(w1.y >> 16);
      alo[6] = (short)(w1.z >> 16); alo[7] = (short)(w1.w >> 16);
      acc = __builtin_amdgcn_mfma_f32_16x16x32_bf16(ahi, bhi[ks], acc, 0, 0, 0);
      acc = __builtin_amdgcn_mfma_f32_16x16x32_bf16(ahi, blo[ks], acc, 0, 0, 0);
      acc = __builtin_amdgcn_mfma_f32_16x16x32_bf16(alo, bhi[ks], acc, 0, 0, 0);
    }
  }

  // ---- tanh + ca2 weighting in C-layout, reduce over j (16 lanes) ----
  {
    float ev[4];
#pragma unroll
    for (int r = 0; r < 4; ++r)
      ev[r] = fast_tanh(acc[r] + cb1) * cw2;
#pragma unroll
    for (int o = 1; o < 16; o <<= 1)
#pragma unroll
      for (int r = 0; r < 4; ++r) ev[r] += __shfl_xor(ev[r], o, 64);
    if ((lane & 15) == 0)
      *(float4*)&spart[wv][qd * 4] = make_float4(ev[0], ev[1], ev[2], ev[3]);
  }
  __syncthreads();                                   // B4

  // ---- all-thread redundant softmax + weighted sum from h regs ----
  {
    float scl16[kCHUNK];
    const float4* s0 = (const float4*)&spart[0][0];
    const float4* s1 = (const float4*)&spart[1][0];
    float mx = -1e30f;
#pragma unroll
    for (int g = 0; g < 4; ++g) {
      float4 a = s0[g], bq = s1[g];
      scl16[g*4+0] = a.x + bq.x + cb2;
      scl16[g*4+1] = a.y + bq.y + cb2;
      scl16[g*4+2] = a.z + bq.z + cb2;
      scl16[g*4+3] = a.w + bq.w + cb2;
    }
#pragma unroll
    for (int t = 0; t < kCHUNK; ++t) mx = fmaxf(mx, scl16[t]);
    float e[kCHUNK], ssum = 0.f;
#pragma unroll
    for (int t = 0; t < kCHUNK; ++t) { e[t] = __expf(scl16[t] - mx); ssum += e[t]; }
    float inv = 1.f / ssum;
    float acc2 = 0.f;
#pragma unroll
    for (int t = 0; t < kCHUNK; ++t) acc2 = fmaf(e[t] * inv, h[t], acc2);
    summ[d] = acc2;
  }
  __syncthreads();                                   // B5

  // ---- projections -> HALF-angles to global (R8 verified) ----
  if (tid < kNP) {
    float acc = pp_b[tid];
    const float4* s4 = (const float4*)summ;
#pragma unroll 8
    for (int q = 0; q < 32; ++q) {
      float4 v = s4[q];
      acc = fmaf(v.x, pp_w[(q*4+0)*kNP + tid], acc);
      acc = fmaf(v.y, pp_w[(q*4+1)*kNP + tid], acc);
      acc = fmaf(v.z, pp_w[(q*4+2)*kNP + tid], acc);
      acc = fmaf(v.w, pp_w[(q*4+3)*kNP + tid], acc);
    }
    csb_g[(size_t)chunk * 126 + 6 + tid] = 0.5f * acc;
  } else if (tid < kNP + kNQ) {
    int jj = tid - kNP;
    float acc = ep_b[jj];
    const float4* s4 = (const float4*)summ;
#pragma unroll 8
    for (int q = 0; q < 32; ++q) {
      float4 v = s4[q];
      acc = fmaf(v.x, ep_w[(q*4+0)*kNQ + jj], acc);
      acc = fmaf(v.y, ep_w[(q*4+1)*kNQ + jj], acc);
      acc = fmaf(v.z, ep_w[(q*4+2)*kNQ + jj], acc);
      acc = fmaf(v.w, ep_w[(q*4+3)*kNQ + jj], acc);
    }
    float a = fast_tanh(acc) * kPI;
    csb_g[(size_t)chunk * 126 + jj] = 0.5f * a;
  }
}

// ---------------------------------------------------------------------------
// k_circ: verbatim R8 (verified).

__global__ __launch_bounds__(64) void k_circ(const float* __restrict__ csb_g,
                                             float* __restrict__ qv_g)
{
  const int lane  = threadIdx.x;
  const int c     = lane >> 2;
  const int l     = lane & 3;
  const int chunk = blockIdx.x * 16 + c;
  const float* cp = csb_g + (size_t)chunk * 126;
  const int b0 = (l >> 1) & 1;
  const int b1 = l & 1;

  float sr[16], si[16];
#pragma unroll
  for (int r = 0; r < 16; ++r) { sr[r] = 0.f; si[r] = 0.f; }
  sr[0] = (l == 0) ? 1.f : 0.f;

  {
    float gc[6], gs[6];
#pragma unroll
    for (int g = 0; g < 6; ++g) { float th = cp[g]; gc[g] = __cosf(th); gs[g] = __sinf(th); }
    ry_lane<2>(gc[0], b0 ? gs[0] : -gs[0], sr, si);
    ry_lane<1>(gc[1], b1 ? gs[1] : -gs[1], sr, si);
    ry_reg<8>(gc[2], gs[2], sr, si);
    ry_reg<4>(gc[3], gs[3], sr, si);
    ry_reg<2>(gc[4], gs[4], sr, si);
    ry_reg<1>(gc[5], gs[5], sr, si);
  }

  for (int a = 0; a < 4; ++a) {
    const float* pb = cp + 6 + a * 30;
    float gc[30], gs[30];
#pragma unroll
    for (int g = 0; g < 30; ++g) { float th = pb[g]; gc[g] = __cosf(th); gs[g] = __sinf(th); }
    rx_lane<2>(gc[0], gs[0], sr, si);
    ry_lane<2>(gc[1], b0 ? gs[1] : -gs[1], sr, si);
    rz_lane   (gc[2], b0 ? gs[2] : -gs[2], sr, si);
    rx_lane<1>(gc[3], gs[3], sr, si);
    ry_lane<1>(gc[4], b1 ? gs[4] : -gs[4], sr, si);
    rz_lane   (gc[5], b1 ? gs[5] : -gs[5], sr, si);
    rx_reg<8>(gc[6],  gs[6],  sr, si);  ry_reg<8>(gc[7],  gs[7],  sr, si);  rz_reg<8>(gc[8],  gs[8],  sr, si);
    rx_reg<4>(gc[9],  gs[9],  sr, si);  ry_reg<4>(gc[10], gs[10], sr, si);  rz_reg<4>(gc[11], gs[11], sr, si);
    rx_reg<2>(gc[12], gs[12], sr, si);  ry_reg<2>(gc[13], gs[13], sr, si);  rz_reg<2>(gc[14], gs[14], sr, si);
    rx_reg<1>(gc[15], gs[15], sr, si);  ry_reg<1>(gc[16], gs[16], sr, si);  rz_reg<1>(gc[17], gs[17], sr, si);
    { float c2 = b0 ? gc[18] : 1.f, s2 = b0 ? gs[18] : 0.f; rx_lane<1>(c2, s2, sr, si); }
    { float c2 = b1 ? gc[19] : 1.f, s2 = b1 ? gs[19] : 0.f; rx_reg<8>(c2, s2, sr, si); }
    crx_reg_reg<4, 8>(gc[20], gs[20], sr, si);
    crx_reg_reg<2, 4>(gc[21], gs[21], sr, si);
    crx_reg_reg<1, 2>(gc[22], gs[22], sr, si);
    crx_reg_lane<2, 1>(gc[23], gs[23], sr, si);
    crx_reg_reg<2, 1>(gc[24], gs[24], sr, si);
    crx_reg_reg<4, 2>(gc[25], gs[25], sr, si);
    crx_reg_reg<8, 4>(gc[26], gs[26], sr, si);
    crx_reg_lane<1, 8>(gc[27], gs[27], sr, si);
    { float c2 = b1 ? gc[28] : 1.f, s2 = b1 ? gs[28] : 0.f; rx_lane<2>(c2, s2, sr, si); }
    { float c2 = b0 ? gc[29] : 1.f, s2 = b0 ? gs[29] : 0.f; rx_reg<1>(c2, s2, sr, si); }
  }

  float res[18];
  {
    float tr = 0.f, ti = 0.f, zz = 0.f;
#pragma unroll
    for (int r = 0; r < 16; ++r) {
      float pr = qp<2>(sr[r]), pi = qp<2>(si[r]);
      tr = fmaf(sr[r], pr, fmaf(si[r], pi, tr));
      ti = fmaf(sr[r], pi, fmaf(-si[r], pr, ti));
      zz = fmaf(sr[r], sr[r], fmaf(si[r], si[r], zz));
    }
    tr = b0 ? 0.f : tr;  ti = b0 ? 0.f : ti;  zz = b0 ? -zz : zz;
    tr += qp<1>(tr); tr += qp<2>(tr);
    ti += qp<1>(ti); ti += qp<2>(ti);
    zz += qp<1>(zz); zz += qp<2>(zz);
    res[0] = 2.f * tr; res[6] = 2.f * ti; res[12] = zz;
  }
  {
    float tr = 0.f, ti = 0.f, zz = 0.f;
#pragma unroll
    for (int r = 0; r < 16; ++r) {
      float pr = qp<1>(sr[r]), pi = qp<1>(si[r]);
      tr = fmaf(sr[r], pr, fmaf(si[r], pi, tr));
      ti = fmaf(sr[r], pi, fmaf(-si[r], pr, ti));
      zz = fmaf(sr[r], sr[r], fmaf(si[r], si[r], zz));
    }
    tr = b1 ? 0.f : tr;  ti = b1 ? 0.f : ti;  zz = b1 ? -zz : zz;
    tr += qp<1>(tr); tr += qp<2>(tr);
    ti += qp<1>(ti); ti += qp<2>(ti);
    zz += qp<1>(zz); zz += qp<2>(zz);
    res[1] = 2.f * tr; res[7] = 2.f * ti; res[13] = zz;
  }
  {
    float tr, ti, zz;
    meas_reg<8>(sr, si, tr, ti, zz); res[2] = 2.f*tr; res[8]  = 2.f*ti; res[14] = zz;
    meas_reg<4>(sr, si, tr, ti, zz); res[3] = 2.f*tr; res[9]  = 2.f*ti; res[15] = zz;
    meas_reg<2>(sr, si, tr, ti, zz); res[4] = 2.f*tr; res[10] = 2.f*ti; res[16] = zz;
    meas_reg<1>(sr, si, tr, ti, zz); res[5] = 2.f*tr; res[11] = 2.f*ti; res[17] = zz;
  }
  if (l == 0) {
    float* qo = qv_g + (size_t)chunk * 18;
#pragma unroll
    for (int k = 0; k < 18; ++k) qo[k] = res[k];
  }
}

// ---------------------------------------------------------------------------
// k_post: verbatim R8 (one chunk per block — wide beats looped, R9 lesson).

__global__ __launch_bounds__(128) void k_post(
    const float* __restrict__ qv_g,
    const float* __restrict__ op_w, const float* __restrict__ op_b,
    const float* __restrict__ ln2_g, const float* __restrict__ ln2_b,
    const float* __restrict__ sa1_w, const float* __restrict__ sa1_b,
    const float* __restrict__ sa2_w, const float* __restrict__ sa2_b,
    float* __restrict__ cf, float* __restrict__ sclb)
{
  __shared__ float cfs[132];
  __shared__ float part1[32];
  __shared__ float red[4];

  const int chunk = blockIdx.x, tid = threadIdx.x, d = tid;
  const int j = tid & 31, sub = tid >> 5;

  float qv[18];
  {
    const float* qpp = qv_g + (size_t)chunk * 18;
#pragma unroll
    for (int k = 0; k < 18; ++k) qv[k] = qpp[k];
  }
  float acc = op_b[d];
#pragma unroll
  for (int k = 0; k < 18; ++k) acc = fmaf(qv[k], op_w[k * kDM + d], acc);

  float v = acc, v2 = acc * acc;
#pragma unroll
  for (int o = 32; o; o >>= 1) { v += __shfl_xor(v, o, 64); v2 += __shfl_xor(v2, o, 64); }
  if ((tid & 63) == 0) { red[tid >> 6] = v; red[2 + (tid >> 6)] = v2; }
  __syncthreads();
  float s1 = red[0] + red[1], s2 = red[2] + red[3];
  float m = s1 * (1.f / kDM);
  float var = s2 * (1.f / kDM) - m * m;
  float xn = fmaf((acc - m) * rsqrtf(var + 1e-5f), ln2_g[d], ln2_b[d]);
  float cfv = fast_silu(xn);
  cf[(size_t)chunk * kDM + d] = cfv;
  cfs[d] = cfv;
  __syncthreads();

  float acc2 = 0.f;
  {
    const float* wp2 = sa1_w + (sub * 32) * 32 + j;
#pragma unroll
    for (int q = 0; q < 8; ++q) {
      float4 hv = *(const float4*)&cfs[sub * 32 + q * 4];
      acc2 = fmaf(hv.x, wp2[(q*4+0)*32], acc2);
      acc2 = fmaf(hv.y, wp2[(q*4+1)*32], acc2);
      acc2 = fmaf(hv.z, wp2[(q*4+2)*32], acc2);
      acc2 = fmaf(hv.w, wp2[(q*4+3)*32], acc2);
    }
  }
  acc2 += __shfl_xor(acc2, 32, 64);
  if (sub == 2) part1[j] = acc2;
  __syncthreads();
  if (tid < 32) {
    float hv = fast_tanh(acc2 + part1[j] + sa1_b[j]) * sa2_w[j];
#pragma unroll
    for (int o = 16; o; o >>= 1) hv += __shfl_xor(hv, o, 64);
    if (j == 0) sclb[chunk] = hv + sa2_b[0];
  }
}

// ---------------------------------------------------------------------------
// k_rpart / k_final: verbatim R8.

__global__ __launch_bounds__(128) void k_rpart(
    const float* __restrict__ cf, const float* __restrict__ sclb,
    float* __restrict__ rep_part)
{
  __shared__ float wl[kNCH];
  __shared__ float red2[2];

  const int blk = blockIdx.x, tid = threadIdx.x;
  const int b = blk >> 3, sl = blk & 7;

  float s = sclb[b * kNCH + tid];
  float mx = s;
#pragma unroll
  for (int o = 32; o; o >>= 1) mx = fmaxf(mx, __shfl_xor(mx, o, 64));
  if ((tid & 63) == 0) red2[tid >> 6] = mx;
  __syncthreads();
  mx = fmaxf(red2[0], red2[1]);
  wl[tid] = __expf(s - mx);
  __syncthreads();

  const float* cfb = cf + ((size_t)b * kNCH + sl * 16) * kDM;
  const float* wls = wl + sl * 16;
  float a0 = 0.f, a1 = 0.f, a2 = 0.f, a3 = 0.f;
#pragma unroll
  for (int k = 0; k < 16; k += 4) {
    a0 = fmaf(wls[k+0], cfb[(k+0) * kDM + tid], a0);
    a1 = fmaf(wls[k+1], cfb[(k+1) * kDM + tid], a1);
    a2 = fmaf(wls[k+2], cfb[(k+2) * kDM + tid], a2);
    a3 = fmaf(wls[k+3], cfb[(k+3) * kDM + tid], a3);
  }
  rep_part[(size_t)blk * kDM + tid] = (a0 + a1) + (a2 + a3);
}

__global__ __launch_bounds__(128) void k_final(
    const float* __restrict__ rep_part, const float* __restrict__ sclb,
    const float* __restrict__ cl1_w, const float* __restrict__ cl1_b,
    const float* __restrict__ cl2_w, const float* __restrict__ cl2_b,
    float* __restrict__ out)
{
  __shared__ float summ[132];
  __shared__ float up[64];
  __shared__ float ul[64];
  __shared__ float red2[4];

  const int b = blockIdx.x, tid = threadIdx.x;
  float s = sclb[b * kNCH + tid];
  float mx = s;
#pragma unroll
  for (int o = 32; o; o >>= 1) mx = fmaxf(mx, __shfl_xor(mx, o, 64));
  if ((tid & 63) == 0) red2[tid >> 6] = mx;
  __syncthreads();
  mx = fmaxf(red2[0], red2[1]);
  float e = __expf(s - mx);
  float se = e;
#pragma unroll
  for (int o = 32; o; o >>= 1) se += __shfl_xor(se, o, 64);
  if ((tid & 63) == 0) red2[2 + (tid >> 6)] = se;
  __syncthreads();
  float inv = 1.f / (red2[2] + red2[3]);

  float rp = 0.f;
#pragma unroll
  for (int p8 = 0; p8 < 8; ++p8) rp += rep_part[((size_t)b * 8 + p8) * kDM + tid];
  summ[tid] = rp * inv;
  __syncthreads();

  {
    int jj = tid & 63, half = tid >> 6;
    float acc = 0.f;
#pragma unroll
    for (int q = 0; q < 16; ++q) {
      float4 v = *(const float4*)&summ[half * 64 + q * 4];
      acc = fmaf(v.x, cl1_w[(half*64 + q*4 + 0) * 64 + jj], acc);
      acc = fmaf(v.y, cl1_w[(half*64 + q*4 + 1) * 64 + jj], acc);
      acc = fmaf(v.z, cl1_w[(half*64 + q*4 + 2) * 64 + jj], acc);
      acc = fmaf(v.w, cl1_w[(half*64 + q*4 + 3) * 64 + jj], acc);
    }
    if (half == 1) up[jj] = acc;
    __syncthreads();
    if (half == 0) ul[jj] = fast_silu(acc + up[jj] + cl1_b[jj]);
  }
  __syncthreads();

  if (tid < 2) {
    float acc = cl2_b[tid];
#pragma unroll
    for (int k = 0; k < 64; ++k) acc = fmaf(ul[k], cl2_w[k * 2 + tid], acc);
    out[b * 2 + tid] = acc;
  }
}

// ===========================================================================
// FALLBACK (ws too small): verbatim R8 fallback pipeline.
// ===========================================================================

__device__ __forceinline__ void fb_rx(float2 cs, int w, int lane, float& ar, float& ai) {
  int m = 1 << (5 - w);
  float pr = __shfl_xor(ar, m, 64), pi = __shfl_xor(ai, m, 64);
  float nr = fmaf(cs.x, ar, cs.y * pi), ni = fmaf(cs.x, ai, -cs.y * pr);
  ar = nr; ai = ni;
}
__device__ __forceinline__ void fb_ry(float2 cs, int w, int lane, float& ar, float& ai) {
  int m = 1 << (5 - w);
  float pr = __shfl_xor(ar, m, 64), pi = __shfl_xor(ai, m, 64);
  float sg = ((lane >> (5 - w)) & 1) ? cs.y : -cs.y;
  float nr = fmaf(cs.x, ar, sg * pr), ni = fmaf(cs.x, ai, sg * pi);
  ar = nr; ai = ni;
}
__device__ __forceinline__ void fb_rz(float2 cs, int w, int lane, float& ar, float& ai) {
  float sp = ((lane >> (5 - w)) & 1) ? cs.y : -cs.y;
  float nr = fmaf(ar, cs.x, -ai * sp), ni = fmaf(ar, sp, ai * cs.x);
  ar = nr; ai = ni;
}
__device__ __forceinline__ void fb_crx(float2 cs, int w0, int w1, int lane, float& ar, float& ai) {
  int m = 1 << (5 - w1);
  float pr = __shfl_xor(ar, m, 64), pi = __shfl_xor(ai, m, 64);
  if ((lane >> (5 - w0)) & 1) {
    float nr = fmaf(cs.x, ar, cs.y * pi), ni = fmaf(cs.x, ai, -cs.y * pr);
    ar = nr; ai = ni;
  }
}
__device__ __forceinline__ void fb_ansatz(const float2* cs, int lane, float& ar, float& ai) {
#pragma unroll
  for (int i = 0; i < kNQ; ++i) {
    fb_rx(cs[3*i+0], i, lane, ar, ai);
    fb_ry(cs[3*i+1], i, lane, ar, ai);
    fb_rz(cs[3*i+2], i, lane, ar, ai);
  }
  int off = 18;
#pragma unroll
  for (int i = 0; i < kNQ; ++i) fb_crx(cs[off++], i, (i+1)%kNQ, lane, ar, ai);
#pragma unroll
  for (int i = kNQ-1; i >= 0; --i) fb_crx(cs[off++], i, (i+5)%kNQ, lane, ar, ai);
}

__global__ __launch_bounds__(128) void k_chunk_fb(
    const float* __restrict__ x,
    const float* __restrict__ conv_w, const float* __restrict__ conv_b,
    const float* __restrict__ ln1_g,  const float* __restrict__ ln1_b,
    const float* __restrict__ ca1_w,  const float* __restrict__ ca1_b,
    const float* __restrict__ ca2_w,  const float* __restrict__ ca2_b,
    const float* __restrict__ pp_w,   const float* __restrict__ pp_b,
    const float* __restrict__ ep_w,   const float* __restrict__ ep_b,
    const float* __restrict__ op_w,   const float* __restrict__ op_b,
    const float* __restrict__ ln2_g,  const float* __restrict__ ln2_b,
    float* __restrict__ cf)
{
  __shared__ float hbuf[kCHUNK][132];
  __shared__ __align__(16) float Bu[512];
  __shared__ float mrow[kCHUNK], irow[kCHUNK];
  __shared__ float red[4];
  float (*xs)[kCHUNK+2] = (float(*)[kCHUNK+2])Bu;
  float (*part)[32] = (float(*)[32])Bu;
  float* summ = Bu; float* wl = Bu + 128; float* qv = Bu + 144;
  float2* csb = (float2*)(Bu + 164);

  const int tid = threadIdx.x, chunk = blockIdx.x;
  const int b = chunk >> 7, nc = chunk & 127, t0 = nc * kCHUNK, d = tid;
  const int j = tid & 31, sub = tid >> 5;

  float w12[12];
  {
    const float4* cw = (const float4*)(conv_w + d*12);
    float4 a0=cw[0],a1=cw[1],a2=cw[2];
    w12[0]=a0.x;w12[1]=a0.y;w12[2]=a0.z;w12[3]=a0.w;
    w12[4]=a1.x;w12[5]=a1.y;w12[6]=a1.z;w12[7]=a1.w;
    w12[8]=a2.x;w12[9]=a2.y;w12[10]=a2.z;w12[11]=a2.w;
  }
  float cb = conv_b[d], g1 = ln1_g[d], b1 = ln1_b[d];
  float wreg[32];
  { const float* wp = ca1_w + (sub*32)*32 + j;
#pragma unroll
    for (int k = 0; k < 32; ++k) wreg[k] = wp[k*32]; }

  if (tid < kCH*(kCHUNK+2)) {
    int ch = tid/(kCHUNK+2), pos = tid%(kCHUNK+2), s = t0-1+pos;
    float v = 0.f; if (s >= 0 && s < kSEQ) v = x[(b*kCH+ch)*kSEQ + s];
    xs[ch][pos] = v;
  }
  __syncthreads();
#pragma unroll
  for (int t = 0; t < kCHUNK; ++t) {
    float acc = cb;
#pragma unroll
    for (int ch = 0; ch < kCH; ++ch)
#pragma unroll
      for (int k = 0; k < 3; ++k) acc = fmaf(xs[ch][t+k], w12[ch*3+k], acc);
    hbuf[t][d] = acc;
  }
  __syncthreads();
  {
    int row = tid >> 3, k = tid & 7;
    const float4* rp = (const float4*)&hbuf[row][k*16];
    float s1 = 0.f, s2 = 0.f;
#pragma unroll
    for (int q = 0; q < 4; ++q) {
      float4 v = rp[q];
      s1 += v.x+v.y+v.z+v.w;
      s2 = fmaf(v.x,v.x,s2); s2 = fmaf(v.y,v.y,s2);
      s2 = fmaf(v.z,v.z,s2); s2 = fmaf(v.w,v.w,s2);
    }
#pragma unroll
    for (int o = 1; o < 8; o <<= 1) { s1 += __shfl_xor(s1,o,64); s2 += __shfl_xor(s2,o,64); }
    if (k == 0) {
      float m = s1*(1.f/kDM);
      mrow[row] = m; irow[row] = rsqrtf(s2*(1.f/kDM) - m*m + 1e-5f);
    }
  }
  __syncthreads();
#pragma unroll
  for (int t = 0; t < kCHUNK; ++t)
    hbuf[t][d] = fmaf((hbuf[t][d]-mrow[t])*irow[t], g1, b1);
  __syncthreads();
  float p[kCHUNK];
#pragma unroll
  for (int t = 0; t < kCHUNK; ++t) {
    float acc = 0.f;
#pragma unroll
    for (int qq = 0; qq < 8; ++qq) {
      int q = (qq + 2*sub) & 7;
      float4 v = *(const float4*)&hbuf[t][sub*32 + q*4];
      acc = fmaf(v.x,wreg[q*4+0],acc); acc = fmaf(v.y,wreg[q*4+1],acc);
      acc = fmaf(v.z,wreg[q*4+2],acc); acc = fmaf(v.w,wreg[q*4+3],acc);
    }
    p[t] = acc;
  }
#pragma unroll
  for (int t = 0; t < kCHUNK; ++t) p[t] += __shfl_xor(p[t], 32, 64);
  if (sub == 2) {
#pragma unroll
    for (int t = 0; t < kCHUNK; ++t) part[t][j] = p[t];
  }
  __syncthreads();
  if (tid < 64) {
    float bj = ca1_b[j], w2 = ca2_w[j];
#pragma unroll
    for (int t = 0; t < kCHUNK; ++t) p[t] = fast_tanh(p[t] + part[t][j] + bj) * w2;
#pragma unroll
    for (int o = 16; o; o >>= 1)
#pragma unroll
      for (int t = 0; t < kCHUNK; ++t) p[t] += __shfl_xor(p[t], o, 64);
    float mx = p[0];
#pragma unroll
    for (int t = 1; t < kCHUNK; ++t) mx = fmaxf(mx, p[t]);
    float e[kCHUNK], ssum = 0.f;
#pragma unroll
    for (int t = 0; t < kCHUNK; ++t) { e[t] = __expf(p[t]-mx); ssum += e[t]; }
    float inv = 1.f/ssum;
    if (tid == 0) {
      float4* w4 = (float4*)wl;
      w4[0]=make_float4(e[0]*inv,e[1]*inv,e[2]*inv,e[3]*inv);
      w4[1]=make_float4(e[4]*inv,e[5]*inv,e[6]*inv,e[7]*inv);
      w4[2]=make_float4(e[8]*inv,e[9]*inv,e[10]*inv,e[11]*inv);
      w4[3]=make_float4(e[12]*inv,e[13]*inv,e[14]*inv,e[15]*inv);
    }
  }
  __syncthreads();
  {
    float acc = 0.f;
    const float4* w4 = (const float4*)wl;
#pragma unroll
    for (int tq = 0; tq < 4; ++tq) {
      float4 wv = w4[tq];
      acc = fmaf(wv.x,hbuf[tq*4+0][d],acc); acc = fmaf(wv.y,hbuf[tq*4+1][d],acc);
      acc = fmaf(wv.z,hbuf[tq*4+2][d],acc); acc = fmaf(wv.w,hbuf[tq*4+3][d],acc);
    }
    summ[d] = acc;
  }
  __syncthreads();
  if (tid < kNP) {
    float acc = pp_b[tid];
    const float4* s4 = (const float4*)summ;
#pragma unroll 8
    for (int q = 0; q < 32; ++q) {
      float4 v = s4[q];
      acc = fmaf(v.x,pp_w[(q*4+0)*kNP+tid],acc); acc = fmaf(v.y,pp_w[(q*4+1)*kNP+tid],acc);
      acc = fmaf(v.z,pp_w[(q*4+2)*kNP+tid],acc); acc = fmaf(v.w,pp_w[(q*4+3)*kNP+tid],acc);
    }
    csb[6+tid] = make_float2(__cosf(0.5f*acc), __sinf(0.5f*acc));
  } else if (tid < kNP + kNQ) {
    int jj = tid - kNP;
    float acc = ep_b[jj];
    for (int dd = 0; dd < kDM; ++dd) acc = fmaf(summ[dd], ep_w[dd*kNQ+jj], acc);
    float a = fast_tanh(acc) * kPI;
    csb[jj] = make_float2(__cosf(0.5f*a), __sinf(0.5f*a));
  }
  float ow[18];
#pragma unroll
  for (int jj = 0; jj < 18; ++jj) ow[jj] = op_w[jj*kDM + d];
  float g2 = ln2_g[d], b2 = ln2_b[d], ob = op_b[d];
  __syncthreads();
  if (tid < 64) {
    int lane = tid;
    float ar = (lane == 0) ? 1.f : 0.f, ai = 0.f;
#pragma unroll
    for (int i = 0; i < kNQ; ++i) fb_ry(csb[i], i, lane, ar, ai);
    fb_ansatz(csb+6, lane, ar, ai);  fb_ansatz(csb+36, lane, ar, ai);
    fb_ansatz(csb+66, lane, ar, ai); fb_ansatz(csb+96, lane, ar, ai);
#pragma unroll
    for (int i = 0; i < kNQ; ++i) {
      int m = 1 << (5-i);
      float pr = __shfl_xor(ar, m, 64), pi = __shfl_xor(ai, m, 64);
      int bit = (lane >> (5-i)) & 1;
      float nrm = fmaf(ar,ar,ai*ai);
      float abr, abi, zz;
      if (bit) { abr = 0.f; abi = 0.f; zz = -nrm; }
      else { abr = fmaf(ar,pr,ai*pi); abi = fmaf(ar,pi,-ai*pr); zz = nrm; }
#pragma unroll
      for (int o = 32; o; o >>= 1) {
        abr += __shfl_xor(abr,o,64); abi += __shfl_xor(abi,o,64); zz += __shfl_xor(zz,o,64);
      }
      if (lane == 0) { qv[i] = 2.f*abr; qv[kNQ+i] = 2.f*abi; qv[2*kNQ+i] = zz; }
    }
  }
  __syncthreads();
  {
    float acc = ob;
#pragma unroll
    for (int jj = 0; jj < 18; ++jj) acc = fmaf(qv[jj], ow[jj], acc);
    float v = acc, v2 = acc*acc;
#pragma unroll
    for (int o = 32; o; o >>= 1) { v += __shfl_xor(v,o,64); v2 += __shfl_xor(v2,o,64); }
    if ((tid & 63) == 0) { red[tid>>6] = v; red[2+(tid>>6)] = v2; }
    __syncthreads();
    float s1 = red[0]+red[1], s2 = red[2]+red[3];
    float m = s1*(1.f/kDM), var = s2*(1.f/kDM) - m*m;
    float xn = fmaf((acc-m)*rsqrtf(var+1e-5f), g2, b2);
    cf[(size_t)chunk*kDM + d] = fast_silu(xn);
  }
}

__global__ __launch_bounds__(256) void k_scl_fb(
    const float* __restrict__ cf,
    const float* __restrict__ sa1_w, const float* __restrict__ sa1_b,
    const float* __restrict__ sa2_w, const float* __restrict__ sa2_b,
    float* __restrict__ scl)
{
  int tid = threadIdx.x, wid = tid >> 6, lane = tid & 63;
  int pair = blockIdx.x * 4 + wid;
  int j = lane & 31, hh = lane >> 5;
  const float4* row = (const float4*)(cf + (size_t)pair*kDM + hh*64);
  const float* wp = sa1_w + (hh*64)*32 + j;
  float acc = 0.f;
#pragma unroll
  for (int q = 0; q < 16; ++q) {
    float4 v = row[q];
    acc = fmaf(v.x,wp[(q*4+0)*32],acc); acc = fmaf(v.y,wp[(q*4+1)*32],acc);
    acc = fmaf(v.z,wp[(q*4+2)*32],acc); acc = fmaf(v.w,wp[(q*4+3)*32],acc);
  }
  acc += __shfl_xor(acc, 32, 64);
  float hv = fast_tanh(acc + sa1_b[j]);
  float v = hv * sa2_w[j];
#pragma unroll
  for (int o = 16; o; o >>= 1) v += __shfl_xor(v, o, 64);
  if (lane == 0) scl[pair] = v + sa2_b[0];
}

__global__ __launch_bounds__(512) void k_pool_cf(
    const float* __restrict__ cf, const float* __restrict__ scl,
    const float* __restrict__ cl1_w, const float* __restrict__ cl1_b,
    const float* __restrict__ cl2_w, const float* __restrict__ cl2_b,
    float* __restrict__ out)
{
  __shared__ float wl[kNCH];
  __shared__ float rep4[4][kDM];
  __shared__ float ulp[8][64];
  __shared__ float ul[64];
  __shared__ float red2[16];
  int b = blockIdx.x, tid = threadIdx.x;
  int idx = tid & 127, wid = tid >> 6;
  float s = scl[b*kNCH + idx];
  float mx = s;
#pragma unroll
  for (int o = 32; o; o >>= 1) mx = fmaxf(mx, __shfl_xor(mx,o,64));
  if ((tid & 63) == 0) red2[wid] = mx;
  __syncthreads();
  mx = fmaxf(red2[0], red2[1]);
  float e = __expf(s - mx);
  float se = e;
#pragma unroll
  for (int o = 32; o; o >>= 1) se += __shfl_xor(se,o,64);
  if ((tid & 63) == 0) red2[8+wid] = se;
  if (tid < kNCH) wl[tid] = e;
  __syncthreads();
  float inv = 1.f/(red2[8]+red2[9]);
  {
    int dd = tid & 127, qq = tid >> 7;
    const float* cfb = cf + (size_t)b*kNCH*kDM + (size_t)qq*32*kDM;
    const float* wlq = wl + qq*32;
    float a0=0,a1=0,a2=0,a3=0;
#pragma unroll 4
    for (int ncc = 0; ncc < 32; ncc += 4) {
      a0 = fmaf(wlq[ncc+0], cfb[(ncc+0)*kDM+dd], a0);
      a1 = fmaf(wlq[ncc+1], cfb[(ncc+1)*kDM+dd], a1);
      a2 = fmaf(wlq[ncc+2], cfb[(ncc+2)*kDM+dd], a2);
      a3 = fmaf(wlq[ncc+3], cfb[(ncc+3)*kDM+dd], a3);
    }
    rep4[qq][dd] = (a0+a1)+(a2+a3);
  }
  __syncthreads();
  {
    int jj = tid & 63, qq = tid >> 6;
    float accp = 0.f;
#pragma unroll
    for (int k = 0; k < 16; ++k) {
      int dd = qq*16 + k;
      float rv = ((rep4[0][dd]+rep4[1][dd])+(rep4[2][dd]+rep4[3][dd]))*inv;
      accp = fmaf(rv, cl1_w[dd*64+jj], accp);
    }
    ulp[qq][jj] = accp;
  }
  __syncthreads();
  if (tid < 64) {
    float acc = cl1_b[tid];
#pragma unroll
    for (int q = 0; q < 8; ++q) acc += ulp[q][tid];
    ul[tid] = fast_silu(acc);
  }
  __syncthreads();
  if (tid < 2) {
    float acc = cl2_b[tid];
#pragma unroll
    for (int k = 0; k < 64; ++k) acc = fmaf(ul[k], cl2_w[k*2+tid], acc);
    out[b*2+tid] = acc;
  }
}

// ---------------------------------------------------------------------------

extern "C" void kernel_launch(void* const* d_in, const int* in_sizes, int n_in,
                              void* d_out, int out_size, void* d_ws, size_t ws_size,
                              hipStream_t stream) {
  const float* x      = (const float*)d_in[0];
  const float* conv_w = (const float*)d_in[1];
  const float* conv_b = (const float*)d_in[2];
  const float* ln1_g  = (const float*)d_in[3];
  const float* ln1_b  = (const float*)d_in[4];
  const float* ca1_w  = (const float*)d_in[5];
  const float* ca1_b  = (const float*)d_in[6];
  const float* ca2_w  = (const float*)d_in[7];
  const float* ca2_b  = (const float*)d_in[8];
  const float* pp_w   = (const float*)d_in[9];
  const float* pp_b   = (const float*)d_in[10];
  const float* ep_w   = (const float*)d_in[11];
  const float* ep_b   = (const float*)d_in[12];
  const float* op_w   = (const float*)d_in[13];
  const float* op_b   = (const float*)d_in[14];
  const float* ln2_g  = (const float*)d_in[15];
  const float* ln2_b  = (const float*)d_in[16];
  const float* sa1_w  = (const float*)d_in[17];
  const float* sa1_b  = (const float*)d_in[18];
  const float* sa2_w  = (const float*)d_in[19];
  const float* sa2_b  = (const float*)d_in[20];
  const float* cl1_w  = (const float*)d_in[21];
  const float* cl1_b  = (const float*)d_in[22];
  const float* cl2_w  = (const float*)d_in[23];
  const float* cl2_b  = (const float*)d_in[24];
  float* out = (float*)d_out;

  const size_t nch = (size_t)kBATCH * kNCH;  // 16384
  const size_t fA    = nch * kDM;            // csb (126f) / cf (128f) aliased
  const size_t need  = (fA + nch * 18 + nch + 1024 * kDM) * sizeof(float);

  if (ws_size >= need) {
    float* A     = (float*)d_ws;
    float* qv_g  = A + fA;
    float* sclb  = qv_g + nch * 18;
    float* rpart = sclb + nch;
    k_pre<<<kBATCH * kNCH, 128, 0, stream>>>(
        x, conv_w, conv_b, ln1_g, ln1_b, ca1_w, ca1_b, ca2_w, ca2_b,
        pp_w, pp_b, ep_w, ep_b, A);
    k_circ<<<(kBATCH * kNCH) / 16, 64, 0, stream>>>(A, qv_g);
    k_post<<<kBATCH * kNCH, 128, 0, stream>>>(
        qv_g, op_w, op_b, ln2_g, ln2_b, sa1_w, sa1_b, sa2_w, sa2_b, A, sclb);
    k_rpart<<<kBATCH * 8, 128, 0, stream>>>(A, sclb, rpart);
    k_final<<<kBATCH, 128, 0, stream>>>(rpart, sclb, cl1_w, cl1_b, cl2_w, cl2_b, out);
  } else {
    float* cf   = (float*)d_ws;
    float* sclb = cf + nch * kDM;
    k_chunk_fb<<<kBATCH * kNCH, 128, 0, stream>>>(
        x, conv_w, conv_b, ln1_g, ln1_b, ca1_w, ca1_b, ca2_w, ca2_b,
        pp_w, pp_b, ep_w, ep_b, op_w, op_b, ln2_g, ln2_b, cf);
    k_scl_fb<<<(kBATCH * kNCH) / 4, 256, 0, stream>>>(cf, sa1_w, sa1_b, sa2_w, sa2_b, sclb);
    k_pool_cf<<<kBATCH, 512, 0, stream>>>(cf, sclb, cl1_w, cl1_b, cl2_w, cl2_b, out);
  }
}

// Round 11
// 227.312 us; speedup vs baseline: 1.5320x; 1.0079x over previous
//
#include <hip/hip_runtime.h>
#include <math.h>

// ---------------------------------------------------------------------------
// QuantumTransformerE2E on MI355X — R11.
// R10 (229 µs) + ONE change: gate sincos precomputed in k_pre's projection
// epilogue (126 thread-parallel sincos; removes 252 transcendentals and the
// 60-VGPR gc/gs live set from every k_circ lane — 4x redundancy gone).
// k_circ_cs reads (cos,sin) float2 pairs, stride 256/chunk.
// Tier1 needs 18.0 MB ws (cf+rpart aliased into dead csA); tier2 = R10 path
// (12.1 MB, same k_pre with emit_cs=0 + old k_circ); tier3 = R8 fallback.
// ---------------------------------------------------------------------------

constexpr int kNQ    = 6;
constexpr int kDM    = 128;
constexpr int kCH    = 4;
constexpr int kSEQ   = 2048;
constexpr int kCHUNK = 16;
constexpr int kBATCH = 128;
constexpr int kNCH   = kSEQ / kCHUNK;  // 128
constexpr int kNP    = 120;
constexpr float kPI  = 3.14159265358979323846f;

typedef __attribute__((ext_vector_type(8))) short bf16x8;
typedef __attribute__((ext_vector_type(4))) float f32x4;

__device__ __forceinline__ float fast_tanh(float x) {
  float e = __expf(-2.f * fabsf(x));
  float r = (1.f - e) * __builtin_amdgcn_rcpf(1.f + e);
  return copysignf(r, x);
}
__device__ __forceinline__ float fast_silu(float x) {
  return x * __builtin_amdgcn_rcpf(1.f + __expf(-x));
}

// quad_perm DPP helpers (VALU pipe).
template <int XM>
__device__ __forceinline__ float qp(float v) {
  constexpr int ctrl = (XM == 1) ? 0xB1 : 0x4E;
  return __int_as_float(
      __builtin_amdgcn_update_dpp(0, __float_as_int(v), ctrl, 0xF, 0xF, true));
}

// ---- register-resident 6-qubit gates (verified R8/R10) ---------------------

template <int RB>
__device__ __forceinline__ void rx_reg(float c, float s, float* sr, float* si) {
#pragma unroll
  for (int r0 = 0; r0 < 16; ++r0) {
    if (r0 & RB) continue;
    int r1 = r0 | RB;
    float ar = sr[r0], ai = si[r0], br = sr[r1], bi = si[r1];
    sr[r0] = fmaf(c, ar,  s * bi);  si[r0] = fmaf(c, ai, -s * br);
    sr[r1] = fmaf(c, br,  s * ai);  si[r1] = fmaf(c, bi, -s * ar);
  }
}

template <int RB>
__device__ __forceinline__ void ry_reg(float c, float s, float* sr, float* si) {
#pragma unroll
  for (int r0 = 0; r0 < 16; ++r0) {
    if (r0 & RB) continue;
    int r1 = r0 | RB;
    float ar = sr[r0], ai = si[r0], br = sr[r1], bi = si[r1];
    sr[r0] = fmaf(c, ar, -s * br);  si[r0] = fmaf(c, ai, -s * bi);
    sr[r1] = fmaf(s, ar,  c * br);  si[r1] = fmaf(s, ai,  c * bi);
  }
}

template <int RB>
__device__ __forceinline__ void rz_reg(float c, float s, float* sr, float* si) {
#pragma unroll
  for (int r = 0; r < 16; ++r) {
    float sp = (r & RB) ? s : -s;
    float ar = sr[r], ai = si[r];
    sr[r] = fmaf(c, ar, -sp * ai);
    si[r] = fmaf(c, ai,  sp * ar);
  }
}

template <int XM>
__device__ __forceinline__ void rx_lane(float c, float s, float* sr, float* si) {
#pragma unroll
  for (int r = 0; r < 16; ++r) {
    float pr = qp<XM>(sr[r]), pi = qp<XM>(si[r]);
    sr[r] = fmaf(c, sr[r],  s * pi);
    si[r] = fmaf(c, si[r], -s * pr);
  }
}

template <int XM>
__device__ __forceinline__ void ry_lane(float c, float sg, float* sr, float* si) {
#pragma unroll
  for (int r = 0; r < 16; ++r) {
    float pr = qp<XM>(sr[r]), pi = qp<XM>(si[r]);
    sr[r] = fmaf(c, sr[r], sg * pr);
    si[r] = fmaf(c, si[r], sg * pi);
  }
}

__device__ __forceinline__ void rz_lane(float c, float sp, float* sr, float* si) {
#pragma unroll
  for (int r = 0; r < 16; ++r) {
    float ar = sr[r], ai = si[r];
    sr[r] = fmaf(c, ar, -sp * ai);
    si[r] = fmaf(c, ai,  sp * ar);
  }
}

template <int RB, int CB>
__device__ __forceinline__ void crx_reg_reg(float c, float s, float* sr, float* si) {
#pragma unroll
  for (int r0 = 0; r0 < 16; ++r0) {
    if ((r0 & RB) || !(r0 & CB)) continue;
    int r1 = r0 | RB;
    float ar = sr[r0], ai = si[r0], br = sr[r1], bi = si[r1];
    sr[r0] = fmaf(c, ar,  s * bi);  si[r0] = fmaf(c, ai, -s * br);
    sr[r1] = fmaf(c, br,  s * ai);  si[r1] = fmaf(c, bi, -s * ar);
  }
}

template <int XM, int CB>
__device__ __forceinline__ void crx_reg_lane(float c, float s, float* sr, float* si) {
#pragma unroll
  for (int r = 0; r < 16; ++r) {
    if (!(r & CB)) continue;
    float pr = qp<XM>(sr[r]), pi = qp<XM>(si[r]);
    sr[r] = fmaf(c, sr[r],  s * pi);
    si[r] = fmaf(c, si[r], -s * pr);
  }
}

template <int RB>
__device__ __forceinline__ void meas_reg(const float* sr, const float* si,
                                         float& tr, float& ti, float& zz) {
  tr = 0.f; ti = 0.f; zz = 0.f;
#pragma unroll
  for (int r0 = 0; r0 < 16; ++r0) {
    float n = fmaf(sr[r0], sr[r0], si[r0] * si[r0]);
    zz += (r0 & RB) ? -n : n;
    if (r0 & RB) continue;
    int r1 = r0 | RB;
    tr = fmaf(sr[r0], sr[r1], fmaf(si[r0], si[r1], tr));
    ti = fmaf(sr[r0], si[r1], fmaf(-si[r0], sr[r1], ti));
  }
  tr += qp<1>(tr); tr += qp<2>(tr);
  ti += qp<1>(ti); ti += qp<2>(ti);
  zz += qp<1>(zz); zz += qp<2>(zz);
}

// ---------------------------------------------------------------------------
// k_pre: conv(global) + LN1 + MFMA chunk attention + projections.
// emit_cs=1: write (cos,sin) of half-angles, stride 256/chunk.
// emit_cs=0: write half-angles, stride 126/chunk (R10 tier2 path).

__global__ __launch_bounds__(128) void k_pre(
    const float* __restrict__ x,
    const float* __restrict__ conv_w, const float* __restrict__ conv_b,
    const float* __restrict__ ln1_g,  const float* __restrict__ ln1_b,
    const float* __restrict__ ca1_w,  const float* __restrict__ ca1_b,
    const float* __restrict__ ca2_w,  const float* __restrict__ ca2_b,
    const float* __restrict__ pp_w,   const float* __restrict__ pp_b,
    const float* __restrict__ ep_w,   const float* __restrict__ ep_b,
    float* __restrict__ outb, int emit_cs)
{
  __shared__ float hbuf[kCHUNK][132];           // fp32 raw, then (hi,lo) packed
  __shared__ __align__(16) float spart[2][16];  // per-wave score partials
  __shared__ __align__(16) float summ[kDM];
  __shared__ float mrow[kCHUNK], irow[kCHUNK];

  const int tid   = threadIdx.x;
  const int chunk = blockIdx.x;
  const int b     = chunk >> 7;
  const int nc    = chunk & 127;
  const int t0    = nc * kCHUNK;
  const int d     = tid;
  const int lane  = tid & 63;
  const int wv    = tid >> 6;                   // wave id = N-tile id
  const int col   = (lane & 15) + 16 * wv;      // j column 0..31
  const int qd    = lane >> 4;                  // 0..3

  // ---- early loads (fly under conv) ----
  float w12[12];
  {
    const float4* cw = (const float4*)(conv_w + d * 12);
    float4 a0 = cw[0], a1 = cw[1], a2 = cw[2];
    w12[0]=a0.x; w12[1]=a0.y; w12[2]=a0.z; w12[3]=a0.w;
    w12[4]=a1.x; w12[5]=a1.y; w12[6]=a1.z; w12[7]=a1.w;
    w12[8]=a2.x; w12[9]=a2.y; w12[10]=a2.z; w12[11]=a2.w;
  }
  float cb = conv_b[d];
  float g1 = ln1_g[d], b1 = ln1_b[d];
  float Bf[32];
#pragma unroll
  for (int ks = 0; ks < 4; ++ks)
#pragma unroll
    for (int jj = 0; jj < 8; ++jj)
      Bf[ks * 8 + jj] = ca1_w[(ks * 32 + qd * 8 + jj) * 32 + col];
  float cb1 = ca1_b[col], cw2 = ca2_w[col], cb2 = ca2_b[0];

  // ---- conv1d from global -> raw h regs + hbuf fp32 ----
  float h[kCHUNK];
#pragma unroll
  for (int t = 0; t < kCHUNK; ++t) h[t] = cb;
#pragma unroll
  for (int ch = 0; ch < kCH; ++ch) {
    const float* xb = x + ((size_t)b * kCH + ch) * kSEQ + t0 - 4;
    float xv[24];
#pragma unroll
    for (int sl = 1; sl <= 4; ++sl) {
      float4 v = *(const float4*)(xb + sl * 4);
      xv[sl*4+0]=v.x; xv[sl*4+1]=v.y; xv[sl*4+2]=v.z; xv[sl*4+3]=v.w;
    }
    if (nc > 0) {
      float4 v = *(const float4*)(xb);
      xv[0]=v.x; xv[1]=v.y; xv[2]=v.z; xv[3]=v.w;
    } else { xv[0]=xv[1]=xv[2]=xv[3]=0.f; }
    if (nc < 127) {
      float4 v = *(const float4*)(xb + 20);
      xv[20]=v.x; xv[21]=v.y; xv[22]=v.z; xv[23]=v.w;
    } else { xv[20]=xv[21]=xv[22]=xv[23]=0.f; }
    float c0 = w12[ch*3+0], c1 = w12[ch*3+1], c2 = w12[ch*3+2];
#pragma unroll
    for (int t = 0; t < kCHUNK; ++t)
      h[t] = fmaf(xv[t+3], c0, fmaf(xv[t+4], c1, fmaf(xv[t+5], c2, h[t])));
  }
#pragma unroll
  for (int t = 0; t < kCHUNK; ++t) hbuf[t][d] = h[t];
  __syncthreads();                                   // B1

  // ---- LN1 stats ----
  {
    int row = tid >> 3, k = tid & 7;
    const float4* rp = (const float4*)&hbuf[row][k * 16];
    float s1 = 0.f, s2 = 0.f;
#pragma unroll
    for (int q = 0; q < 4; ++q) {
      float4 v = rp[q];
      s1 += v.x + v.y + v.z + v.w;
      s2 = fmaf(v.x,v.x,s2); s2 = fmaf(v.y,v.y,s2);
      s2 = fmaf(v.z,v.z,s2); s2 = fmaf(v.w,v.w,s2);
    }
#pragma unroll
    for (int o = 1; o < 8; o <<= 1) {
      s1 += __shfl_xor(s1, o, 64);
      s2 += __shfl_xor(s2, o, 64);
    }
    if (k == 0) {
      float m = s1 * (1.f / kDM);
      mrow[row] = m;
      irow[row] = rsqrtf(s2 * (1.f / kDM) - m * m + 1e-5f);
    }
  }
  __syncthreads();                                   // B2

  // ---- LN1 apply in regs + write (hi,lo) bf16 pair per element ----
#pragma unroll
  for (int t = 0; t < kCHUNK; ++t) {
    h[t] = fmaf((h[t] - mrow[t]) * irow[t], g1, b1);
    unsigned hb = __float_as_uint(h[t]);
    float lof = h[t] - __uint_as_float(hb & 0xffff0000u);
    unsigned pk = (hb >> 16) | (__float_as_uint(lof) & 0xffff0000u);
    ((unsigned*)&hbuf[t][0])[d] = pk;
  }
  __syncthreads();                                   // B3

  // ---- split B into bf16 hi/lo fragment vectors ----
  bf16x8 bhi[4], blo[4];
#pragma unroll
  for (int ks = 0; ks < 4; ++ks)
#pragma unroll
    for (int jj = 0; jj < 8; ++jj) {
      float bvf = Bf[ks * 8 + jj];
      unsigned bb = __float_as_uint(bvf);
      bhi[ks][jj] = (short)(bb >> 16);
      float lf = bvf - __uint_as_float(bb & 0xffff0000u);
      blo[ks][jj] = (short)(__float_as_uint(lf) >> 16);
    }

  // ---- MFMA GEMV: C[16][16] per wave, K=128 in 4 steps, 3-term split ----
  f32x4 acc = {0.f, 0.f, 0.f, 0.f};
  {
    const unsigned* hrow = (const unsigned*)&hbuf[lane & 15][0];
#pragma unroll
    for (int ks = 0; ks < 4; ++ks) {
      const uint4* ap = (const uint4*)(hrow + ks * 32 + qd * 8);
      uint4 w0 = ap[0], w1 = ap[1];
      bf16x8 ahi, alo;
      ahi[0] = (short)(w0.x & 0xffff); ahi[1] = (short)(w0.y & 0xffff);
      ahi[2] = (short)(w0.z & 0xffff); ahi[3] = (short)(w0.w & 0xffff);
      ahi[4] = (short)(w1.x & 0xffff); ahi[5] = (short)(w1.y & 0xffff);
      ahi[6] = (short)(w1.z & 0xffff); ahi[7] = (short)(w1.w & 0xffff);
      alo[0] = (short)(w0.x >> 16); alo[1] = (short)(w0.y >> 16);
      alo[2] = (short)(w0.z >> 16); alo[3] = (short)(w0.w >> 16);
      alo[4] = (short)(w1.x >> 16); alo[5] = (short)(w1.y >> 16);
      alo[6] = (short)(w1.z >> 16); alo[7] = (short)(w1.w >> 16);
      acc = __builtin_amdgcn_mfma_f32_16x16x32_bf16(ahi, bhi[ks], acc, 0, 0, 0);
      acc = __builtin_amdgcn_mfma_f32_16x16x32_bf16(ahi, blo[ks], acc, 0, 0, 0);
      acc = __builtin_amdgcn_mfma_f32_16x16x32_bf16(alo, bhi[ks], acc, 0, 0, 0);
    }
  }

  // ---- tanh + ca2 weighting in C-layout, reduce over j (16 lanes) ----
  {
    float ev[4];
#pragma unroll
    for (int r = 0; r < 4; ++r)
      ev[r] = fast_tanh(acc[r] + cb1) * cw2;
#pragma unroll
    for (int o = 1; o < 16; o <<= 1)
#pragma unroll
      for (int r = 0; r < 4; ++r) ev[r] += __shfl_xor(ev[r], o, 64);
    if ((lane & 15) == 0)
      *(float4*)&spart[wv][qd * 4] = make_float4(ev[0], ev[1], ev[2], ev[3]);
  }
  __syncthreads();                                   // B4

  // ---- all-thread redundant softmax + weighted sum from h regs ----
  {
    float scl16[kCHUNK];
    const float4* s0 = (const float4*)&spart[0][0];
    const float4* s1 = (const float4*)&spart[1][0];
    float mx = -1e30f;
#pragma unroll
    for (int g = 0; g < 4; ++g) {
      float4 a = s0[g], bq = s1[g];
      scl16[g*4+0] = a.x + bq.x + cb2;
      scl16[g*4+1] = a.y + bq.y + cb2;
      scl16[g*4+2] = a.z + bq.z + cb2;
      scl16[g*4+3] = a.w + bq.w + cb2;
    }
#pragma unroll
    for (int t = 0; t < kCHUNK; ++t) mx = fmaxf(mx, scl16[t]);
    float e[kCHUNK], ssum = 0.f;
#pragma unroll
    for (int t = 0; t < kCHUNK; ++t) { e[t] = __expf(scl16[t] - mx); ssum += e[t]; }
    float inv = 1.f / ssum;
    float acc2 = 0.f;
#pragma unroll
    for (int t = 0; t < kCHUNK; ++t) acc2 = fmaf(e[t] * inv, h[t], acc2);
    summ[d] = acc2;
  }
  __syncthreads();                                   // B5

  // ---- projections -> half-angles (tier2) or (cos,sin) pairs (tier1) ----
  if (tid < kNP) {
    float acc = pp_b[tid];
    const float4* s4 = (const float4*)summ;
#pragma unroll 8
    for (int q = 0; q < 32; ++q) {
      float4 v = s4[q];
      acc = fmaf(v.x, pp_w[(q*4+0)*kNP + tid], acc);
      acc = fmaf(v.y, pp_w[(q*4+1)*kNP + tid], acc);
      acc = fmaf(v.z, pp_w[(q*4+2)*kNP + tid], acc);
      acc = fmaf(v.w, pp_w[(q*4+3)*kNP + tid], acc);
    }
    float ha = 0.5f * acc;
    if (emit_cs) {
      ((float2*)(outb + (size_t)chunk * 256))[6 + tid] =
          make_float2(__cosf(ha), __sinf(ha));
    } else {
      outb[(size_t)chunk * 126 + 6 + tid] = ha;
    }
  } else if (tid < kNP + kNQ) {
    int jj = tid - kNP;
    float acc = ep_b[jj];
    const float4* s4 = (const float4*)summ;
#pragma unroll 8
    for (int q = 0; q < 32; ++q) {
      float4 v = s4[q];
      acc = fmaf(v.x, ep_w[(q*4+0)*kNQ + jj], acc);
      acc = fmaf(v.y, ep_w[(q*4+1)*kNQ + jj], acc);
      acc = fmaf(v.z, ep_w[(q*4+2)*kNQ + jj], acc);
      acc = fmaf(v.w, ep_w[(q*4+3)*kNQ + jj], acc);
    }
    float ha = 0.5f * fast_tanh(acc) * kPI;
    if (emit_cs) {
      ((float2*)(outb + (size_t)chunk * 256))[jj] =
          make_float2(__cosf(ha), __sinf(ha));
    } else {
      outb[(size_t)chunk * 126 + jj] = ha;
    }
  }
}

// ---------------------------------------------------------------------------
// k_circ_cs: tier1 — reads precomputed (cos,sin) pairs, ZERO transcendentals.

__global__ __launch_bounds__(64) void k_circ_cs(const float* __restrict__ csA,
                                                float* __restrict__ qv_g)
{
  const int lane  = threadIdx.x;
  const int c     = lane >> 2;
  const int l     = lane & 3;
  const int chunk = blockIdx.x * 16 + c;
  const float2* cp = (const float2*)(csA + (size_t)chunk * 256);
  const int b0 = (l >> 1) & 1;
  const int b1 = l & 1;

  float sr[16], si[16];
#pragma unroll
  for (int r = 0; r < 16; ++r) { sr[r] = 0.f; si[r] = 0.f; }
  sr[0] = (l == 0) ? 1.f : 0.f;

  {
    float2 q0 = cp[0], q1 = cp[1], q2 = cp[2], q3 = cp[3], q4 = cp[4], q5 = cp[5];
    ry_lane<2>(q0.x, b0 ? q0.y : -q0.y, sr, si);
    ry_lane<1>(q1.x, b1 ? q1.y : -q1.y, sr, si);
    ry_reg<8>(q2.x, q2.y, sr, si);
    ry_reg<4>(q3.x, q3.y, sr, si);
    ry_reg<2>(q4.x, q4.y, sr, si);
    ry_reg<1>(q5.x, q5.y, sr, si);
  }

  for (int a = 0; a < 4; ++a) {
    const float2* pb = cp + 6 + a * 30;
    float2 t;
    t = pb[0];  rx_lane<2>(t.x, t.y, sr, si);
    t = pb[1];  ry_lane<2>(t.x, b0 ? t.y : -t.y, sr, si);
    t = pb[2];  rz_lane   (t.x, b0 ? t.y : -t.y, sr, si);
    t = pb[3];  rx_lane<1>(t.x, t.y, sr, si);
    t = pb[4];  ry_lane<1>(t.x, b1 ? t.y : -t.y, sr, si);
    t = pb[5];  rz_lane   (t.x, b1 ? t.y : -t.y, sr, si);
    t = pb[6];  rx_reg<8>(t.x, t.y, sr, si);
    t = pb[7];  ry_reg<8>(t.x, t.y, sr, si);
    t = pb[8];  rz_reg<8>(t.x, t.y, sr, si);
    t = pb[9];  rx_reg<4>(t.x, t.y, sr, si);
    t = pb[10]; ry_reg<4>(t.x, t.y, sr, si);
    t = pb[11]; rz_reg<4>(t.x, t.y, sr, si);
    t = pb[12]; rx_reg<2>(t.x, t.y, sr, si);
    t = pb[13]; ry_reg<2>(t.x, t.y, sr, si);
    t = pb[14]; rz_reg<2>(t.x, t.y, sr, si);
    t = pb[15]; rx_reg<1>(t.x, t.y, sr, si);
    t = pb[16]; ry_reg<1>(t.x, t.y, sr, si);
    t = pb[17]; rz_reg<1>(t.x, t.y, sr, si);
    t = pb[18]; { float c2 = b0 ? t.x : 1.f, s2 = b0 ? t.y : 0.f; rx_lane<1>(c2, s2, sr, si); }
    t = pb[19]; { float c2 = b1 ? t.x : 1.f, s2 = b1 ? t.y : 0.f; rx_reg<8>(c2, s2, sr, si); }
    t = pb[20]; crx_reg_reg<4, 8>(t.x, t.y, sr, si);
    t = pb[21]; crx_reg_reg<2, 4>(t.x, t.y, sr, si);
    t = pb[22]; crx_reg_reg<1, 2>(t.x, t.y, sr, si);
    t = pb[23]; crx_reg_lane<2, 1>(t.x, t.y, sr, si);
    t = pb[24]; crx_reg_reg<2, 1>(t.x, t.y, sr, si);
    t = pb[25]; crx_reg_reg<4, 2>(t.x, t.y, sr, si);
    t = pb[26]; crx_reg_reg<8, 4>(t.x, t.y, sr, si);
    t = pb[27]; crx_reg_lane<1, 8>(t.x, t.y, sr, si);
    t = pb[28]; { float c2 = b1 ? t.x : 1.f, s2 = b1 ? t.y : 0.f; rx_lane<2>(c2, s2, sr, si); }
    t = pb[29]; { float c2 = b0 ? t.x : 1.f, s2 = b0 ? t.y : 0.f; rx_reg<1>(c2, s2, sr, si); }
  }

  float res[18];
  {
    float tr = 0.f, ti = 0.f, zz = 0.f;
#pragma unroll
    for (int r = 0; r < 16; ++r) {
      float pr = qp<2>(sr[r]), pi = qp<2>(si[r]);
      tr = fmaf(sr[r], pr, fmaf(si[r], pi, tr));
      ti = fmaf(sr[r], pi, fmaf(-si[r], pr, ti));
      zz = fmaf(sr[r], sr[r], fmaf(si[r], si[r], zz));
    }
    tr = b0 ? 0.f : tr;  ti = b0 ? 0.f : ti;  zz = b0 ? -zz : zz;
    tr += qp<1>(tr); tr += qp<2>(tr);
    ti += qp<1>(ti); ti += qp<2>(ti);
    zz += qp<1>(zz); zz += qp<2>(zz);
    res[0] = 2.f * tr; res[6] = 2.f * ti; res[12] = zz;
  }
  {
    float tr = 0.f, ti = 0.f, zz = 0.f;
#pragma unroll
    for (int r = 0; r < 16; ++r) {
      float pr = qp<1>(sr[r]), pi = qp<1>(si[r]);
      tr = fmaf(sr[r], pr, fmaf(si[r], pi, tr));
      ti = fmaf(sr[r], pi, fmaf(-si[r], pr, ti));
      zz = fmaf(sr[r], sr[r], fmaf(si[r], si[r], zz));
    }
    tr = b1 ? 0.f : tr;  ti = b1 ? 0.f : ti;  zz = b1 ? -zz : zz;
    tr += qp<1>(tr); tr += qp<2>(tr);
    ti += qp<1>(ti); ti += qp<2>(ti);
    zz += qp<1>(zz); zz += qp<2>(zz);
    res[1] = 2.f * tr; res[7] = 2.f * ti; res[13] = zz;
  }
  {
    float tr, ti, zz;
    meas_reg<8>(sr, si, tr, ti, zz); res[2] = 2.f*tr; res[8]  = 2.f*ti; res[14] = zz;
    meas_reg<4>(sr, si, tr, ti, zz); res[3] = 2.f*tr; res[9]  = 2.f*ti; res[15] = zz;
    meas_reg<2>(sr, si, tr, ti, zz); res[4] = 2.f*tr; res[10] = 2.f*ti; res[16] = zz;
    meas_reg<1>(sr, si, tr, ti, zz); res[5] = 2.f*tr; res[11] = 2.f*ti; res[17] = zz;
  }
  if (l == 0) {
    float* qo = qv_g + (size_t)chunk * 18;
#pragma unroll
    for (int k = 0; k < 18; ++k) qo[k] = res[k];
  }
}

// ---------------------------------------------------------------------------
// k_circ: tier2 (verbatim R10) — reads half-angles stride 126, computes sincos.

__global__ __launch_bounds__(64) void k_circ(const float* __restrict__ csb_g,
                                             float* __restrict__ qv_g)
{
  const int lane  = threadIdx.x;
  const int c     = lane >> 2;
  const int l     = lane & 3;
  const int chunk = blockIdx.x * 16 + c;
  const float* cp = csb_g + (size_t)chunk * 126;
  const int b0 = (l >> 1) & 1;
  const int b1 = l & 1;

  float sr[16], si[16];
#pragma unroll
  for (int r = 0; r < 16; ++r) { sr[r] = 0.f; si[r] = 0.f; }
  sr[0] = (l == 0) ? 1.f : 0.f;

  {
    float gc[6], gs[6];
#pragma unroll
    for (int g = 0; g < 6; ++g) { float th = cp[g]; gc[g] = __cosf(th); gs[g] = __sinf(th); }
    ry_lane<2>(gc[0], b0 ? gs[0] : -gs[0], sr, si);
    ry_lane<1>(gc[1], b1 ? gs[1] : -gs[1], sr, si);
    ry_reg<8>(gc[2], gs[2], sr, si);
    ry_reg<4>(gc[3], gs[3], sr, si);
    ry_reg<2>(gc[4], gs[4], sr, si);
    ry_reg<1>(gc[5], gs[5], sr, si);
  }

  for (int a = 0; a < 4; ++a) {
    const float* pb = cp + 6 + a * 30;
    float gc[30], gs[30];
#pragma unroll
    for (int g = 0; g < 30; ++g) { float th = pb[g]; gc[g] = __cosf(th); gs[g] = __sinf(th); }
    rx_lane<2>(gc[0], gs[0], sr, si);
    ry_lane<2>(gc[1], b0 ? gs[1] : -gs[1], sr, si);
    rz_lane   (gc[2], b0 ? gs[2] : -gs[2], sr, si);
    rx_lane<1>(gc[3], gs[3], sr, si);
    ry_lane<1>(gc[4], b1 ? gs[4] : -gs[4], sr, si);
    rz_lane   (gc[5], b1 ? gs[5] : -gs[5], sr, si);
    rx_reg<8>(gc[6],  gs[6],  sr, si);  ry_reg<8>(gc[7],  gs[7],  sr, si);  rz_reg<8>(gc[8],  gs[8],  sr, si);
    rx_reg<4>(gc[9],  gs[9],  sr, si);  ry_reg<4>(gc[10], gs[10], sr, si);  rz_reg<4>(gc[11], gs[11], sr, si);
    rx_reg<2>(gc[12], gs[12], sr, si);  ry_reg<2>(gc[13], gs[13], sr, si);  rz_reg<2>(gc[14], gs[14], sr, si);
    rx_reg<1>(gc[15], gs[15], sr, si);  ry_reg<1>(gc[16], gs[16], sr, si);  rz_reg<1>(gc[17], gs[17], sr, si);
    { float c2 = b0 ? gc[18] : 1.f, s2 = b0 ? gs[18] : 0.f; rx_lane<1>(c2, s2, sr, si); }
    { float c2 = b1 ? gc[19] : 1.f, s2 = b1 ? gs[19] : 0.f; rx_reg<8>(c2, s2, sr, si); }
    crx_reg_reg<4, 8>(gc[20], gs[20], sr, si);
    crx_reg_reg<2, 4>(gc[21], gs[21], sr, si);
    crx_reg_reg<1, 2>(gc[22], gs[22], sr, si);
    crx_reg_lane<2, 1>(gc[23], gs[23], sr, si);
    crx_reg_reg<2, 1>(gc[24], gs[24], sr, si);
    crx_reg_reg<4, 2>(gc[25], gs[25], sr, si);
    crx_reg_reg<8, 4>(gc[26], gs[26], sr, si);
    crx_reg_lane<1, 8>(gc[27], gs[27], sr, si);
    { float c2 = b1 ? gc[28] : 1.f, s2 = b1 ? gs[28] : 0.f; rx_lane<2>(c2, s2, sr, si); }
    { float c2 = b0 ? gc[29] : 1.f, s2 = b0 ? gs[29] : 0.f; rx_reg<1>(c2, s2, sr, si); }
  }

  float res[18];
  {
    float tr = 0.f, ti = 0.f, zz = 0.f;
#pragma unroll
    for (int r = 0; r < 16; ++r) {
      float pr = qp<2>(sr[r]), pi = qp<2>(si[r]);
      tr = fmaf(sr[r], pr, fmaf(si[r], pi, tr));
      ti = fmaf(sr[r], pi, fmaf(-si[r], pr, ti));
      zz = fmaf(sr[r], sr[r], fmaf(si[r], si[r], zz));
    }
    tr = b0 ? 0.f : tr;  ti = b0 ? 0.f : ti;  zz = b0 ? -zz : zz;
    tr += qp<1>(tr); tr += qp<2>(tr);
    ti += qp<1>(ti); ti += qp<2>(ti);
    zz += qp<1>(zz); zz += qp<2>(zz);
    res[0] = 2.f * tr; res[6] = 2.f * ti; res[12] = zz;
  }
  {
    float tr = 0.f, ti = 0.f, zz = 0.f;
#pragma unroll
    for (int r = 0; r < 16; ++r) {
      float pr = qp<1>(sr[r]), pi = qp<1>(si[r]);
      tr = fmaf(sr[r], pr, fmaf(si[r], pi, tr));
      ti = fmaf(sr[r], pi, fmaf(-si[r], pr, ti));
      zz = fmaf(sr[r], sr[r], fmaf(si[r], si[r], zz));
    }
    tr = b1 ? 0.f : tr;  ti = b1 ? 0.f : ti;  zz = b1 ? -zz : zz;
    tr += qp<1>(tr); tr += qp<2>(tr);
    ti += qp<1>(ti); ti += qp<2>(ti);
    zz += qp<1>(zz); zz += qp<2>(zz);
    res[1] = 2.f * tr; res[7] = 2.f * ti; res[13] = zz;
  }
  {
    float tr, ti, zz;
    meas_reg<8>(sr, si, tr, ti, zz); res[2] = 2.f*tr; res[8]  = 2.f*ti; res[14] = zz;
    meas_reg<4>(sr, si, tr, ti, zz); res[3] = 2.f*tr; res[9]  = 2.f*ti; res[15] = zz;
    meas_reg<2>(sr, si, tr, ti, zz); res[4] = 2.f*tr; res[10] = 2.f*ti; res[16] = zz;
    meas_reg<1>(sr, si, tr, ti, zz); res[5] = 2.f*tr; res[11] = 2.f*ti; res[17] = zz;
  }
  if (l == 0) {
    float* qo = qv_g + (size_t)chunk * 18;
#pragma unroll
    for (int k = 0; k < 18; ++k) qo[k] = res[k];
  }
}

// ---------------------------------------------------------------------------
// k_post / k_rpart / k_final: verbatim R8/R10.

__global__ __launch_bounds__(128) void k_post(
    const float* __restrict__ qv_g,
    const float* __restrict__ op_w, const float* __restrict__ op_b,
    const float* __restrict__ ln2_g, const float* __restrict__ ln2_b,
    const float* __restrict__ sa1_w, const float* __restrict__ sa1_b,
    const float* __restrict__ sa2_w, const float* __restrict__ sa2_b,
    float* __restrict__ cf, float* __restrict__ sclb)
{
  __shared__ float cfs[132];
  __shared__ float part1[32];
  __shared__ float red[4];

  const int chunk = blockIdx.x, tid = threadIdx.x, d = tid;
  const int j = tid & 31, sub = tid >> 5;

  float qv[18];
  {
    const float* qpp = qv_g + (size_t)chunk * 18;
#pragma unroll
    for (int k = 0; k < 18; ++k) qv[k] = qpp[k];
  }
  float acc = op_b[d];
#pragma unroll
  for (int k = 0; k < 18; ++k) acc = fmaf(qv[k], op_w[k * kDM + d], acc);

  float v = acc, v2 = acc * acc;
#pragma unroll
  for (int o = 32; o; o >>= 1) { v += __shfl_xor(v, o, 64); v2 += __shfl_xor(v2, o, 64); }
  if ((tid & 63) == 0) { red[tid >> 6] = v; red[2 + (tid >> 6)] = v2; }
  __syncthreads();
  float s1 = red[0] + red[1], s2 = red[2] + red[3];
  float m = s1 * (1.f / kDM);
  float var = s2 * (1.f / kDM) - m * m;
  float xn = fmaf((acc - m) * rsqrtf(var + 1e-5f), ln2_g[d], ln2_b[d]);
  float cfv = fast_silu(xn);
  cf[(size_t)chunk * kDM + d] = cfv;
  cfs[d] = cfv;
  __syncthreads();

  float acc2 = 0.f;
  {
    const float* wp2 = sa1_w + (sub * 32) * 32 + j;
#pragma unroll
    for (int q = 0; q < 8; ++q) {
      float4 hv = *(const float4*)&cfs[sub * 32 + q * 4];
      acc2 = fmaf(hv.x, wp2[(q*4+0)*32], acc2);
      acc2 = fmaf(hv.y, wp2[(q*4+1)*32], acc2);
      acc2 = fmaf(hv.z, wp2[(q*4+2)*32], acc2);
      acc2 = fmaf(hv.w, wp2[(q*4+3)*32], acc2);
    }
  }
  acc2 += __shfl_xor(acc2, 32, 64);
  if (sub == 2) part1[j] = acc2;
  __syncthreads();
  if (tid < 32) {
    float hv = fast_tanh(acc2 + part1[j] + sa1_b[j]) * sa2_w[j];
#pragma unroll
    for (int o = 16; o; o >>= 1) hv += __shfl_xor(hv, o, 64);
    if (j == 0) sclb[chunk] = hv + sa2_b[0];
  }
}

__global__ __launch_bounds__(128) void k_rpart(
    const float* __restrict__ cf, const float* __restrict__ sclb,
    float* __restrict__ rep_part)
{
  __shared__ float wl[kNCH];
  __shared__ float red2[2];

  const int blk = blockIdx.x, tid = threadIdx.x;
  const int b = blk >> 3, sl = blk & 7;

  float s = sclb[b * kNCH + tid];
  float mx = s;
#pragma unroll
  for (int o = 32; o; o >>= 1) mx = fmaxf(mx, __shfl_xor(mx, o, 64));
  if ((tid & 63) == 0) red2[tid >> 6] = mx;
  __syncthreads();
  mx = fmaxf(red2[0], red2[1]);
  wl[tid] = __expf(s - mx);
  __syncthreads();

  const float* cfb = cf + ((size_t)b * kNCH + sl * 16) * kDM;
  const float* wls = wl + sl * 16;
  float a0 = 0.f, a1 = 0.f, a2 = 0.f, a3 = 0.f;
#pragma unroll
  for (int k = 0; k < 16; k += 4) {
    a0 = fmaf(wls[k+0], cfb[(k+0) * kDM + tid], a0);
    a1 = fmaf(wls[k+1], cfb[(k+1) * kDM + tid], a1);
    a2 = fmaf(wls[k+2], cfb[(k+2) * kDM + tid], a2);
    a3 = fmaf(wls[k+3], cfb[(k+3) * kDM + tid], a3);
  }
  rep_part[(size_t)blk * kDM + tid] = (a0 + a1) + (a2 + a3);
}

__global__ __launch_bounds__(128) void k_final(
    const float* __restrict__ rep_part, const float* __restrict__ sclb,
    const float* __restrict__ cl1_w, const float* __restrict__ cl1_b,
    const float* __restrict__ cl2_w, const float* __restrict__ cl2_b,
    float* __restrict__ out)
{
  __shared__ float summ[132];
  __shared__ float up[64];
  __shared__ float ul[64];
  __shared__ float red2[4];

  const int b = blockIdx.x, tid = threadIdx.x;
  float s = sclb[b * kNCH + tid];
  float mx = s;
#pragma unroll
  for (int o = 32; o; o >>= 1) mx = fmaxf(mx, __shfl_xor(mx, o, 64));
  if ((tid & 63) == 0) red2[tid >> 6] = mx;
  __syncthreads();
  mx = fmaxf(red2[0], red2[1]);
  float e = __expf(s - mx);
  float se = e;
#pragma unroll
  for (int o = 32; o; o >>= 1) se += __shfl_xor(se, o, 64);
  if ((tid & 63) == 0) red2[2 + (tid >> 6)] = se;
  __syncthreads();
  float inv = 1.f / (red2[2] + red2[3]);

  float rp = 0.f;
#pragma unroll
  for (int p8 = 0; p8 < 8; ++p8) rp += rep_part[((size_t)b * 8 + p8) * kDM + tid];
  summ[tid] = rp * inv;
  __syncthreads();

  {
    int jj = tid & 63, half = tid >> 6;
    float acc = 0.f;
#pragma unroll
    for (int q = 0; q < 16; ++q) {
      float4 v = *(const float4*)&summ[half * 64 + q * 4];
      acc = fmaf(v.x, cl1_w[(half*64 + q*4 + 0) * 64 + jj], acc);
      acc = fmaf(v.y, cl1_w[(half*64 + q*4 + 1) * 64 + jj], acc);
      acc = fmaf(v.z, cl1_w[(half*64 + q*4 + 2) * 64 + jj], acc);
      acc = fmaf(v.w, cl1_w[(half*64 + q*4 + 3) * 64 + jj], acc);
    }
    if (half == 1) up[jj] = acc;
    __syncthreads();
    if (half == 0) ul[jj] = fast_silu(acc + up[jj] + cl1_b[jj]);
  }
  __syncthreads();

  if (tid < 2) {
    float acc = cl2_b[tid];
#pragma unroll
    for (int k = 0; k < 64; ++k) acc = fmaf(ul[k], cl2_w[k * 2 + tid], acc);
    out[b * 2 + tid] = acc;
  }
}

// ===========================================================================
// FALLBACK tier3 (ws too small): verbatim R8 fallback pipeline.
// ===========================================================================

__device__ __forceinline__ void fb_rx(float2 cs, int w, int lane, float& ar, float& ai) {
  int m = 1 << (5 - w);
  float pr = __shfl_xor(ar, m, 64), pi = __shfl_xor(ai, m, 64);
  float nr = fmaf(cs.x, ar, cs.y * pi), ni = fmaf(cs.x, ai, -cs.y * pr);
  ar = nr; ai = ni;
}
__device__ __forceinline__ void fb_ry(float2 cs, int w, int lane, float& ar, float& ai) {
  int m = 1 << (5 - w);
  float pr = __shfl_xor(ar, m, 64), pi = __shfl_xor(ai, m, 64);
  float sg = ((lane >> (5 - w)) & 1) ? cs.y : -cs.y;
  float nr = fmaf(cs.x, ar, sg * pr), ni = fmaf(cs.x, ai, sg * pi);
  ar = nr; ai = ni;
}
__device__ __forceinline__ void fb_rz(float2 cs, int w, int lane, float& ar, float& ai) {
  float sp = ((lane >> (5 - w)) & 1) ? cs.y : -cs.y;
  float nr = fmaf(ar, cs.x, -ai * sp), ni = fmaf(ar, sp, ai * cs.x);
  ar = nr; ai = ni;
}
__device__ __forceinline__ void fb_crx(float2 cs, int w0, int w1, int lane, float& ar, float& ai) {
  int m = 1 << (5 - w1);
  float pr = __shfl_xor(ar, m, 64), pi = __shfl_xor(ai, m, 64);
  if ((lane >> (5 - w0)) & 1) {
    float nr = fmaf(cs.x, ar, cs.y * pi), ni = fmaf(cs.x, ai, -cs.y * pr);
    ar = nr; ai = ni;
  }
}
__device__ __forceinline__ void fb_ansatz(const float2* cs, int lane, float& ar, float& ai) {
#pragma unroll
  for (int i = 0; i < kNQ; ++i) {
    fb_rx(cs[3*i+0], i, lane, ar, ai);
    fb_ry(cs[3*i+1], i, lane, ar, ai);
    fb_rz(cs[3*i+2], i, lane, ar, ai);
  }
  int off = 18;
#pragma unroll
  for (int i = 0; i < kNQ; ++i) fb_crx(cs[off++], i, (i+1)%kNQ, lane, ar, ai);
#pragma unroll
  for (int i = kNQ-1; i >= 0; --i) fb_crx(cs[off++], i, (i+5)%kNQ, lane, ar, ai);
}

__global__ __launch_bounds__(128) void k_chunk_fb(
    const float* __restrict__ x,
    const float* __restrict__ conv_w, const float* __restrict__ conv_b,
    const float* __restrict__ ln1_g,  const float* __restrict__ ln1_b,
    const float* __restrict__ ca1_w,  const float* __restrict__ ca1_b,
    const float* __restrict__ ca2_w,  const float* __restrict__ ca2_b,
    const float* __restrict__ pp_w,   const float* __restrict__ pp_b,
    const float* __restrict__ ep_w,   const float* __restrict__ ep_b,
    const float* __restrict__ op_w,   const float* __restrict__ op_b,
    const float* __restrict__ ln2_g,  const float* __restrict__ ln2_b,
    float* __restrict__ cf)
{
  __shared__ float hbuf[kCHUNK][132];
  __shared__ __align__(16) float Bu[512];
  __shared__ float mrow[kCHUNK], irow[kCHUNK];
  __shared__ float red[4];
  float (*xs)[kCHUNK+2] = (float(*)[kCHUNK+2])Bu;
  float (*part)[32] = (float(*)[32])Bu;
  float* summ = Bu; float* wl = Bu + 128; float* qv = Bu + 144;
  float2* csb = (float2*)(Bu + 164);

  const int tid = threadIdx.x, chunk = blockIdx.x;
  const int b = chunk >> 7, nc = chunk & 127, t0 = nc * kCHUNK, d = tid;
  const int j = tid & 31, sub = tid >> 5;

  float w12[12];
  {
    const float4* cw = (const float4*)(conv_w + d*12);
    float4 a0=cw[0],a1=cw[1],a2=cw[2];
    w12[0]=a0.x;w12[1]=a0.y;w12[2]=a0.z;w12[3]=a0.w;
    w12[4]=a1.x;w12[5]=a1.y;w12[6]=a1.z;w12[7]=a1.w;
    w12[8]=a2.x;w12[9]=a2.y;w12[10]=a2.z;w12[11]=a2.w;
  }
  float cb = conv_b[d], g1 = ln1_g[d], b1 = ln1_b[d];
  float wreg[32];
  { const float* wp = ca1_w + (sub*32)*32 + j;
#pragma unroll
    for (int k = 0; k < 32; ++k) wreg[k] = wp[k*32]; }

  if (tid < kCH*(kCHUNK+2)) {
    int ch = tid/(kCHUNK+2), pos = tid%(kCHUNK+2), s = t0-1+pos;
    float v = 0.f; if (s >= 0 && s < kSEQ) v = x[(b*kCH+ch)*kSEQ + s];
    xs[ch][pos] = v;
  }
  __syncthreads();
#pragma unroll
  for (int t = 0; t < kCHUNK; ++t) {
    float acc = cb;
#pragma unroll
    for (int ch = 0; ch < kCH; ++ch)
#pragma unroll
      for (int k = 0; k < 3; ++k) acc = fmaf(xs[ch][t+k], w12[ch*3+k], acc);
    hbuf[t][d] = acc;
  }
  __syncthreads();
  {
    int row = tid >> 3, k = tid & 7;
    const float4* rp = (const float4*)&hbuf[row][k*16];
    float s1 = 0.f, s2 = 0.f;
#pragma unroll
    for (int q = 0; q < 4; ++q) {
      float4 v = rp[q];
      s1 += v.x+v.y+v.z+v.w;
      s2 = fmaf(v.x,v.x,s2); s2 = fmaf(v.y,v.y,s2);
      s2 = fmaf(v.z,v.z,s2); s2 = fmaf(v.w,v.w,s2);
    }
#pragma unroll
    for (int o = 1; o < 8; o <<= 1) { s1 += __shfl_xor(s1,o,64); s2 += __shfl_xor(s2,o,64); }
    if (k == 0) {
      float m = s1*(1.f/kDM);
      mrow[row] = m; irow[row] = rsqrtf(s2*(1.f/kDM) - m*m + 1e-5f);
    }
  }
  __syncthreads();
#pragma unroll
  for (int t = 0; t < kCHUNK; ++t)
    hbuf[t][d] = fmaf((hbuf[t][d]-mrow[t])*irow[t], g1, b1);
  __syncthreads();
  float p[kCHUNK];
#pragma unroll
  for (int t = 0; t < kCHUNK; ++t) {
    float acc = 0.f;
#pragma unroll
    for (int qq = 0; qq < 8; ++qq) {
      int q = (qq + 2*sub) & 7;
      float4 v = *(const float4*)&hbuf[t][sub*32 + q*4];
      acc = fmaf(v.x,wreg[q*4+0],acc); acc = fmaf(v.y,wreg[q*4+1],acc);
      acc = fmaf(v.z,wreg[q*4+2],acc); acc = fmaf(v.w,wreg[q*4+3],acc);
    }
    p[t] = acc;
  }
#pragma unroll
  for (int t = 0; t < kCHUNK; ++t) p[t] += __shfl_xor(p[t], 32, 64);
  if (sub == 2) {
#pragma unroll
    for (int t = 0; t < kCHUNK; ++t) part[t][j] = p[t];
  }
  __syncthreads();
  if (tid < 64) {
    float bj = ca1_b[j], w2 = ca2_w[j];
#pragma unroll
    for (int t = 0; t < kCHUNK; ++t) p[t] = fast_tanh(p[t] + part[t][j] + bj) * w2;
#pragma unroll
    for (int o = 16; o; o >>= 1)
#pragma unroll
      for (int t = 0; t < kCHUNK; ++t) p[t] += __shfl_xor(p[t], o, 64);
    float mx = p[0];
#pragma unroll
    for (int t = 1; t < kCHUNK; ++t) mx = fmaxf(mx, p[t]);
    float e[kCHUNK], ssum = 0.f;
#pragma unroll
    for (int t = 0; t < kCHUNK; ++t) { e[t] = __expf(p[t]-mx); ssum += e[t]; }
    float inv = 1.f/ssum;
    if (tid == 0) {
      float4* w4 = (float4*)wl;
      w4[0]=make_float4(e[0]*inv,e[1]*inv,e[2]*inv,e[3]*inv);
      w4[1]=make_float4(e[4]*inv,e[5]*inv,e[6]*inv,e[7]*inv);
      w4[2]=make_float4(e[8]*inv,e[9]*inv,e[10]*inv,e[11]*inv);
      w4[3]=make_float4(e[12]*inv,e[13]*inv,e[14]*inv,e[15]*inv);
    }
  }
  __syncthreads();
  {
    float acc = 0.f;
    const float4* w4 = (const float4*)wl;
#pragma unroll
    for (int tq = 0; tq < 4; ++tq) {
      float4 wv = w4[tq];
      acc = fmaf(wv.x,hbuf[tq*4+0][d],acc); acc = fmaf(wv.y,hbuf[tq*4+1][d],acc);
      acc = fmaf(wv.z,hbuf[tq*4+2][d],acc); acc = fmaf(wv.w,hbuf[tq*4+3][d],acc);
    }
    summ[d] = acc;
  }
  __syncthreads();
  if (tid < kNP) {
    float acc = pp_b[tid];
    const float4* s4 = (const float4*)summ;
#pragma unroll 8
    for (int q = 0; q < 32; ++q) {
      float4 v = s4[q];
      acc = fmaf(v.x,pp_w[(q*4+0)*kNP+tid],acc); acc = fmaf(v.y,pp_w[(q*4+1)*kNP+tid],acc);
      acc = fmaf(v.z,pp_w[(q*4+2)*kNP+tid],acc); acc = fmaf(v.w,pp_w[(q*4+3)*kNP+tid],acc);
    }
    csb[6+tid] = make_float2(__cosf(0.5f*acc), __sinf(0.5f*acc));
  } else if (tid < kNP + kNQ) {
    int jj = tid - kNP;
    float acc = ep_b[jj];
    for (int dd = 0; dd < kDM; ++dd) acc = fmaf(summ[dd], ep_w[dd*kNQ+jj], acc);
    float a = fast_tanh(acc) * kPI;
    csb[jj] = make_float2(__cosf(0.5f*a), __sinf(0.5f*a));
  }
  float ow[18];
#pragma unroll
  for (int jj = 0; jj < 18; ++jj) ow[jj] = op_w[jj*kDM + d];
  float g2 = ln2_g[d], b2 = ln2_b[d], ob = op_b[d];
  __syncthreads();
  if (tid < 64) {
    int lane = tid;
    float ar = (lane == 0) ? 1.f : 0.f, ai = 0.f;
#pragma unroll
    for (int i = 0; i < kNQ; ++i) fb_ry(csb[i], i, lane, ar, ai);
    fb_ansatz(csb+6, lane, ar, ai);  fb_ansatz(csb+36, lane, ar, ai);
    fb_ansatz(csb+66, lane, ar, ai); fb_ansatz(csb+96, lane, ar, ai);
#pragma unroll
    for (int i = 0; i < kNQ; ++i) {
      int m = 1 << (5-i);
      float pr = __shfl_xor(ar, m, 64), pi = __shfl_xor(ai, m, 64);
      int bit = (lane >> (5-i)) & 1;
      float nrm = fmaf(ar,ar,ai*ai);
      float abr, abi, zz;
      if (bit) { abr = 0.f; abi = 0.f; zz = -nrm; }
      else { abr = fmaf(ar,pr,ai*pi); abi = fmaf(ar,pi,-ai*pr); zz = nrm; }
#pragma unroll
      for (int o = 32; o; o >>= 1) {
        abr += __shfl_xor(abr,o,64); abi += __shfl_xor(abi,o,64); zz += __shfl_xor(zz,o,64);
      }
      if (lane == 0) { qv[i] = 2.f*abr; qv[kNQ+i] = 2.f*abi; qv[2*kNQ+i] = zz; }
    }
  }
  __syncthreads();
  {
    float acc = ob;
#pragma unroll
    for (int jj = 0; jj < 18; ++jj) acc = fmaf(qv[jj], ow[jj], acc);
    float v = acc, v2 = acc*acc;
#pragma unroll
    for (int o = 32; o; o >>= 1) { v += __shfl_xor(v,o,64); v2 += __shfl_xor(v2,o,64); }
    if ((tid & 63) == 0) { red[tid>>6] = v; red[2+(tid>>6)] = v2; }
    __syncthreads();
    float s1 = red[0]+red[1], s2 = red[2]+red[3];
    float m = s1*(1.f/kDM), var = s2*(1.f/kDM) - m*m;
    float xn = fmaf((acc-m)*rsqrtf(var+1e-5f), g2, b2);
    cf[(size_t)chunk*kDM + d] = fast_silu(xn);
  }
}

__global__ __launch_bounds__(256) void k_scl_fb(
    const float* __restrict__ cf,
    const float* __restrict__ sa1_w, const float* __restrict__ sa1_b,
    const float* __restrict__ sa2_w, const float* __restrict__ sa2_b,
    float* __restrict__ scl)
{
  int tid = threadIdx.x, wid = tid >> 6, lane = tid & 63;
  int pair = blockIdx.x * 4 + wid;
  int j = lane & 31, hh = lane >> 5;
  const float4* row = (const float4*)(cf + (size_t)pair*kDM + hh*64);
  const float* wp = sa1_w + (hh*64)*32 + j;
  float acc = 0.f;
#pragma unroll
  for (int q = 0; q < 16; ++q) {
    float4 v = row[q];
    acc = fmaf(v.x,wp[(q*4+0)*32],acc); acc = fmaf(v.y,wp[(q*4+1)*32],acc);
    acc = fmaf(v.z,wp[(q*4+2)*32],acc); acc = fmaf(v.w,wp[(q*4+3)*32],acc);
  }
  acc += __shfl_xor(acc, 32, 64);
  float hv = fast_tanh(acc + sa1_b[j]);
  float v = hv * sa2_w[j];
#pragma unroll
  for (int o = 16; o; o >>= 1) v += __shfl_xor(v, o, 64);
  if (lane == 0) scl[pair] = v + sa2_b[0];
}

__global__ __launch_bounds__(512) void k_pool_cf(
    const float* __restrict__ cf, const float* __restrict__ scl,
    const float* __restrict__ cl1_w, const float* __restrict__ cl1_b,
    const float* __restrict__ cl2_w, const float* __restrict__ cl2_b,
    float* __restrict__ out)
{
  __shared__ float wl[kNCH];
  __shared__ float rep4[4][kDM];
  __shared__ float ulp[8][64];
  __shared__ float ul[64];
  __shared__ float red2[16];
  int b = blockIdx.x, tid = threadIdx.x;
  int idx = tid & 127, wid = tid >> 6;
  float s = scl[b*kNCH + idx];
  float mx = s;
#pragma unroll
  for (int o = 32; o; o >>= 1) mx = fmaxf(mx, __shfl_xor(mx,o,64));
  if ((tid & 63) == 0) red2[wid] = mx;
  __syncthreads();
  mx = fmaxf(red2[0], red2[1]);
  float e = __expf(s - mx);
  float se = e;
#pragma unroll
  for (int o = 32; o; o >>= 1) se += __shfl_xor(se,o,64);
  if ((tid & 63) == 0) red2[8+wid] = se;
  if (tid < kNCH) wl[tid] = e;
  __syncthreads();
  float inv = 1.f/(red2[8]+red2[9]);
  {
    int dd = tid & 127, qq = tid >> 7;
    const float* cfb = cf + (size_t)b*kNCH*kDM + (size_t)qq*32*kDM;
    const float* wlq = wl + qq*32;
    float a0=0,a1=0,a2=0,a3=0;
#pragma unroll 4
    for (int ncc = 0; ncc < 32; ncc += 4) {
      a0 = fmaf(wlq[ncc+0], cfb[(ncc+0)*kDM+dd], a0);
      a1 = fmaf(wlq[ncc+1], cfb[(ncc+1)*kDM+dd], a1);
      a2 = fmaf(wlq[ncc+2], cfb[(ncc+2)*kDM+dd], a2);
      a3 = fmaf(wlq[ncc+3], cfb[(ncc+3)*kDM+dd], a3);
    }
    rep4[qq][dd] = (a0+a1)+(a2+a3);
  }
  __syncthreads();
  {
    int jj = tid & 63, qq = tid >> 6;
    float accp = 0.f;
#pragma unroll
    for (int k = 0; k < 16; ++k) {
      int dd = qq*16 + k;
      float rv = ((rep4[0][dd]+rep4[1][dd])+(rep4[2][dd]+rep4[3][dd]))*inv;
      accp = fmaf(rv, cl1_w[dd*64+jj], accp);
    }
    ulp[qq][jj] = accp;
  }
  __syncthreads();
  if (tid < 64) {
    float acc = cl1_b[tid];
#pragma unroll
    for (int q = 0; q < 8; ++q) acc += ulp[q][tid];
    ul[tid] = fast_silu(acc);
  }
  __syncthreads();
  if (tid < 2) {
    float acc = cl2_b[tid];
#pragma unroll
    for (int k = 0; k < 64; ++k) acc = fmaf(ul[k], cl2_w[k*2+tid], acc);
    out[b*2+tid] = acc;
  }
}

// ---------------------------------------------------------------------------

extern "C" void kernel_launch(void* const* d_in, const int* in_sizes, int n_in,
                              void* d_out, int out_size, void* d_ws, size_t ws_size,
                              hipStream_t stream) {
  const float* x      = (const float*)d_in[0];
  const float* conv_w = (const float*)d_in[1];
  const float* conv_b = (const float*)d_in[2];
  const float* ln1_g  = (const float*)d_in[3];
  const float* ln1_b  = (const float*)d_in[4];
  const float* ca1_w  = (const float*)d_in[5];
  const float* ca1_b  = (const float*)d_in[6];
  const float* ca2_w  = (const float*)d_in[7];
  const float* ca2_b  = (const float*)d_in[8];
  const float* pp_w   = (const float*)d_in[9];
  const float* pp_b   = (const float*)d_in[10];
  const float* ep_w   = (const float*)d_in[11];
  const float* ep_b   = (const float*)d_in[12];
  const float* op_w   = (const float*)d_in[13];
  const float* op_b   = (const float*)d_in[14];
  const float* ln2_g  = (const float*)d_in[15];
  const float* ln2_b  = (const float*)d_in[16];
  const float* sa1_w  = (const float*)d_in[17];
  const float* sa1_b  = (const float*)d_in[18];
  const float* sa2_w  = (const float*)d_in[19];
  const float* sa2_b  = (const float*)d_in[20];
  const float* cl1_w  = (const float*)d_in[21];
  const float* cl1_b  = (const float*)d_in[22];
  const float* cl2_w  = (const float*)d_in[23];
  const float* cl2_b  = (const float*)d_in[24];
  float* out = (float*)d_out;

  const size_t nch   = (size_t)kBATCH * kNCH;  // 16384
  const size_t fCS   = nch * 256;              // (cos,sin) pairs; cf+rpart alias inside
  const size_t need1 = (fCS + nch * 18 + nch) * sizeof(float);              // 18.0 MB
  const size_t fA    = nch * kDM;
  const size_t need2 = (fA + nch * 18 + nch + 1024 * kDM) * sizeof(float);  // 12.1 MB

  if (ws_size >= need1) {
    // tier1: cs pairs precomputed in k_pre. Aliasing is stream-ordered-safe:
    // csA dead after k_circ_cs; cf (base) and rpart (base+nch*128) live after.
    float* csA   = (float*)d_ws;
    float* cf    = csA;
    float* rpart = csA + nch * kDM;
    float* qv_g  = csA + fCS;
    float* sclb  = qv_g + nch * 18;
    k_pre<<<kBATCH * kNCH, 128, 0, stream>>>(
        x, conv_w, conv_b, ln1_g, ln1_b, ca1_w, ca1_b, ca2_w, ca2_b,
        pp_w, pp_b, ep_w, ep_b, csA, 1);
    k_circ_cs<<<(kBATCH * kNCH) / 16, 64, 0, stream>>>(csA, qv_g);
    k_post<<<kBATCH * kNCH, 128, 0, stream>>>(
        qv_g, op_w, op_b, ln2_g, ln2_b, sa1_w, sa1_b, sa2_w, sa2_b, cf, sclb);
    k_rpart<<<kBATCH * 8, 128, 0, stream>>>(cf, sclb, rpart);
    k_final<<<kBATCH, 128, 0, stream>>>(rpart, sclb, cl1_w, cl1_b, cl2_w, cl2_b, out);
  } else if (ws_size >= need2) {
    // tier2: R10 path (half-angles, k_circ computes sincos).
    float* A     = (float*)d_ws;
    float* qv_g  = A + fA;
    float* sclb  = qv_g + nch * 18;
    float* rpart = sclb + nch;
    k_pre<<<kBATCH * kNCH, 128, 0, stream>>>(
        x, conv_w, conv_b, ln1_g, ln1_b, ca1_w, ca1_b, ca2_w, ca2_b,
        pp_w, pp_b, ep_w, ep_b, A, 0);
    k_circ<<<(kBATCH * kNCH) / 16, 64, 0, stream>>>(A, qv_g);
    k_post<<<kBATCH * kNCH, 128, 0, stream>>>(
        qv_g, op_w, op_b, ln2_g, ln2_b, sa1_w, sa1_b, sa2_w, sa2_b, A, sclb);
    k_rpart<<<kBATCH * 8, 128, 0, stream>>>(A, sclb, rpart);
    k_final<<<kBATCH, 128, 0, stream>>>(rpart, sclb, cl1_w, cl1_b, cl2_w, cl2_b, out);
  } else {
    // tier3: R8 fallback.
    float* cf   = (float*)d_ws;
    float* sclb = cf + nch * kDM;
    k_chunk_fb<<<kBATCH * kNCH, 128, 0, stream>>>(
        x, conv_w, conv_b, ln1_g, ln1_b, ca1_w, ca1_b, ca2_w, ca2_b,
        pp_w, pp_b, ep_w, ep_b, op_w, op_b, ln2_g, ln2_b, cf);
    k_scl_fb<<<(kBATCH * kNCH) / 4, 256, 0, stream>>>(cf, sa1_w, sa1_b, sa2_w, sa2_b, sclb);
    k_pool_cf<<<kBATCH, 512, 0, stream>>>(cf, sclb, cl1_w, cl1_b, cl2_w, cl2_b, out);
  }
}

// Round 12
// 225.589 us; speedup vs baseline: 1.5437x; 1.0076x over previous
//
#include <hip/hip_runtime.h>
#include <math.h>

// ---------------------------------------------------------------------------
// QuantumTransformerE2E on MI355X — R12.
// R11 (227 µs) + two tail changes:
//  (1) kernels 5 -> 4: k_rpart+k_final replaced by the 512-thr per-batch
//      k_pool_cf (verified in R6) — one fewer launch boundary.
//  (2) k_circ_cs stages its 16 chunks' (cos,sin) arrays into LDS with one
//      coalesced bulk load (16 float4/lane), circuit reads broadcast
//      ds_read_b64 — removes ~126 exposed global-load latencies at the
//      1-wave/SIMD occupancy where nothing else can hide them.
// k_pre / k_post verbatim R10/R11 (verified).
// ---------------------------------------------------------------------------

constexpr int kNQ    = 6;
constexpr int kDM    = 128;
constexpr int kCH    = 4;
constexpr int kSEQ   = 2048;
constexpr int kCHUNK = 16;
constexpr int kBATCH = 128;
constexpr int kNCH   = kSEQ / kCHUNK;  // 128
constexpr int kNP    = 120;
constexpr float kPI  = 3.14159265358979323846f;

typedef __attribute__((ext_vector_type(8))) short bf16x8;
typedef __attribute__((ext_vector_type(4))) float f32x4;

__device__ __forceinline__ float fast_tanh(float x) {
  float e = __expf(-2.f * fabsf(x));
  float r = (1.f - e) * __builtin_amdgcn_rcpf(1.f + e);
  return copysignf(r, x);
}
__device__ __forceinline__ float fast_silu(float x) {
  return x * __builtin_amdgcn_rcpf(1.f + __expf(-x));
}

// quad_perm DPP helpers (VALU pipe).
template <int XM>
__device__ __forceinline__ float qp(float v) {
  constexpr int ctrl = (XM == 1) ? 0xB1 : 0x4E;
  return __int_as_float(
      __builtin_amdgcn_update_dpp(0, __float_as_int(v), ctrl, 0xF, 0xF, true));
}

// ---- register-resident 6-qubit gates (verified R8/R10) ---------------------

template <int RB>
__device__ __forceinline__ void rx_reg(float c, float s, float* sr, float* si) {
#pragma unroll
  for (int r0 = 0; r0 < 16; ++r0) {
    if (r0 & RB) continue;
    int r1 = r0 | RB;
    float ar = sr[r0], ai = si[r0], br = sr[r1], bi = si[r1];
    sr[r0] = fmaf(c, ar,  s * bi);  si[r0] = fmaf(c, ai, -s * br);
    sr[r1] = fmaf(c, br,  s * ai);  si[r1] = fmaf(c, bi, -s * ar);
  }
}

template <int RB>
__device__ __forceinline__ void ry_reg(float c, float s, float* sr, float* si) {
#pragma unroll
  for (int r0 = 0; r0 < 16; ++r0) {
    if (r0 & RB) continue;
    int r1 = r0 | RB;
    float ar = sr[r0], ai = si[r0], br = sr[r1], bi = si[r1];
    sr[r0] = fmaf(c, ar, -s * br);  si[r0] = fmaf(c, ai, -s * bi);
    sr[r1] = fmaf(s, ar,  c * br);  si[r1] = fmaf(s, ai,  c * bi);
  }
}

template <int RB>
__device__ __forceinline__ void rz_reg(float c, float s, float* sr, float* si) {
#pragma unroll
  for (int r = 0; r < 16; ++r) {
    float sp = (r & RB) ? s : -s;
    float ar = sr[r], ai = si[r];
    sr[r] = fmaf(c, ar, -sp * ai);
    si[r] = fmaf(c, ai,  sp * ar);
  }
}

template <int XM>
__device__ __forceinline__ void rx_lane(float c, float s, float* sr, float* si) {
#pragma unroll
  for (int r = 0; r < 16; ++r) {
    float pr = qp<XM>(sr[r]), pi = qp<XM>(si[r]);
    sr[r] = fmaf(c, sr[r],  s * pi);
    si[r] = fmaf(c, si[r], -s * pr);
  }
}

template <int XM>
__device__ __forceinline__ void ry_lane(float c, float sg, float* sr, float* si) {
#pragma unroll
  for (int r = 0; r < 16; ++r) {
    float pr = qp<XM>(sr[r]), pi = qp<XM>(si[r]);
    sr[r] = fmaf(c, sr[r], sg * pr);
    si[r] = fmaf(c, si[r], sg * pi);
  }
}

__device__ __forceinline__ void rz_lane(float c, float sp, float* sr, float* si) {
#pragma unroll
  for (int r = 0; r < 16; ++r) {
    float ar = sr[r], ai = si[r];
    sr[r] = fmaf(c, ar, -sp * ai);
    si[r] = fmaf(c, ai,  sp * ar);
  }
}

template <int RB, int CB>
__device__ __forceinline__ void crx_reg_reg(float c, float s, float* sr, float* si) {
#pragma unroll
  for (int r0 = 0; r0 < 16; ++r0) {
    if ((r0 & RB) || !(r0 & CB)) continue;
    int r1 = r0 | RB;
    float ar = sr[r0], ai = si[r0], br = sr[r1], bi = si[r1];
    sr[r0] = fmaf(c, ar,  s * bi);  si[r0] = fmaf(c, ai, -s * br);
    sr[r1] = fmaf(c, br,  s * ai);  si[r1] = fmaf(c, bi, -s * ar);
  }
}

template <int XM, int CB>
__device__ __forceinline__ void crx_reg_lane(float c, float s, float* sr, float* si) {
#pragma unroll
  for (int r = 0; r < 16; ++r) {
    if (!(r & CB)) continue;
    float pr = qp<XM>(sr[r]), pi = qp<XM>(si[r]);
    sr[r] = fmaf(c, sr[r],  s * pi);
    si[r] = fmaf(c, si[r], -s * pr);
  }
}

template <int RB>
__device__ __forceinline__ void meas_reg(const float* sr, const float* si,
                                         float& tr, float& ti, float& zz) {
  tr = 0.f; ti = 0.f; zz = 0.f;
#pragma unroll
  for (int r0 = 0; r0 < 16; ++r0) {
    float n = fmaf(sr[r0], sr[r0], si[r0] * si[r0]);
    zz += (r0 & RB) ? -n : n;
    if (r0 & RB) continue;
    int r1 = r0 | RB;
    tr = fmaf(sr[r0], sr[r1], fmaf(si[r0], si[r1], tr));
    ti = fmaf(sr[r0], si[r1], fmaf(-si[r0], sr[r1], ti));
  }
  tr += qp<1>(tr); tr += qp<2>(tr);
  ti += qp<1>(ti); ti += qp<2>(ti);
  zz += qp<1>(zz); zz += qp<2>(zz);
}

// ---------------------------------------------------------------------------
// k_pre: conv(global) + LN1 + MFMA chunk attention + projections.
// emit_cs=1: write (cos,sin) of half-angles, stride 256/chunk.
// emit_cs=0: write half-angles, stride 126/chunk (tier2).

__global__ __launch_bounds__(128) void k_pre(
    const float* __restrict__ x,
    const float* __restrict__ conv_w, const float* __restrict__ conv_b,
    const float* __restrict__ ln1_g,  const float* __restrict__ ln1_b,
    const float* __restrict__ ca1_w,  const float* __restrict__ ca1_b,
    const float* __restrict__ ca2_w,  const float* __restrict__ ca2_b,
    const float* __restrict__ pp_w,   const float* __restrict__ pp_b,
    const float* __restrict__ ep_w,   const float* __restrict__ ep_b,
    float* __restrict__ outb, int emit_cs)
{
  __shared__ float hbuf[kCHUNK][132];
  __shared__ __align__(16) float spart[2][16];
  __shared__ __align__(16) float summ[kDM];
  __shared__ float mrow[kCHUNK], irow[kCHUNK];

  const int tid   = threadIdx.x;
  const int chunk = blockIdx.x;
  const int b     = chunk >> 7;
  const int nc    = chunk & 127;
  const int t0    = nc * kCHUNK;
  const int d     = tid;
  const int lane  = tid & 63;
  const int wv    = tid >> 6;
  const int col   = (lane & 15) + 16 * wv;
  const int qd    = lane >> 4;

  float w12[12];
  {
    const float4* cw = (const float4*)(conv_w + d * 12);
    float4 a0 = cw[0], a1 = cw[1], a2 = cw[2];
    w12[0]=a0.x; w12[1]=a0.y; w12[2]=a0.z; w12[3]=a0.w;
    w12[4]=a1.x; w12[5]=a1.y; w12[6]=a1.z; w12[7]=a1.w;
    w12[8]=a2.x; w12[9]=a2.y; w12[10]=a2.z; w12[11]=a2.w;
  }
  float cb = conv_b[d];
  float g1 = ln1_g[d], b1 = ln1_b[d];
  float Bf[32];
#pragma unroll
  for (int ks = 0; ks < 4; ++ks)
#pragma unroll
    for (int jj = 0; jj < 8; ++jj)
      Bf[ks * 8 + jj] = ca1_w[(ks * 32 + qd * 8 + jj) * 32 + col];
  float cb1 = ca1_b[col], cw2 = ca2_w[col], cb2 = ca2_b[0];

  float h[kCHUNK];
#pragma unroll
  for (int t = 0; t < kCHUNK; ++t) h[t] = cb;
#pragma unroll
  for (int ch = 0; ch < kCH; ++ch) {
    const float* xb = x + ((size_t)b * kCH + ch) * kSEQ + t0 - 4;
    float xv[24];
#pragma unroll
    for (int sl = 1; sl <= 4; ++sl) {
      float4 v = *(const float4*)(xb + sl * 4);
      xv[sl*4+0]=v.x; xv[sl*4+1]=v.y; xv[sl*4+2]=v.z; xv[sl*4+3]=v.w;
    }
    if (nc > 0) {
      float4 v = *(const float4*)(xb);
      xv[0]=v.x; xv[1]=v.y; xv[2]=v.z; xv[3]=v.w;
    } else { xv[0]=xv[1]=xv[2]=xv[3]=0.f; }
    if (nc < 127) {
      float4 v = *(const float4*)(xb + 20);
      xv[20]=v.x; xv[21]=v.y; xv[22]=v.z; xv[23]=v.w;
    } else { xv[20]=xv[21]=xv[22]=xv[23]=0.f; }
    float c0 = w12[ch*3+0], c1 = w12[ch*3+1], c2 = w12[ch*3+2];
#pragma unroll
    for (int t = 0; t < kCHUNK; ++t)
      h[t] = fmaf(xv[t+3], c0, fmaf(xv[t+4], c1, fmaf(xv[t+5], c2, h[t])));
  }
#pragma unroll
  for (int t = 0; t < kCHUNK; ++t) hbuf[t][d] = h[t];
  __syncthreads();

  {
    int row = tid >> 3, k = tid & 7;
    const float4* rp = (const float4*)&hbuf[row][k * 16];
    float s1 = 0.f, s2 = 0.f;
#pragma unroll
    for (int q = 0; q < 4; ++q) {
      float4 v = rp[q];
      s1 += v.x + v.y + v.z + v.w;
      s2 = fmaf(v.x,v.x,s2); s2 = fmaf(v.y,v.y,s2);
      s2 = fmaf(v.z,v.z,s2); s2 = fmaf(v.w,v.w,s2);
    }
#pragma unroll
    for (int o = 1; o < 8; o <<= 1) {
      s1 += __shfl_xor(s1, o, 64);
      s2 += __shfl_xor(s2, o, 64);
    }
    if (k == 0) {
      float m = s1 * (1.f / kDM);
      mrow[row] = m;
      irow[row] = rsqrtf(s2 * (1.f / kDM) - m * m + 1e-5f);
    }
  }
  __syncthreads();

#pragma unroll
  for (int t = 0; t < kCHUNK; ++t) {
    h[t] = fmaf((h[t] - mrow[t]) * irow[t], g1, b1);
    unsigned hb = __float_as_uint(h[t]);
    float lof = h[t] - __uint_as_float(hb & 0xffff0000u);
    unsigned pk = (hb >> 16) | (__float_as_uint(lof) & 0xffff0000u);
    ((unsigned*)&hbuf[t][0])[d] = pk;
  }
  __syncthreads();

  bf16x8 bhi[4], blo[4];
#pragma unroll
  for (int ks = 0; ks < 4; ++ks)
#pragma unroll
    for (int jj = 0; jj < 8; ++jj) {
      float bvf = Bf[ks * 8 + jj];
      unsigned bb = __float_as_uint(bvf);
      bhi[ks][jj] = (short)(bb >> 16);
      float lf = bvf - __uint_as_float(bb & 0xffff0000u);
      blo[ks][jj] = (short)(__float_as_uint(lf) >> 16);
    }

  f32x4 acc = {0.f, 0.f, 0.f, 0.f};
  {
    const unsigned* hrow = (const unsigned*)&hbuf[lane & 15][0];
#pragma unroll
    for (int ks = 0; ks < 4; ++ks) {
      const uint4* ap = (const uint4*)(hrow + ks * 32 + qd * 8);
      uint4 w0 = ap[0], w1 = ap[1];
      bf16x8 ahi, alo;
      ahi[0] = (short)(w0.x & 0xffff); ahi[1] = (short)(w0.y & 0xffff);
      ahi[2] = (short)(w0.z & 0xffff); ahi[3] = (short)(w0.w & 0xffff);
      ahi[4] = (short)(w1.x & 0xffff); ahi[5] = (short)(w1.y & 0xffff);
      ahi[6] = (short)(w1.z & 0xffff); ahi[7] = (short)(w1.w & 0xffff);
      alo[0] = (short)(w0.x >> 16); alo[1] = (short)(w0.y >> 16);
      alo[2] = (short)(w0.z >> 16); alo[3] = (short)(w0.w >> 16);
      alo[4] = (short)(w1.x >> 16); alo[5] = (short)(w1.y >> 16);
      alo[6] = (short)(w1.z >> 16); alo[7] = (short)(w1.w >> 16);
      acc = __builtin_amdgcn_mfma_f32_16x16x32_bf16(ahi, bhi[ks], acc, 0, 0, 0);
      acc = __builtin_amdgcn_mfma_f32_16x16x32_bf16(ahi, blo[ks], acc, 0, 0, 0);
      acc = __builtin_amdgcn_mfma_f32_16x16x32_bf16(alo, bhi[ks], acc, 0, 0, 0);
    }
  }

  {
    float ev[4];
#pragma unroll
    for (int r = 0; r < 4; ++r)
      ev[r] = fast_tanh(acc[r] + cb1) * cw2;
#pragma unroll
    for (int o = 1; o < 16; o <<= 1)
#pragma unroll
      for (int r = 0; r < 4; ++r) ev[r] += __shfl_xor(ev[r], o, 64);
    if ((lane & 15) == 0)
      *(float4*)&spart[wv][qd * 4] = make_float4(ev[0], ev[1], ev[2], ev[3]);
  }
  __syncthreads();

  {
    float scl16[kCHUNK];
    const float4* s0 = (const float4*)&spart[0][0];
    const float4* s1 = (const float4*)&spart[1][0];
    float mx = -1e30f;
#pragma unroll
    for (int g = 0; g < 4; ++g) {
      float4 a = s0[g], bq = s1[g];
      scl16[g*4+0] = a.x + bq.x + cb2;
      scl16[g*4+1] = a.y + bq.y + cb2;
      scl16[g*4+2] = a.z + bq.z + cb2;
      scl16[g*4+3] = a.w + bq.w + cb2;
    }
#pragma unroll
    for (int t = 0; t < kCHUNK; ++t) mx = fmaxf(mx, scl16[t]);
    float e[kCHUNK], ssum = 0.f;
#pragma unroll
    for (int t = 0; t < kCHUNK; ++t) { e[t] = __expf(scl16[t] - mx); ssum += e[t]; }
    float inv = 1.f / ssum;
    float acc2 = 0.f;
#pragma unroll
    for (int t = 0; t < kCHUNK; ++t) acc2 = fmaf(e[t] * inv, h[t], acc2);
    summ[d] = acc2;
  }
  __syncthreads();

  if (tid < kNP) {
    float acc = pp_b[tid];
    const float4* s4 = (const float4*)summ;
#pragma unroll 8
    for (int q = 0; q < 32; ++q) {
      float4 v = s4[q];
      acc = fmaf(v.x, pp_w[(q*4+0)*kNP + tid], acc);
      acc = fmaf(v.y, pp_w[(q*4+1)*kNP + tid], acc);
      acc = fmaf(v.z, pp_w[(q*4+2)*kNP + tid], acc);
      acc = fmaf(v.w, pp_w[(q*4+3)*kNP + tid], acc);
    }
    float ha = 0.5f * acc;
    if (emit_cs) {
      ((float2*)(outb + (size_t)chunk * 256))[6 + tid] =
          make_float2(__cosf(ha), __sinf(ha));
    } else {
      outb[(size_t)chunk * 126 + 6 + tid] = ha;
    }
  } else if (tid < kNP + kNQ) {
    int jj = tid - kNP;
    float acc = ep_b[jj];
    const float4* s4 = (const float4*)summ;
#pragma unroll 8
    for (int q = 0; q < 32; ++q) {
      float4 v = s4[q];
      acc = fmaf(v.x, ep_w[(q*4+0)*kNQ + jj], acc);
      acc = fmaf(v.y, ep_w[(q*4+1)*kNQ + jj], acc);
      acc = fmaf(v.z, ep_w[(q*4+2)*kNQ + jj], acc);
      acc = fmaf(v.w, ep_w[(q*4+3)*kNQ + jj], acc);
    }
    float ha = 0.5f * fast_tanh(acc) * kPI;
    if (emit_cs) {
      ((float2*)(outb + (size_t)chunk * 256))[jj] =
          make_float2(__cosf(ha), __sinf(ha));
    } else {
      outb[(size_t)chunk * 126 + jj] = ha;
    }
  }
}

// ---------------------------------------------------------------------------
// k_circ_cs: tier1 — LDS-staged (cos,sin); zero transcendentals, bulk global
// load (16 coalesced float4/lane) replaces 126 exposed global loads.

constexpr int kCsStride = 260;  // floats; b128-aligned (1040 B), <=2-way bank alias

__global__ __launch_bounds__(64) void k_circ_cs(const float* __restrict__ csA,
                                                float* __restrict__ qv_g)
{
  __shared__ __align__(16) float lds[16 * kCsStride];  // 16.6 KB

  const int lane  = threadIdx.x;
  const int c     = lane >> 2;
  const int l     = lane & 3;
  const int chunk = blockIdx.x * 16 + c;
  const int b0 = (l >> 1) & 1;
  const int b1 = l & 1;

  // ---- stage: iteration i copies chunk i's 256 floats ----
  {
    const float4* src = (const float4*)(csA + (size_t)blockIdx.x * 16 * 256);
#pragma unroll
    for (int i = 0; i < 16; ++i) {
      float4 v = src[i * 64 + lane];
      *(float4*)&lds[i * kCsStride + lane * 4] = v;
    }
  }
  __syncthreads();

  const float2* cp = (const float2*)&lds[c * kCsStride];

  float sr[16], si[16];
#pragma unroll
  for (int r = 0; r < 16; ++r) { sr[r] = 0.f; si[r] = 0.f; }
  sr[0] = (l == 0) ? 1.f : 0.f;

  {
    float2 q0 = cp[0], q1 = cp[1], q2 = cp[2], q3 = cp[3], q4 = cp[4], q5 = cp[5];
    ry_lane<2>(q0.x, b0 ? q0.y : -q0.y, sr, si);
    ry_lane<1>(q1.x, b1 ? q1.y : -q1.y, sr, si);
    ry_reg<8>(q2.x, q2.y, sr, si);
    ry_reg<4>(q3.x, q3.y, sr, si);
    ry_reg<2>(q4.x, q4.y, sr, si);
    ry_reg<1>(q5.x, q5.y, sr, si);
  }

  for (int a = 0; a < 4; ++a) {
    const float2* pb = cp + 6 + a * 30;
    float2 t;
    t = pb[0];  rx_lane<2>(t.x, t.y, sr, si);
    t = pb[1];  ry_lane<2>(t.x, b0 ? t.y : -t.y, sr, si);
    t = pb[2];  rz_lane   (t.x, b0 ? t.y : -t.y, sr, si);
    t = pb[3];  rx_lane<1>(t.x, t.y, sr, si);
    t = pb[4];  ry_lane<1>(t.x, b1 ? t.y : -t.y, sr, si);
    t = pb[5];  rz_lane   (t.x, b1 ? t.y : -t.y, sr, si);
    t = pb[6];  rx_reg<8>(t.x, t.y, sr, si);
    t = pb[7];  ry_reg<8>(t.x, t.y, sr, si);
    t = pb[8];  rz_reg<8>(t.x, t.y, sr, si);
    t = pb[9];  rx_reg<4>(t.x, t.y, sr, si);
    t = pb[10]; ry_reg<4>(t.x, t.y, sr, si);
    t = pb[11]; rz_reg<4>(t.x, t.y, sr, si);
    t = pb[12]; rx_reg<2>(t.x, t.y, sr, si);
    t = pb[13]; ry_reg<2>(t.x, t.y, sr, si);
    t = pb[14]; rz_reg<2>(t.x, t.y, sr, si);
    t = pb[15]; rx_reg<1>(t.x, t.y, sr, si);
    t = pb[16]; ry_reg<1>(t.x, t.y, sr, si);
    t = pb[17]; rz_reg<1>(t.x, t.y, sr, si);
    t = pb[18]; { float c2 = b0 ? t.x : 1.f, s2 = b0 ? t.y : 0.f; rx_lane<1>(c2, s2, sr, si); }
    t = pb[19]; { float c2 = b1 ? t.x : 1.f, s2 = b1 ? t.y : 0.f; rx_reg<8>(c2, s2, sr, si); }
    t = pb[20]; crx_reg_reg<4, 8>(t.x, t.y, sr, si);
    t = pb[21]; crx_reg_reg<2, 4>(t.x, t.y, sr, si);
    t = pb[22]; crx_reg_reg<1, 2>(t.x, t.y, sr, si);
    t = pb[23]; crx_reg_lane<2, 1>(t.x, t.y, sr, si);
    t = pb[24]; crx_reg_reg<2, 1>(t.x, t.y, sr, si);
    t = pb[25]; crx_reg_reg<4, 2>(t.x, t.y, sr, si);
    t = pb[26]; crx_reg_reg<8, 4>(t.x, t.y, sr, si);
    t = pb[27]; crx_reg_lane<1, 8>(t.x, t.y, sr, si);
    t = pb[28]; { float c2 = b1 ? t.x : 1.f, s2 = b1 ? t.y : 0.f; rx_lane<2>(c2, s2, sr, si); }
    t = pb[29]; { float c2 = b0 ? t.x : 1.f, s2 = b0 ? t.y : 0.f; rx_reg<1>(c2, s2, sr, si); }
  }

  float res[18];
  {
    float tr = 0.f, ti = 0.f, zz = 0.f;
#pragma unroll
    for (int r = 0; r < 16; ++r) {
      float pr = qp<2>(sr[r]), pi = qp<2>(si[r]);
      tr = fmaf(sr[r], pr, fmaf(si[r], pi, tr));
      ti = fmaf(sr[r], pi, fmaf(-si[r], pr, ti));
      zz = fmaf(sr[r], sr[r], fmaf(si[r], si[r], zz));
    }
    tr = b0 ? 0.f : tr;  ti = b0 ? 0.f : ti;  zz = b0 ? -zz : zz;
    tr += qp<1>(tr); tr += qp<2>(tr);
    ti += qp<1>(ti); ti += qp<2>(ti);
    zz += qp<1>(zz); zz += qp<2>(zz);
    res[0] = 2.f * tr; res[6] = 2.f * ti; res[12] = zz;
  }
  {
    float tr = 0.f, ti = 0.f, zz = 0.f;
#pragma unroll
    for (int r = 0; r < 16; ++r) {
      float pr = qp<1>(sr[r]), pi = qp<1>(si[r]);
      tr = fmaf(sr[r], pr, fmaf(si[r], pi, tr));
      ti = fmaf(sr[r], pi, fmaf(-si[r], pr, ti));
      zz = fmaf(sr[r], sr[r], fmaf(si[r], si[r], zz));
    }
    tr = b1 ? 0.f : tr;  ti = b1 ? 0.f : ti;  zz = b1 ? -zz : zz;
    tr += qp<1>(tr); tr += qp<2>(tr);
    ti += qp<1>(ti); ti += qp<2>(ti);
    zz += qp<1>(zz); zz += qp<2>(zz);
    res[1] = 2.f * tr; res[7] = 2.f * ti; res[13] = zz;
  }
  {
    float tr, ti, zz;
    meas_reg<8>(sr, si, tr, ti, zz); res[2] = 2.f*tr; res[8]  = 2.f*ti; res[14] = zz;
    meas_reg<4>(sr, si, tr, ti, zz); res[3] = 2.f*tr; res[9]  = 2.f*ti; res[15] = zz;
    meas_reg<2>(sr, si, tr, ti, zz); res[4] = 2.f*tr; res[10] = 2.f*ti; res[16] = zz;
    meas_reg<1>(sr, si, tr, ti, zz); res[5] = 2.f*tr; res[11] = 2.f*ti; res[17] = zz;
  }
  if (l == 0) {
    float* qo = qv_g + (size_t)chunk * 18;
#pragma unroll
    for (int k = 0; k < 18; ++k) qo[k] = res[k];
  }
}

// ---------------------------------------------------------------------------
// k_circ: tier2 (verbatim R10) — reads half-angles stride 126, computes sincos.

__global__ __launch_bounds__(64) void k_circ(const float* __restrict__ csb_g,
                                             float* __restrict__ qv_g)
{
  const int lane  = threadIdx.x;
  const int c     = lane >> 2;
  const int l     = lane & 3;
  const int chunk = blockIdx.x * 16 + c;
  const float* cp = csb_g + (size_t)chunk * 126;
  const int b0 = (l >> 1) & 1;
  const int b1 = l & 1;

  float sr[16], si[16];
#pragma unroll
  for (int r = 0; r < 16; ++r) { sr[r] = 0.f; si[r] = 0.f; }
  sr[0] = (l == 0) ? 1.f : 0.f;

  {
    float gc[6], gs[6];
#pragma unroll
    for (int g = 0; g < 6; ++g) { float th = cp[g]; gc[g] = __cosf(th); gs[g] = __sinf(th); }
    ry_lane<2>(gc[0], b0 ? gs[0] : -gs[0], sr, si);
    ry_lane<1>(gc[1], b1 ? gs[1] : -gs[1], sr, si);
    ry_reg<8>(gc[2], gs[2], sr, si);
    ry_reg<4>(gc[3], gs[3], sr, si);
    ry_reg<2>(gc[4], gs[4], sr, si);
    ry_reg<1>(gc[5], gs[5], sr, si);
  }

  for (int a = 0; a < 4; ++a) {
    const float* pb = cp + 6 + a * 30;
    float gc[30], gs[30];
#pragma unroll
    for (int g = 0; g < 30; ++g) { float th = pb[g]; gc[g] = __cosf(th); gs[g] = __sinf(th); }
    rx_lane<2>(gc[0], gs[0], sr, si);
    ry_lane<2>(gc[1], b0 ? gs[1] : -gs[1], sr, si);
    rz_lane   (gc[2], b0 ? gs[2] : -gs[2], sr, si);
    rx_lane<1>(gc[3], gs[3], sr, si);
    ry_lane<1>(gc[4], b1 ? gs[4] : -gs[4], sr, si);
    rz_lane   (gc[5], b1 ? gs[5] : -gs[5], sr, si);
    rx_reg<8>(gc[6],  gs[6],  sr, si);  ry_reg<8>(gc[7],  gs[7],  sr, si);  rz_reg<8>(gc[8],  gs[8],  sr, si);
    rx_reg<4>(gc[9],  gs[9],  sr, si);  ry_reg<4>(gc[10], gs[10], sr, si);  rz_reg<4>(gc[11], gs[11], sr, si);
    rx_reg<2>(gc[12], gs[12], sr, si);  ry_reg<2>(gc[13], gs[13], sr, si);  rz_reg<2>(gc[14], gs[14], sr, si);
    rx_reg<1>(gc[15], gs[15], sr, si);  ry_reg<1>(gc[16], gs[16], sr, si);  rz_reg<1>(gc[17], gs[17], sr, si);
    { float c2 = b0 ? gc[18] : 1.f, s2 = b0 ? gs[18] : 0.f; rx_lane<1>(c2, s2, sr, si); }
    { float c2 = b1 ? gc[19] : 1.f, s2 = b1 ? gs[19] : 0.f; rx_reg<8>(c2, s2, sr, si); }
    crx_reg_reg<4, 8>(gc[20], gs[20], sr, si);
    crx_reg_reg<2, 4>(gc[21], gs[21], sr, si);
    crx_reg_reg<1, 2>(gc[22], gs[22], sr, si);
    crx_reg_lane<2, 1>(gc[23], gs[23], sr, si);
    crx_reg_reg<2, 1>(gc[24], gs[24], sr, si);
    crx_reg_reg<4, 2>(gc[25], gs[25], sr, si);
    crx_reg_reg<8, 4>(gc[26], gs[26], sr, si);
    crx_reg_lane<1, 8>(gc[27], gs[27], sr, si);
    { float c2 = b1 ? gc[28] : 1.f, s2 = b1 ? gs[28] : 0.f; rx_lane<2>(c2, s2, sr, si); }
    { float c2 = b0 ? gc[29] : 1.f, s2 = b0 ? gs[29] : 0.f; rx_reg<1>(c2, s2, sr, si); }
  }

  float res[18];
  {
    float tr = 0.f, ti = 0.f, zz = 0.f;
#pragma unroll
    for (int r = 0; r < 16; ++r) {
      float pr = qp<2>(sr[r]), pi = qp<2>(si[r]);
      tr = fmaf(sr[r], pr, fmaf(si[r], pi, tr));
      ti = fmaf(sr[r], pi, fmaf(-si[r], pr, ti));
      zz = fmaf(sr[r], sr[r], fmaf(si[r], si[r], zz));
    }
    tr = b0 ? 0.f : tr;  ti = b0 ? 0.f : ti;  zz = b0 ? -zz : zz;
    tr += qp<1>(tr); tr += qp<2>(tr);
    ti += qp<1>(ti); ti += qp<2>(ti);
    zz += qp<1>(zz); zz += qp<2>(zz);
    res[0] = 2.f * tr; res[6] = 2.f * ti; res[12] = zz;
  }
  {
    float tr = 0.f, ti = 0.f, zz = 0.f;
#pragma unroll
    for (int r = 0; r < 16; ++r) {
      float pr = qp<1>(sr[r]), pi = qp<1>(si[r]);
      tr = fmaf(sr[r], pr, fmaf(si[r], pi, tr));
      ti = fmaf(sr[r], pi, fmaf(-si[r], pr, ti));
      zz = fmaf(sr[r], sr[r], fmaf(si[r], si[r], zz));
    }
    tr = b1 ? 0.f : tr;  ti = b1 ? 0.f : ti;  zz = b1 ? -zz : zz;
    tr += qp<1>(tr); tr += qp<2>(tr);
    ti += qp<1>(ti); ti += qp<2>(ti);
    zz += qp<1>(zz); zz += qp<2>(zz);
    res[1] = 2.f * tr; res[7] = 2.f * ti; res[13] = zz;
  }
  {
    float tr, ti, zz;
    meas_reg<8>(sr, si, tr, ti, zz); res[2] = 2.f*tr; res[8]  = 2.f*ti; res[14] = zz;
    meas_reg<4>(sr, si, tr, ti, zz); res[3] = 2.f*tr; res[9]  = 2.f*ti; res[15] = zz;
    meas_reg<2>(sr, si, tr, ti, zz); res[4] = 2.f*tr; res[10] = 2.f*ti; res[16] = zz;
    meas_reg<1>(sr, si, tr, ti, zz); res[5] = 2.f*tr; res[11] = 2.f*ti; res[17] = zz;
  }
  if (l == 0) {
    float* qo = qv_g + (size_t)chunk * 18;
#pragma unroll
    for (int k = 0; k < 18; ++k) qo[k] = res[k];
  }
}

// ---------------------------------------------------------------------------
// k_post: verbatim R8/R10.

__global__ __launch_bounds__(128) void k_post(
    const float* __restrict__ qv_g,
    const float* __restrict__ op_w, const float* __restrict__ op_b,
    const float* __restrict__ ln2_g, const float* __restrict__ ln2_b,
    const float* __restrict__ sa1_w, const float* __restrict__ sa1_b,
    const float* __restrict__ sa2_w, const float* __restrict__ sa2_b,
    float* __restrict__ cf, float* __restrict__ sclb)
{
  __shared__ float cfs[132];
  __shared__ float part1[32];
  __shared__ float red[4];

  const int chunk = blockIdx.x, tid = threadIdx.x, d = tid;
  const int j = tid & 31, sub = tid >> 5;

  float qv[18];
  {
    const float* qpp = qv_g + (size_t)chunk * 18;
#pragma unroll
    for (int k = 0; k < 18; ++k) qv[k] = qpp[k];
  }
  float acc = op_b[d];
#pragma unroll
  for (int k = 0; k < 18; ++k) acc = fmaf(qv[k], op_w[k * kDM + d], acc);

  float v = acc, v2 = acc * acc;
#pragma unroll
  for (int o = 32; o; o >>= 1) { v += __shfl_xor(v, o, 64); v2 += __shfl_xor(v2, o, 64); }
  if ((tid & 63) == 0) { red[tid >> 6] = v; red[2 + (tid >> 6)] = v2; }
  __syncthreads();
  float s1 = red[0] + red[1], s2 = red[2] + red[3];
  float m = s1 * (1.f / kDM);
  float var = s2 * (1.f / kDM) - m * m;
  float xn = fmaf((acc - m) * rsqrtf(var + 1e-5f), ln2_g[d], ln2_b[d]);
  float cfv = fast_silu(xn);
  cf[(size_t)chunk * kDM + d] = cfv;
  cfs[d] = cfv;
  __syncthreads();

  float acc2 = 0.f;
  {
    const float* wp2 = sa1_w + (sub * 32) * 32 + j;
#pragma unroll
    for (int q = 0; q < 8; ++q) {
      float4 hv = *(const float4*)&cfs[sub * 32 + q * 4];
      acc2 = fmaf(hv.x, wp2[(q*4+0)*32], acc2);
      acc2 = fmaf(hv.y, wp2[(q*4+1)*32], acc2);
      acc2 = fmaf(hv.z, wp2[(q*4+2)*32], acc2);
      acc2 = fmaf(hv.w, wp2[(q*4+3)*32], acc2);
    }
  }
  acc2 += __shfl_xor(acc2, 32, 64);
  if (sub == 2) part1[j] = acc2;
  __syncthreads();
  if (tid < 32) {
    float hv = fast_tanh(acc2 + part1[j] + sa1_b[j]) * sa2_w[j];
#pragma unroll
    for (int o = 16; o; o >>= 1) hv += __shfl_xor(hv, o, 64);
    if (j == 0) sclb[chunk] = hv + sa2_b[0];
  }
}

// ---------------------------------------------------------------------------
// k_pool_cf: per-batch 512-thr softmax + pooling + classifier (ran in R6).

__global__ __launch_bounds__(512) void k_pool_cf(
    const float* __restrict__ cf, const float* __restrict__ scl,
    const float* __restrict__ cl1_w, const float* __restrict__ cl1_b,
    const float* __restrict__ cl2_w, const float* __restrict__ cl2_b,
    float* __restrict__ out)
{
  __shared__ float wl[kNCH];
  __shared__ float rep4[4][kDM];
  __shared__ float ulp[8][64];
  __shared__ float ul[64];
  __shared__ float red2[16];
  int b = blockIdx.x, tid = threadIdx.x;
  int idx = tid & 127, wid = tid >> 6;
  float s = scl[b*kNCH + idx];
  float mx = s;
#pragma unroll
  for (int o = 32; o; o >>= 1) mx = fmaxf(mx, __shfl_xor(mx,o,64));
  if ((tid & 63) == 0) red2[wid] = mx;
  __syncthreads();
  mx = fmaxf(red2[0], red2[1]);
  float e = __expf(s - mx);
  float se = e;
#pragma unroll
  for (int o = 32; o; o >>= 1) se += __shfl_xor(se,o,64);
  if ((tid & 63) == 0) red2[8+wid] = se;
  if (tid < kNCH) wl[tid] = e;
  __syncthreads();
  float inv = 1.f/(red2[8]+red2[9]);
  {
    int dd = tid & 127, qq = tid >> 7;
    const float* cfb = cf + (size_t)b*kNCH*kDM + (size_t)qq*32*kDM;
    const float* wlq = wl + qq*32;
    float a0=0,a1=0,a2=0,a3=0;
#pragma unroll 4
    for (int ncc = 0; ncc < 32; ncc += 4) {
      a0 = fmaf(wlq[ncc+0], cfb[(ncc+0)*kDM+dd], a0);
      a1 = fmaf(wlq[ncc+1], cfb[(ncc+1)*kDM+dd], a1);
      a2 = fmaf(wlq[ncc+2], cfb[(ncc+2)*kDM+dd], a2);
      a3 = fmaf(wlq[ncc+3], cfb[(ncc+3)*kDM+dd], a3);
    }
    rep4[qq][dd] = (a0+a1)+(a2+a3);
  }
  __syncthreads();
  {
    int jj = tid & 63, qq = tid >> 6;
    float accp = 0.f;
#pragma unroll
    for (int k = 0; k < 16; ++k) {
      int dd = qq*16 + k;
      float rv = ((rep4[0][dd]+rep4[1][dd])+(rep4[2][dd]+rep4[3][dd]))*inv;
      accp = fmaf(rv, cl1_w[dd*64+jj], accp);
    }
    ulp[qq][jj] = accp;
  }
  __syncthreads();
  if (tid < 64) {
    float acc = cl1_b[tid];
#pragma unroll
    for (int q = 0; q < 8; ++q) acc += ulp[q][tid];
    ul[tid] = fast_silu(acc);
  }
  __syncthreads();
  if (tid < 2) {
    float acc = cl2_b[tid];
#pragma unroll
    for (int k = 0; k < 64; ++k) acc = fmaf(ul[k], cl2_w[k*2+tid], acc);
    out[b*2+tid] = acc;
  }
}

// ===========================================================================
// FALLBACK tier3 (ws too small): verbatim R8 fallback pipeline.
// ===========================================================================

__device__ __forceinline__ void fb_rx(float2 cs, int w, int lane, float& ar, float& ai) {
  int m = 1 << (5 - w);
  float pr = __shfl_xor(ar, m, 64), pi = __shfl_xor(ai, m, 64);
  float nr = fmaf(cs.x, ar, cs.y * pi), ni = fmaf(cs.x, ai, -cs.y * pr);
  ar = nr; ai = ni;
}
__device__ __forceinline__ void fb_ry(float2 cs, int w, int lane, float& ar, float& ai) {
  int m = 1 << (5 - w);
  float pr = __shfl_xor(ar, m, 64), pi = __shfl_xor(ai, m, 64);
  float sg = ((lane >> (5 - w)) & 1) ? cs.y : -cs.y;
  float nr = fmaf(cs.x, ar, sg * pr), ni = fmaf(cs.x, ai, sg * pi);
  ar = nr; ai = ni;
}
__device__ __forceinline__ void fb_rz(float2 cs, int w, int lane, float& ar, float& ai) {
  float sp = ((lane >> (5 - w)) & 1) ? cs.y : -cs.y;
  float nr = fmaf(ar, cs.x, -ai * sp), ni = fmaf(ar, sp, ai * cs.x);
  ar = nr; ai = ni;
}
__device__ __forceinline__ void fb_crx(float2 cs, int w0, int w1, int lane, float& ar, float& ai) {
  int m = 1 << (5 - w1);
  float pr = __shfl_xor(ar, m, 64), pi = __shfl_xor(ai, m, 64);
  if ((lane >> (5 - w0)) & 1) {
    float nr = fmaf(cs.x, ar, cs.y * pi), ni = fmaf(cs.x, ai, -cs.y * pr);
    ar = nr; ai = ni;
  }
}
__device__ __forceinline__ void fb_ansatz(const float2* cs, int lane, float& ar, float& ai) {
#pragma unroll
  for (int i = 0; i < kNQ; ++i) {
    fb_rx(cs[3*i+0], i, lane, ar, ai);
    fb_ry(cs[3*i+1], i, lane, ar, ai);
    fb_rz(cs[3*i+2], i, lane, ar, ai);
  }
  int off = 18;
#pragma unroll
  for (int i = 0; i < kNQ; ++i) fb_crx(cs[off++], i, (i+1)%kNQ, lane, ar, ai);
#pragma unroll
  for (int i = kNQ-1; i >= 0; --i) fb_crx(cs[off++], i, (i+5)%kNQ, lane, ar, ai);
}

__global__ __launch_bounds__(128) void k_chunk_fb(
    const float* __restrict__ x,
    const float* __restrict__ conv_w, const float* __restrict__ conv_b,
    const float* __restrict__ ln1_g,  const float* __restrict__ ln1_b,
    const float* __restrict__ ca1_w,  const float* __restrict__ ca1_b,
    const float* __restrict__ ca2_w,  const float* __restrict__ ca2_b,
    const float* __restrict__ pp_w,   const float* __restrict__ pp_b,
    const float* __restrict__ ep_w,   const float* __restrict__ ep_b,
    const float* __restrict__ op_w,   const float* __restrict__ op_b,
    const float* __restrict__ ln2_g,  const float* __restrict__ ln2_b,
    float* __restrict__ cf)
{
  __shared__ float hbuf[kCHUNK][132];
  __shared__ __align__(16) float Bu[512];
  __shared__ float mrow[kCHUNK], irow[kCHUNK];
  __shared__ float red[4];
  float (*xs)[kCHUNK+2] = (float(*)[kCHUNK+2])Bu;
  float (*part)[32] = (float(*)[32])Bu;
  float* summ = Bu; float* wl = Bu + 128; float* qv = Bu + 144;
  float2* csb = (float2*)(Bu + 164);

  const int tid = threadIdx.x, chunk = blockIdx.x;
  const int b = chunk >> 7, nc = chunk & 127, t0 = nc * kCHUNK, d = tid;
  const int j = tid & 31, sub = tid >> 5;

  float w12[12];
  {
    const float4* cw = (const float4*)(conv_w + d*12);
    float4 a0=cw[0],a1=cw[1],a2=cw[2];
    w12[0]=a0.x;w12[1]=a0.y;w12[2]=a0.z;w12[3]=a0.w;
    w12[4]=a1.x;w12[5]=a1.y;w12[6]=a1.z;w12[7]=a1.w;
    w12[8]=a2.x;w12[9]=a2.y;w12[10]=a2.z;w12[11]=a2.w;
  }
  float cb = conv_b[d], g1 = ln1_g[d], b1 = ln1_b[d];
  float wreg[32];
  { const float* wp = ca1_w + (sub*32)*32 + j;
#pragma unroll
    for (int k = 0; k < 32; ++k) wreg[k] = wp[k*32]; }

  if (tid < kCH*(kCHUNK+2)) {
    int ch = tid/(kCHUNK+2), pos = tid%(kCHUNK+2), s = t0-1+pos;
    float v = 0.f; if (s >= 0 && s < kSEQ) v = x[(b*kCH+ch)*kSEQ + s];
    xs[ch][pos] = v;
  }
  __syncthreads();
#pragma unroll
  for (int t = 0; t < kCHUNK; ++t) {
    float acc = cb;
#pragma unroll
    for (int ch = 0; ch < kCH; ++ch)
#pragma unroll
      for (int k = 0; k < 3; ++k) acc = fmaf(xs[ch][t+k], w12[ch*3+k], acc);
    hbuf[t][d] = acc;
  }
  __syncthreads();
  {
    int row = tid >> 3, k = tid & 7;
    const float4* rp = (const float4*)&hbuf[row][k*16];
    float s1 = 0.f, s2 = 0.f;
#pragma unroll
    for (int q = 0; q < 4; ++q) {
      float4 v = rp[q];
      s1 += v.x+v.y+v.z+v.w;
      s2 = fmaf(v.x,v.x,s2); s2 = fmaf(v.y,v.y,s2);
      s2 = fmaf(v.z,v.z,s2); s2 = fmaf(v.w,v.w,s2);
    }
#pragma unroll
    for (int o = 1; o < 8; o <<= 1) { s1 += __shfl_xor(s1,o,64); s2 += __shfl_xor(s2,o,64); }
    if (k == 0) {
      float m = s1*(1.f/kDM);
      mrow[row] = m; irow[row] = rsqrtf(s2*(1.f/kDM) - m*m + 1e-5f);
    }
  }
  __syncthreads();
#pragma unroll
  for (int t = 0; t < kCHUNK; ++t)
    hbuf[t][d] = fmaf((hbuf[t][d]-mrow[t])*irow[t], g1, b1);
  __syncthreads();
  float p[kCHUNK];
#pragma unroll
  for (int t = 0; t < kCHUNK; ++t) {
    float acc = 0.f;
#pragma unroll
    for (int qq = 0; qq < 8; ++qq) {
      int q = (qq + 2*sub) & 7;
      float4 v = *(const float4*)&hbuf[t][sub*32 + q*4];
      acc = fmaf(v.x,wreg[q*4+0],acc); acc = fmaf(v.y,wreg[q*4+1],acc);
      acc = fmaf(v.z,wreg[q*4+2],acc); acc = fmaf(v.w,wreg[q*4+3],acc);
    }
    p[t] = acc;
  }
#pragma unroll
  for (int t = 0; t < kCHUNK; ++t) p[t] += __shfl_xor(p[t], 32, 64);
  if (sub == 2) {
#pragma unroll
    for (int t = 0; t < kCHUNK; ++t) part[t][j] = p[t];
  }
  __syncthreads();
  if (tid < 64) {
    float bj = ca1_b[j], w2 = ca2_w[j];
#pragma unroll
    for (int t = 0; t < kCHUNK; ++t) p[t] = fast_tanh(p[t] + part[t][j] + bj) * w2;
#pragma unroll
    for (int o = 16; o; o >>= 1)
#pragma unroll
      for (int t = 0; t < kCHUNK; ++t) p[t] += __shfl_xor(p[t], o, 64);
    float mx = p[0];
#pragma unroll
    for (int t = 1; t < kCHUNK; ++t) mx = fmaxf(mx, p[t]);
    float e[kCHUNK], ssum = 0.f;
#pragma unroll
    for (int t = 0; t < kCHUNK; ++t) { e[t] = __expf(p[t]-mx); ssum += e[t]; }
    float inv = 1.f/ssum;
    if (tid == 0) {
      float4* w4 = (float4*)wl;
      w4[0]=make_float4(e[0]*inv,e[1]*inv,e[2]*inv,e[3]*inv);
      w4[1]=make_float4(e[4]*inv,e[5]*inv,e[6]*inv,e[7]*inv);
      w4[2]=make_float4(e[8]*inv,e[9]*inv,e[10]*inv,e[11]*inv);
      w4[3]=make_float4(e[12]*inv,e[13]*inv,e[14]*inv,e[15]*inv);
    }
  }
  __syncthreads();
  {
    float acc = 0.f;
    const float4* w4 = (const float4*)wl;
#pragma unroll
    for (int tq = 0; tq < 4; ++tq) {
      float4 wv = w4[tq];
      acc = fmaf(wv.x,hbuf[tq*4+0][d],acc); acc = fmaf(wv.y,hbuf[tq*4+1][d],acc);
      acc = fmaf(wv.z,hbuf[tq*4+2][d],acc); acc = fmaf(wv.w,hbuf[tq*4+3][d],acc);
    }
    summ[d] = acc;
  }
  __syncthreads();
  if (tid < kNP) {
    float acc = pp_b[tid];
    const float4* s4 = (const float4*)summ;
#pragma unroll 8
    for (int q = 0; q < 32; ++q) {
      float4 v = s4[q];
      acc = fmaf(v.x,pp_w[(q*4+0)*kNP+tid],acc); acc = fmaf(v.y,pp_w[(q*4+1)*kNP+tid],acc);
      acc = fmaf(v.z,pp_w[(q*4+2)*kNP+tid],acc); acc = fmaf(v.w,pp_w[(q*4+3)*kNP+tid],acc);
    }
    csb[6+tid] = make_float2(__cosf(0.5f*acc), __sinf(0.5f*acc));
  } else if (tid < kNP + kNQ) {
    int jj = tid - kNP;
    float acc = ep_b[jj];
    for (int dd = 0; dd < kDM; ++dd) acc = fmaf(summ[dd], ep_w[dd*kNQ+jj], acc);
    float a = fast_tanh(acc) * kPI;
    csb[jj] = make_float2(__cosf(0.5f*a), __sinf(0.5f*a));
  }
  float ow[18];
#pragma unroll
  for (int jj = 0; jj < 18; ++jj) ow[jj] = op_w[jj*kDM + d];
  float g2 = ln2_g[d], b2 = ln2_b[d], ob = op_b[d];
  __syncthreads();
  if (tid < 64) {
    int lane = tid;
    float ar = (lane == 0) ? 1.f : 0.f, ai = 0.f;
#pragma unroll
    for (int i = 0; i < kNQ; ++i) fb_ry(csb[i], i, lane, ar, ai);
    fb_ansatz(csb+6, lane, ar, ai);  fb_ansatz(csb+36, lane, ar, ai);
    fb_ansatz(csb+66, lane, ar, ai); fb_ansatz(csb+96, lane, ar, ai);
#pragma unroll
    for (int i = 0; i < kNQ; ++i) {
      int m = 1 << (5-i);
      float pr = __shfl_xor(ar, m, 64), pi = __shfl_xor(ai, m, 64);
      int bit = (lane >> (5-i)) & 1;
      float nrm = fmaf(ar,ar,ai*ai);
      float abr, abi, zz;
      if (bit) { abr = 0.f; abi = 0.f; zz = -nrm; }
      else { abr = fmaf(ar,pr,ai*pi); abi = fmaf(ar,pi,-ai*pr); zz = nrm; }
#pragma unroll
      for (int o = 32; o; o >>= 1) {
        abr += __shfl_xor(abr,o,64); abi += __shfl_xor(abi,o,64); zz += __shfl_xor(zz,o,64);
      }
      if (lane == 0) { qv[i] = 2.f*abr; qv[kNQ+i] = 2.f*abi; qv[2*kNQ+i] = zz; }
    }
  }
  __syncthreads();
  {
    float acc = ob;
#pragma unroll
    for (int jj = 0; jj < 18; ++jj) acc = fmaf(qv[jj], ow[jj], acc);
    float v = acc, v2 = acc*acc;
#pragma unroll
    for (int o = 32; o; o >>= 1) { v += __shfl_xor(v,o,64); v2 += __shfl_xor(v2,o,64); }
    if ((tid & 63) == 0) { red[tid>>6] = v; red[2+(tid>>6)] = v2; }
    __syncthreads();
    float s1 = red[0]+red[1], s2 = red[2]+red[3];
    float m = s1*(1.f/kDM), var = s2*(1.f/kDM) - m*m;
    float xn = fmaf((acc-m)*rsqrtf(var+1e-5f), g2, b2);
    cf[(size_t)chunk*kDM + d] = fast_silu(xn);
  }
}

__global__ __launch_bounds__(256) void k_scl_fb(
    const float* __restrict__ cf,
    const float* __restrict__ sa1_w, const float* __restrict__ sa1_b,
    const float* __restrict__ sa2_w, const float* __restrict__ sa2_b,
    float* __restrict__ scl)
{
  int tid = threadIdx.x, wid = tid >> 6, lane = tid & 63;
  int pair = blockIdx.x * 4 + wid;
  int j = lane & 31, hh = lane >> 5;
  const float4* row = (const float4*)(cf + (size_t)pair*kDM + hh*64);
  const float* wp = sa1_w + (hh*64)*32 + j;
  float acc = 0.f;
#pragma unroll
  for (int q = 0; q < 16; ++q) {
    float4 v = row[q];
    acc = fmaf(v.x,wp[(q*4+0)*32],acc); acc = fmaf(v.y,wp[(q*4+1)*32],acc);
    acc = fmaf(v.z,wp[(q*4+2)*32],acc); acc = fmaf(v.w,wp[(q*4+3)*32],acc);
  }
  acc += __shfl_xor(acc, 32, 64);
  float hv = fast_tanh(acc + sa1_b[j]);
  float v = hv * sa2_w[j];
#pragma unroll
  for (int o = 16; o; o >>= 1) v += __shfl_xor(v, o, 64);
  if (lane == 0) scl[pair] = v + sa2_b[0];
}

// ---------------------------------------------------------------------------

extern "C" void kernel_launch(void* const* d_in, const int* in_sizes, int n_in,
                              void* d_out, int out_size, void* d_ws, size_t ws_size,
                              hipStream_t stream) {
  const float* x      = (const float*)d_in[0];
  const float* conv_w = (const float*)d_in[1];
  const float* conv_b = (const float*)d_in[2];
  const float* ln1_g  = (const float*)d_in[3];
  const float* ln1_b  = (const float*)d_in[4];
  const float* ca1_w  = (const float*)d_in[5];
  const float* ca1_b  = (const float*)d_in[6];
  const float* ca2_w  = (const float*)d_in[7];
  const float* ca2_b  = (const float*)d_in[8];
  const float* pp_w   = (const float*)d_in[9];
  const float* pp_b   = (const float*)d_in[10];
  const float* ep_w   = (const float*)d_in[11];
  const float* ep_b   = (const float*)d_in[12];
  const float* op_w   = (const float*)d_in[13];
  const float* op_b   = (const float*)d_in[14];
  const float* ln2_g  = (const float*)d_in[15];
  const float* ln2_b  = (const float*)d_in[16];
  const float* sa1_w  = (const float*)d_in[17];
  const float* sa1_b  = (const float*)d_in[18];
  const float* sa2_w  = (const float*)d_in[19];
  const float* sa2_b  = (const float*)d_in[20];
  const float* cl1_w  = (const float*)d_in[21];
  const float* cl1_b  = (const float*)d_in[22];
  const float* cl2_w  = (const float*)d_in[23];
  const float* cl2_b  = (const float*)d_in[24];
  float* out = (float*)d_out;

  const size_t nch   = (size_t)kBATCH * kNCH;  // 16384
  const size_t fCS   = nch * 256;              // cs pairs; cf aliased at base
  const size_t need1 = (fCS + nch * 18 + nch) * sizeof(float);   // 18.0 MB
  const size_t fA    = nch * kDM;
  const size_t need2 = (fA + nch * 18 + nch) * sizeof(float);    // 9.5 MB

  if (ws_size >= need1) {
    // tier1: csA dead after k_circ_cs; cf (base) lives after k_post.
    float* csA   = (float*)d_ws;
    float* cf    = csA;
    float* qv_g  = csA + fCS;
    float* sclb  = qv_g + nch * 18;
    k_pre<<<kBATCH * kNCH, 128, 0, stream>>>(
        x, conv_w, conv_b, ln1_g, ln1_b, ca1_w, ca1_b, ca2_w, ca2_b,
        pp_w, pp_b, ep_w, ep_b, csA, 1);
    k_circ_cs<<<(kBATCH * kNCH) / 16, 64, 0, stream>>>(csA, qv_g);
    k_post<<<kBATCH * kNCH, 128, 0, stream>>>(
        qv_g, op_w, op_b, ln2_g, ln2_b, sa1_w, sa1_b, sa2_w, sa2_b, cf, sclb);
    k_pool_cf<<<kBATCH, 512, 0, stream>>>(
        cf, sclb, cl1_w, cl1_b, cl2_w, cl2_b, out);
  } else if (ws_size >= need2) {
    // tier2: R10 path (half-angles; k_circ computes sincos), pool fused.
    float* A     = (float*)d_ws;
    float* qv_g  = A + fA;
    float* sclb  = qv_g + nch * 18;
    k_pre<<<kBATCH * kNCH, 128, 0, stream>>>(
        x, conv_w, conv_b, ln1_g, ln1_b, ca1_w, ca1_b, ca2_w, ca2_b,
        pp_w, pp_b, ep_w, ep_b, A, 0);
    k_circ<<<(kBATCH * kNCH) / 16, 64, 0, stream>>>(A, qv_g);
    k_post<<<kBATCH * kNCH, 128, 0, stream>>>(
        qv_g, op_w, op_b, ln2_g, ln2_b, sa1_w, sa1_b, sa2_w, sa2_b, A, sclb);
    k_pool_cf<<<kBATCH, 512, 0, stream>>>(
        A, sclb, cl1_w, cl1_b, cl2_w, cl2_b, out);
  } else {
    // tier3: R8 fallback.
    float* cf   = (float*)d_ws;
    float* sclb = cf + nch * kDM;
    k_chunk_fb<<<kBATCH * kNCH, 128, 0, stream>>>(
        x, conv_w, conv_b, ln1_g, ln1_b, ca1_w, ca1_b, ca2_w, ca2_b,
        pp_w, pp_b, ep_w, ep_b, op_w, op_b, ln2_g, ln2_b, cf);
    k_scl_fb<<<(kBATCH * kNCH) / 4, 256, 0, stream>>>(cf, sa1_w, sa1_b, sa2_w, sa2_b, sclb);
    k_pool_cf<<<kBATCH, 512, 0, stream>>>(cf, sclb, cl1_w, cl1_b, cl2_w, cl2_b, out);
  }
}